// Round 1
// baseline (1492.940 us; speedup 1.0000x reference)
//
#include <hip/hip_runtime.h>
#include <hip/hip_bf16.h>
#include <math.h>

// UniMP / TransformerConv block, f32, CSR + per-(node,head) online softmax.
// ws layout (floats): qkvs[N*2048] | agg[N*512] | normed[N*512] | ints...

// ---------------- K1: qkvs = x @ [Wq|Wk|Wv|Wskip] + bias ----------------
__global__ __launch_bounds__(256) void node_gemm_k(
    const float* __restrict__ x,
    const float* __restrict__ Wq, const float* __restrict__ bq,
    const float* __restrict__ Wk, const float* __restrict__ bk,
    const float* __restrict__ Wv, const float* __restrict__ bv,
    const float* __restrict__ Ws, const float* __restrict__ bs,
    float* __restrict__ qkvs, int n)
{
    __shared__ float xs[128][68];   // xs[k][row], padded (16B-aligned rows)
    __shared__ float ws[128][64];   // ws[k][col]
    const int t = threadIdx.x;
    const int bm = blockIdx.x;
    const int col0 = blockIdx.y * 64;       // 0..2047 in steps of 64
    const int mat = col0 >> 9;              // which of the 4 weight matrices
    const int mcol = col0 & 511;
    const float* W = (mat == 0) ? Wq : (mat == 1) ? Wk : (mat == 2) ? Wv : Ws;
    const float* B = (mat == 0) ? bq : (mat == 1) ? bk : (mat == 2) ? bv : bs;

    for (int i = t; i < 64 * 128; i += 256) {
        int r = i >> 7, k = i & 127;
        int row = bm * 64 + r;
        xs[k][r] = (row < n) ? x[(size_t)row * 128 + k] : 0.f;
    }
    for (int i = t; i < 128 * 64; i += 256) {
        int k = i >> 6, c = i & 63;
        ws[k][c] = W[(size_t)k * 512 + mcol + c];
    }
    __syncthreads();

    const int ty = t >> 4, tx = t & 15;
    float acc[4][4] = {};
    #pragma unroll 8
    for (int k = 0; k < 128; ++k) {
        float4 a = *(const float4*)&xs[k][ty * 4];
        float4 b = *(const float4*)&ws[k][tx * 4];
        acc[0][0] += a.x * b.x; acc[0][1] += a.x * b.y; acc[0][2] += a.x * b.z; acc[0][3] += a.x * b.w;
        acc[1][0] += a.y * b.x; acc[1][1] += a.y * b.y; acc[1][2] += a.y * b.z; acc[1][3] += a.y * b.w;
        acc[2][0] += a.z * b.x; acc[2][1] += a.z * b.y; acc[2][2] += a.z * b.z; acc[2][3] += a.z * b.w;
        acc[3][0] += a.w * b.x; acc[3][1] += a.w * b.y; acc[3][2] += a.w * b.z; acc[3][3] += a.w * b.w;
    }
    #pragma unroll
    for (int i = 0; i < 4; ++i) {
        int row = bm * 64 + ty * 4 + i;
        if (row < n) {
            int c = mcol + tx * 4;
            float4 o;
            o.x = acc[i][0] + B[c + 0];
            o.y = acc[i][1] + B[c + 1];
            o.z = acc[i][2] + B[c + 2];
            o.w = acc[i][3] + B[c + 3];
            *(float4*)&qkvs[(size_t)row * 2048 + col0 + tx * 4] = o;
        }
    }
}

// ---------------- CSR build ----------------
__global__ void deg_count_k(const int* __restrict__ dst, int* __restrict__ deg, int E)
{
    int e = blockIdx.x * 256 + threadIdx.x;
    if (e < E) atomicAdd(&deg[dst[e]], 1);
}

__global__ __launch_bounds__(1024) void scan_k(const int* __restrict__ deg,
                                               int* __restrict__ row_start,
                                               int* __restrict__ cursor, int n)
{
    __shared__ int part[1024];
    const int t = threadIdx.x;
    const int c0 = t * 16;                  // supports n <= 16384
    int loc[16];
    int s = 0;
    #pragma unroll
    for (int i = 0; i < 16; ++i) {
        int idx = c0 + i;
        int dv = (idx < n) ? deg[idx] : 0;
        loc[i] = s; s += dv;
    }
    part[t] = s;
    __syncthreads();
    int incl = s;
    for (int off = 1; off < 1024; off <<= 1) {
        int other = (t >= off) ? part[t - off] : 0;
        __syncthreads();
        incl += other;
        part[t] = incl;
        __syncthreads();
    }
    const int base = incl - s;
    #pragma unroll
    for (int i = 0; i < 16; ++i) {
        int idx = c0 + i;
        if (idx < n) { row_start[idx] = base + loc[i]; cursor[idx] = base + loc[i]; }
    }
    if (t == 1023) row_start[n] = incl;
}

__global__ void scatter_k(const int* __restrict__ ei, int* __restrict__ cursor,
                          int* __restrict__ csr_eid, int* __restrict__ csr_src, int E)
{
    int e = blockIdx.x * 256 + threadIdx.x;
    if (e < E) {
        int dnode = ei[E + e];
        int p = atomicAdd(&cursor[dnode], 1);
        csr_eid[p] = e;
        csr_src[p] = ei[e];
    }
}

// ---------------- K5: per-(node,head) fused e-proj + online softmax + PV ----------------
// block = 256 threads: slot = t>>7 (2 nodes in parallel), d = t&127 (output col of head)
// We head-chunk (128x128) in registers; edge_attr row broadcast from LDS.
__global__ __launch_bounds__(256) void aggregate_k(
    const float* __restrict__ qkvs, const float* __restrict__ ea,
    const float* __restrict__ We, const float* __restrict__ be,
    const int* __restrict__ row_start, const int* __restrict__ csr_eid,
    const int* __restrict__ csr_src,
    float* __restrict__ agg, int n)
{
    const int t = threadIdx.x;
    const int slot = t >> 7;
    const int d = t & 127;
    const int h = blockIdx.y;
    const int hd = h * 128 + d;

    float wreg[128];
    #pragma unroll
    for (int c = 0; c < 128; ++c) wreg[c] = We[(size_t)c * 512 + hd];
    const float bias_e = be[hd];

    __shared__ float ea_s[2][128];
    __shared__ float red_s[4];
    __shared__ int degs[2];

    for (int p = 0; p < 4; ++p) {
        const int node = blockIdx.x * 8 + p * 2 + slot;
        const bool nvalid = node < n;
        int rs = 0, deg = 0;
        if (nvalid) { rs = row_start[node]; deg = row_start[node + 1] - rs; }
        __syncthreads();
        if (d == 0) degs[slot] = deg;
        __syncthreads();
        const int mdeg = max(degs[0], degs[1]);
        const float qv = nvalid ? qkvs[(size_t)node * 2048 + hd] * 0.08838834764831845f : 0.f;
        float acc = 0.f, mrun = -3.0e38f, den = 0.f;

        for (int j = 0; j < mdeg; ++j) {
            const bool act = j < deg;
            int eid = 0, src = 0;
            if (act) { eid = csr_eid[rs + j]; src = csr_src[rs + j]; }
            __syncthreads();                                    // A: prev red_s/ea_s reads done
            ea_s[slot][d] = act ? ea[(size_t)eid * 128 + d] : 0.f;
            __syncthreads();                                    // B: ea_s ready
            const float kv = act ? qkvs[(size_t)src * 2048 + 512 + hd] : 0.f;
            const float vv = act ? qkvs[(size_t)src * 2048 + 1024 + hd] : 0.f;
            float e0 = 0.f, e1 = 0.f, e2 = 0.f, e3 = 0.f;       // 4 chains for ILP
            #pragma unroll
            for (int c = 0; c < 128; c += 16) {
                float4 a0 = *(const float4*)&ea_s[slot][c];
                float4 a1 = *(const float4*)&ea_s[slot][c + 4];
                float4 a2 = *(const float4*)&ea_s[slot][c + 8];
                float4 a3 = *(const float4*)&ea_s[slot][c + 12];
                e0 += a0.x * wreg[c + 0] + a0.y * wreg[c + 1] + a0.z * wreg[c + 2] + a0.w * wreg[c + 3];
                e1 += a1.x * wreg[c + 4] + a1.y * wreg[c + 5] + a1.z * wreg[c + 6] + a1.w * wreg[c + 7];
                e2 += a2.x * wreg[c + 8] + a2.y * wreg[c + 9] + a2.z * wreg[c + 10] + a2.w * wreg[c + 11];
                e3 += a3.x * wreg[c + 12] + a3.y * wreg[c + 13] + a3.z * wreg[c + 14] + a3.w * wreg[c + 15];
            }
            const float ev = bias_e + ((e0 + e1) + (e2 + e3));
            float part = (kv + ev) * qv;
            #pragma unroll
            for (int o = 32; o > 0; o >>= 1) part += __shfl_xor(part, o);  // wave64 reduce
            if ((t & 63) == 0) red_s[t >> 6] = part;
            __syncthreads();                                    // C: red_s ready
            const float alpha = red_s[slot * 2] + red_s[slot * 2 + 1];
            if (act) {
                const float mn = fmaxf(mrun, alpha);
                const float sc = expf(mrun - mn);
                const float w  = expf(alpha - mn);
                den = den * sc + w;
                acc = acc * sc + w * (vv + ev);
                mrun = mn;
            }
        }
        if (nvalid) agg[(size_t)node * 512 + hd] = (den > 0.f) ? acc / den : 0.f;
    }
}

// ---------------- K6: y = agg + skip ; LayerNorm -> normed ----------------
__global__ __launch_bounds__(256) void ln_k(
    const float* __restrict__ agg, const float* __restrict__ qkvs,
    const float* __restrict__ g, const float* __restrict__ b,
    float* __restrict__ normed, int n)
{
    const int node = blockIdx.x;
    const int t = threadIdx.x;
    const float y0 = agg[(size_t)node * 512 + t]       + qkvs[(size_t)node * 2048 + 1536 + t];
    const float y1 = agg[(size_t)node * 512 + 256 + t] + qkvs[(size_t)node * 2048 + 1536 + 256 + t];
    __shared__ float rs_s[4];
    float s = y0 + y1;
    #pragma unroll
    for (int o = 32; o > 0; o >>= 1) s += __shfl_xor(s, o);
    if ((t & 63) == 0) rs_s[t >> 6] = s;
    __syncthreads();
    const float mu = (rs_s[0] + rs_s[1] + rs_s[2] + rs_s[3]) * (1.f / 512.f);
    const float d0 = y0 - mu, d1 = y1 - mu;
    float s2 = d0 * d0 + d1 * d1;
    __syncthreads();
    #pragma unroll
    for (int o = 32; o > 0; o >>= 1) s2 += __shfl_xor(s2, o);
    if ((t & 63) == 0) rs_s[t >> 6] = s2;
    __syncthreads();
    const float var = (rs_s[0] + rs_s[1] + rs_s[2] + rs_s[3]) * (1.f / 512.f);
    const float rstd = rsqrtf(var + 1e-5f);
    normed[(size_t)node * 512 + t]       = d0 * rstd * g[t] + b[t];
    normed[(size_t)node * 512 + 256 + t] = d1 * rstd * g[256 + t] + b[256 + t];
}

// ---------------- K7: out = elu(normed @ Wlin + blin + x) ----------------
__global__ __launch_bounds__(256) void out_gemm_k(
    const float* __restrict__ normed, const float* __restrict__ Wlin,
    const float* __restrict__ blin, const float* __restrict__ x,
    float* __restrict__ out, int n)
{
    __shared__ float as[64][68];
    __shared__ float bs2[64][64];
    const int t = threadIdx.x;
    const int bm = blockIdx.x;
    const int col0 = blockIdx.y * 64;
    const int ty = t >> 4, tx = t & 15;
    float acc[4][4] = {};
    for (int k0 = 0; k0 < 512; k0 += 64) {
        for (int i = t; i < 64 * 64; i += 256) {
            int r = i >> 6, k = i & 63;
            int row = bm * 64 + r;
            as[k][r] = (row < n) ? normed[(size_t)row * 512 + k0 + k] : 0.f;
        }
        for (int i = t; i < 64 * 64; i += 256) {
            int k = i >> 6, c = i & 63;
            bs2[k][c] = Wlin[(size_t)(k0 + k) * 128 + col0 + c];
        }
        __syncthreads();
        #pragma unroll 8
        for (int k = 0; k < 64; ++k) {
            float4 a = *(const float4*)&as[k][ty * 4];
            float4 b = *(const float4*)&bs2[k][tx * 4];
            acc[0][0] += a.x * b.x; acc[0][1] += a.x * b.y; acc[0][2] += a.x * b.z; acc[0][3] += a.x * b.w;
            acc[1][0] += a.y * b.x; acc[1][1] += a.y * b.y; acc[1][2] += a.y * b.z; acc[1][3] += a.y * b.w;
            acc[2][0] += a.z * b.x; acc[2][1] += a.z * b.y; acc[2][2] += a.z * b.z; acc[2][3] += a.z * b.w;
            acc[3][0] += a.w * b.x; acc[3][1] += a.w * b.y; acc[3][2] += a.w * b.z; acc[3][3] += a.w * b.w;
        }
        __syncthreads();
    }
    #pragma unroll
    for (int i = 0; i < 4; ++i) {
        int row = bm * 64 + ty * 4 + i;
        if (row < n) {
            int col = col0 + tx * 4;
            float z0 = acc[i][0] + blin[col + 0] + x[(size_t)row * 128 + col + 0];
            float z1 = acc[i][1] + blin[col + 1] + x[(size_t)row * 128 + col + 1];
            float z2 = acc[i][2] + blin[col + 2] + x[(size_t)row * 128 + col + 2];
            float z3 = acc[i][3] + blin[col + 3] + x[(size_t)row * 128 + col + 3];
            float4 o;
            o.x = z0 > 0.f ? z0 : expm1f(z0);
            o.y = z1 > 0.f ? z1 : expm1f(z1);
            o.z = z2 > 0.f ? z2 : expm1f(z2);
            o.w = z3 > 0.f ? z3 : expm1f(z3);
            *(float4*)&out[(size_t)row * 128 + col] = o;
        }
    }
}

extern "C" void kernel_launch(void* const* d_in, const int* in_sizes, int n_in,
                              void* d_out, int out_size, void* d_ws, size_t ws_size,
                              hipStream_t stream)
{
    const float* x   = (const float*)d_in[0];
    const int*   ei  = (const int*)d_in[1];
    const float* ea  = (const float*)d_in[2];
    const float* Wq  = (const float*)d_in[3];
    const float* bq  = (const float*)d_in[4];
    const float* Wk  = (const float*)d_in[5];
    const float* bk  = (const float*)d_in[6];
    const float* Wv  = (const float*)d_in[7];
    const float* bv  = (const float*)d_in[8];
    const float* We  = (const float*)d_in[9];
    const float* be  = (const float*)d_in[10];
    const float* Wsk = (const float*)d_in[11];
    const float* bsk = (const float*)d_in[12];
    const float* lng = (const float*)d_in[13];
    const float* lnb = (const float*)d_in[14];
    const float* Wl  = (const float*)d_in[15];
    const float* bl  = (const float*)d_in[16];
    float* out = (float*)d_out;

    const int n = in_sizes[0] / 128;
    const int E = in_sizes[1] / 2;

    float* qkvs    = (float*)d_ws;
    float* agg     = qkvs + (size_t)n * 2048;
    float* normed  = agg + (size_t)n * 512;
    int* deg       = (int*)(normed + (size_t)n * 512);
    int* row_start = deg + n;
    int* cursor    = row_start + n + 1;
    int* csr_eid   = cursor + n;
    int* csr_src   = csr_eid + E;

    hipMemsetAsync(deg, 0, (size_t)n * sizeof(int), stream);

    dim3 g1((n + 63) / 64, 32);
    node_gemm_k<<<g1, 256, 0, stream>>>(x, Wq, bq, Wk, bk, Wv, bv, Wsk, bsk, qkvs, n);
    deg_count_k<<<(E + 255) / 256, 256, 0, stream>>>(ei + E, deg, E);
    scan_k<<<1, 1024, 0, stream>>>(deg, row_start, cursor, n);
    scatter_k<<<(E + 255) / 256, 256, 0, stream>>>(ei, cursor, csr_eid, csr_src, E);
    dim3 g5((n + 7) / 8, 4);
    aggregate_k<<<g5, 256, 0, stream>>>(qkvs, ea, We, be, row_start, csr_eid, csr_src, agg, n);
    ln_k<<<n, 256, 0, stream>>>(agg, qkvs, lng, lnb, normed, n);
    dim3 g7((n + 63) / 64, 2);
    out_gemm_k<<<g7, 256, 0, stream>>>(normed, Wl, bl, x, out, n);
}

// Round 2
// 531.662 us; speedup vs baseline: 2.8081x; 2.8081x over previous
//
#include <hip/hip_runtime.h>
#include <math.h>

// UniMP / TransformerConv block, f32.
// Algebraic restructure: e = ea@We_h + be_h is never materialized per edge.
//   alpha = (q.k + ea.qe + q.be)/sqrt(D),  qe = x @ WqeT (extra GEMM cols)
//   agg   = sum attn*v[src] + (sum attn*ea) @ We_h + be_h
// qkvs layout per node: [q 512 | k 512 | v 512 | skip 512 | qe 512] stride 2560

// ---------------- K0: WqeT[m,hc] = sum_d Wq[m,hd]*We[c,hd]; bqe[hc] = sum_d bq[hd]*We[c,hd]
__global__ __launch_bounds__(256) void wqe_k(
    const float* __restrict__ Wq, const float* __restrict__ bq,
    const float* __restrict__ We,
    float* __restrict__ WqeT, float* __restrict__ bqe)
{
    const int b = blockIdx.x;
    if (b < 256) {
        const int gid = b * 256 + threadIdx.x;      // 0..65535
        const int m = gid >> 9, hc = gid & 511;
        const int h = hc >> 7, c = hc & 127;
        const float* wq = &Wq[(size_t)m * 512 + h * 128];
        const float* we = &We[(size_t)c * 512 + h * 128];
        float s0 = 0.f, s1 = 0.f;
        #pragma unroll 8
        for (int d = 0; d < 128; d += 2) { s0 += wq[d] * we[d]; s1 += wq[d + 1] * we[d + 1]; }
        WqeT[(size_t)m * 512 + hc] = s0 + s1;
    } else {
        const int hc = (b - 256) * 256 + threadIdx.x;
        const int h = hc >> 7, c = hc & 127;
        const float* we = &We[(size_t)c * 512 + h * 128];
        const float* bb = &bq[h * 128];
        float s = 0.f;
        #pragma unroll 8
        for (int d = 0; d < 128; ++d) s += bb[d] * we[d];
        bqe[hc] = s;
    }
}

// ---------------- K1: qkvs = x @ [Wq|Wk|Wv|Wskip|WqeT] + bias ----------------
__global__ __launch_bounds__(256) void node_gemm_k(
    const float* __restrict__ x,
    const float* __restrict__ Wq, const float* __restrict__ bq,
    const float* __restrict__ Wk, const float* __restrict__ bk,
    const float* __restrict__ Wv, const float* __restrict__ bv,
    const float* __restrict__ Ws, const float* __restrict__ bs,
    const float* __restrict__ Wqe, const float* __restrict__ bqe,
    float* __restrict__ qkvs, int n)
{
    __shared__ float xs[128][68];
    __shared__ float ws[128][64];
    const int t = threadIdx.x;
    const int bm = blockIdx.x;
    const int col0 = blockIdx.y * 64;       // 0..2559
    const int mat = col0 >> 9;              // 0..4
    const int mcol = col0 & 511;
    const float* W = (mat == 0) ? Wq : (mat == 1) ? Wk : (mat == 2) ? Wv : (mat == 3) ? Ws : Wqe;
    const float* B = (mat == 0) ? bq : (mat == 1) ? bk : (mat == 2) ? bv : (mat == 3) ? bs : bqe;

    for (int i = t; i < 64 * 128; i += 256) {
        int r = i >> 7, k = i & 127;
        int row = bm * 64 + r;
        xs[k][r] = (row < n) ? x[(size_t)row * 128 + k] : 0.f;
    }
    for (int i = t; i < 128 * 64; i += 256) {
        int k = i >> 6, c = i & 63;
        ws[k][c] = W[(size_t)k * 512 + mcol + c];
    }
    __syncthreads();

    const int ty = t >> 4, tx = t & 15;
    float acc[4][4] = {};
    #pragma unroll 8
    for (int k = 0; k < 128; ++k) {
        float4 a = *(const float4*)&xs[k][ty * 4];
        float4 b = *(const float4*)&ws[k][tx * 4];
        acc[0][0] += a.x * b.x; acc[0][1] += a.x * b.y; acc[0][2] += a.x * b.z; acc[0][3] += a.x * b.w;
        acc[1][0] += a.y * b.x; acc[1][1] += a.y * b.y; acc[1][2] += a.y * b.z; acc[1][3] += a.y * b.w;
        acc[2][0] += a.z * b.x; acc[2][1] += a.z * b.y; acc[2][2] += a.z * b.z; acc[2][3] += a.z * b.w;
        acc[3][0] += a.w * b.x; acc[3][1] += a.w * b.y; acc[3][2] += a.w * b.z; acc[3][3] += a.w * b.w;
    }
    #pragma unroll
    for (int i = 0; i < 4; ++i) {
        int row = bm * 64 + ty * 4 + i;
        if (row < n) {
            int c = mcol + tx * 4;
            float4 o;
            o.x = acc[i][0] + B[c + 0];
            o.y = acc[i][1] + B[c + 1];
            o.z = acc[i][2] + B[c + 2];
            o.w = acc[i][3] + B[c + 3];
            *(float4*)&qkvs[(size_t)row * 2560 + col0 + tx * 4] = o;
        }
    }
}

// ---------------- CSR build ----------------
__global__ void deg_count_k(const int* __restrict__ dst, int* __restrict__ deg, int E)
{
    int e = blockIdx.x * 256 + threadIdx.x;
    if (e < E) atomicAdd(&deg[dst[e]], 1);
}

__global__ __launch_bounds__(1024) void scan_k(const int* __restrict__ deg,
                                               int* __restrict__ row_start,
                                               int* __restrict__ cursor, int n)
{
    __shared__ int part[1024];
    const int t = threadIdx.x;
    const int c0 = t * 16;                  // supports n <= 16384
    int loc[16];
    int s = 0;
    #pragma unroll
    for (int i = 0; i < 16; ++i) {
        int idx = c0 + i;
        int dv = (idx < n) ? deg[idx] : 0;
        loc[i] = s; s += dv;
    }
    part[t] = s;
    __syncthreads();
    int incl = s;
    for (int off = 1; off < 1024; off <<= 1) {
        int other = (t >= off) ? part[t - off] : 0;
        __syncthreads();
        incl += other;
        part[t] = incl;
        __syncthreads();
    }
    const int base = incl - s;
    #pragma unroll
    for (int i = 0; i < 16; ++i) {
        int idx = c0 + i;
        if (idx < n) { row_start[idx] = base + loc[i]; cursor[idx] = base + loc[i]; }
    }
    if (t == 1023) row_start[n] = incl;
}

__global__ void scatter_k(const int* __restrict__ ei, int* __restrict__ cursor,
                          int* __restrict__ csr_eid, int* __restrict__ csr_src, int E)
{
    int e = blockIdx.x * 256 + threadIdx.x;
    if (e < E) {
        int dnode = ei[E + e];
        int p = atomicAdd(&cursor[dnode], 1);
        csr_eid[p] = e;
        csr_src[p] = ei[e];
    }
}

// ---------------- K5: per-node edge phase (one wave per node, all 4 heads) ----------------
// pass 1: alpha[p,h] = s*(q.k + qe.ea) + qbe_h ; online m/den (scalars only)
// pass 2: w = exp(alpha-m)/den ; wsum += w*ea ; vacc += w*v[src]
__global__ __launch_bounds__(256) void edge_k(
    const float* __restrict__ qkvs, const float* __restrict__ ea,
    const float* __restrict__ be,
    const int* __restrict__ row_start, const int* __restrict__ csr_eid,
    const int* __restrict__ csr_src,
    float* __restrict__ alpha, float* __restrict__ wsum,
    float* __restrict__ vacc, int n)
{
    const int t = threadIdx.x;
    const int lane = t & 63;
    const int node = blockIdx.x * 4 + (t >> 6);
    if (node >= n) return;
    const int rs = row_start[node];
    const int deg = row_start[node + 1] - rs;
    const int c2 = lane * 2;
    const float s = 0.08838834764831845f;   // 1/sqrt(128)
    const size_t nb = (size_t)node * 2560;

    float2 q2[4], qe2[4];
    #pragma unroll
    for (int h = 0; h < 4; ++h) {
        float2 a = *(const float2*)&qkvs[nb + h * 128 + c2];
        q2[h] = make_float2(a.x * s, a.y * s);
        float2 b = *(const float2*)&qkvs[nb + 2048 + h * 128 + c2];
        qe2[h] = make_float2(b.x * s, b.y * s);
    }
    float4 qbe;
    {
        float p[4];
        #pragma unroll
        for (int h = 0; h < 4; ++h) {
            float2 b2 = *(const float2*)&be[h * 128 + c2];
            p[h] = q2[h].x * b2.x + q2[h].y * b2.y;
        }
        #pragma unroll
        for (int o = 32; o > 0; o >>= 1) {
            p[0] += __shfl_xor(p[0], o); p[1] += __shfl_xor(p[1], o);
            p[2] += __shfl_xor(p[2], o); p[3] += __shfl_xor(p[3], o);
        }
        qbe = make_float4(p[0], p[1], p[2], p[3]);
    }

    float m4[4] = {-3e38f, -3e38f, -3e38f, -3e38f};
    float den4[4] = {0.f, 0.f, 0.f, 0.f};

    // ---- pass 1 ----
    for (int j0 = 0; j0 < deg; j0 += 64) {
        const int cnt = min(64, deg - j0);
        int my_eid = 0, my_src = 0;
        if (lane < cnt) { my_eid = csr_eid[rs + j0 + lane]; my_src = csr_src[rs + j0 + lane]; }
        for (int jj = 0; jj < cnt; ++jj) {
            const int eid = __shfl(my_eid, jj);
            const int src = __shfl(my_src, jj);
            const float2 eav = *(const float2*)&ea[(size_t)eid * 128 + c2];
            const size_t sb = (size_t)src * 2560 + 512;
            float p[4];
            #pragma unroll
            for (int h = 0; h < 4; ++h) {
                float2 k2 = *(const float2*)&qkvs[sb + h * 128 + c2];
                p[h] = q2[h].x * k2.x + q2[h].y * k2.y
                     + qe2[h].x * eav.x + qe2[h].y * eav.y;
            }
            #pragma unroll
            for (int o = 32; o > 0; o >>= 1) {
                p[0] += __shfl_xor(p[0], o); p[1] += __shfl_xor(p[1], o);
                p[2] += __shfl_xor(p[2], o); p[3] += __shfl_xor(p[3], o);
            }
            p[0] += qbe.x; p[1] += qbe.y; p[2] += qbe.z; p[3] += qbe.w;
            if (lane < 4) {
                float av = (lane == 0) ? p[0] : (lane == 1) ? p[1] : (lane == 2) ? p[2] : p[3];
                alpha[(size_t)(rs + j0 + jj) * 4 + lane] = av;
            }
            #pragma unroll
            for (int h = 0; h < 4; ++h) {
                float nm = fmaxf(m4[h], p[h]);
                den4[h] = den4[h] * expf(m4[h] - nm) + expf(p[h] - nm);
                m4[h] = nm;
            }
        }
    }
    float rden[4];
    #pragma unroll
    for (int h = 0; h < 4; ++h) rden[h] = (den4[h] > 0.f) ? 1.f / den4[h] : 0.f;

    // ---- pass 2 ----
    float2 ws2[4] = {{0,0},{0,0},{0,0},{0,0}};
    float2 va2[4] = {{0,0},{0,0},{0,0},{0,0}};
    for (int j0 = 0; j0 < deg; j0 += 64) {
        const int cnt = min(64, deg - j0);
        int my_eid = 0, my_src = 0;
        if (lane < cnt) { my_eid = csr_eid[rs + j0 + lane]; my_src = csr_src[rs + j0 + lane]; }
        for (int jj = 0; jj < cnt; ++jj) {
            const int eid = __shfl(my_eid, jj);
            const int src = __shfl(my_src, jj);
            const float4 a4 = *(const float4*)&alpha[(size_t)(rs + j0 + jj) * 4];
            float w[4];
            w[0] = expf(a4.x - m4[0]) * rden[0];
            w[1] = expf(a4.y - m4[1]) * rden[1];
            w[2] = expf(a4.z - m4[2]) * rden[2];
            w[3] = expf(a4.w - m4[3]) * rden[3];
            const float2 eav = *(const float2*)&ea[(size_t)eid * 128 + c2];
            const size_t sb = (size_t)src * 2560 + 1024;
            #pragma unroll
            for (int h = 0; h < 4; ++h) {
                float2 v2 = *(const float2*)&qkvs[sb + h * 128 + c2];
                va2[h].x += w[h] * v2.x; va2[h].y += w[h] * v2.y;
                ws2[h].x += w[h] * eav.x; ws2[h].y += w[h] * eav.y;
            }
        }
    }
    #pragma unroll
    for (int h = 0; h < 4; ++h) {
        *(float2*)&wsum[(size_t)node * 512 + h * 128 + c2] = ws2[h];
        *(float2*)&vacc[(size_t)node * 512 + h * 128 + c2] = va2[h];
    }
}

// ---------------- K6: agg = vacc + wsum @ We_h + be (in place on vacc) ----------------
__global__ __launch_bounds__(256) void final_gemm_k(
    const float* __restrict__ wsum, const float* __restrict__ We,
    const float* __restrict__ be, const int* __restrict__ row_start,
    float* __restrict__ agg, int n)
{
    __shared__ float as[64][68];
    __shared__ float bs2[64][64];
    const int t = threadIdx.x;
    const int bm = blockIdx.x;
    const int col0 = blockIdx.y * 64;   // 0..511
    const int head = col0 >> 7;
    const int ty = t >> 4, tx = t & 15;
    float acc[4][4] = {};
    for (int k0 = 0; k0 < 128; k0 += 64) {
        for (int i = t; i < 64 * 64; i += 256) {
            int r = i >> 6, k = i & 63;
            int row = bm * 64 + r;
            as[k][r] = (row < n) ? wsum[(size_t)row * 512 + head * 128 + k0 + k] : 0.f;
        }
        for (int i = t; i < 64 * 64; i += 256) {
            int k = i >> 6, c = i & 63;
            bs2[k][c] = We[(size_t)(k0 + k) * 512 + col0 + c];
        }
        __syncthreads();
        #pragma unroll 8
        for (int k = 0; k < 64; ++k) {
            float4 a = *(const float4*)&as[k][ty * 4];
            float4 b = *(const float4*)&bs2[k][tx * 4];
            acc[0][0] += a.x * b.x; acc[0][1] += a.x * b.y; acc[0][2] += a.x * b.z; acc[0][3] += a.x * b.w;
            acc[1][0] += a.y * b.x; acc[1][1] += a.y * b.y; acc[1][2] += a.y * b.z; acc[1][3] += a.y * b.w;
            acc[2][0] += a.z * b.x; acc[2][1] += a.z * b.y; acc[2][2] += a.z * b.z; acc[2][3] += a.z * b.w;
            acc[3][0] += a.w * b.x; acc[3][1] += a.w * b.y; acc[3][2] += a.w * b.z; acc[3][3] += a.w * b.w;
        }
        __syncthreads();
    }
    #pragma unroll
    for (int i = 0; i < 4; ++i) {
        int row = bm * 64 + ty * 4 + i;
        if (row < n) {
            int col = col0 + tx * 4;
            const float hb = (row_start[row + 1] > row_start[row]) ? 1.f : 0.f;
            float4 o = *(float4*)&agg[(size_t)row * 512 + col];
            o.x += acc[i][0] + hb * be[col + 0];
            o.y += acc[i][1] + hb * be[col + 1];
            o.z += acc[i][2] + hb * be[col + 2];
            o.w += acc[i][3] + hb * be[col + 3];
            *(float4*)&agg[(size_t)row * 512 + col] = o;
        }
    }
}

// ---------------- K7: y = agg + skip ; LayerNorm -> normed ----------------
__global__ __launch_bounds__(256) void ln_k(
    const float* __restrict__ agg, const float* __restrict__ qkvs,
    const float* __restrict__ g, const float* __restrict__ b,
    float* __restrict__ normed, int n)
{
    const int node = blockIdx.x;
    const int t = threadIdx.x;
    const float y0 = agg[(size_t)node * 512 + t]       + qkvs[(size_t)node * 2560 + 1536 + t];
    const float y1 = agg[(size_t)node * 512 + 256 + t] + qkvs[(size_t)node * 2560 + 1536 + 256 + t];
    __shared__ float rs_s[4];
    float s = y0 + y1;
    #pragma unroll
    for (int o = 32; o > 0; o >>= 1) s += __shfl_xor(s, o);
    if ((t & 63) == 0) rs_s[t >> 6] = s;
    __syncthreads();
    const float mu = (rs_s[0] + rs_s[1] + rs_s[2] + rs_s[3]) * (1.f / 512.f);
    const float d0 = y0 - mu, d1 = y1 - mu;
    float s2 = d0 * d0 + d1 * d1;
    __syncthreads();
    #pragma unroll
    for (int o = 32; o > 0; o >>= 1) s2 += __shfl_xor(s2, o);
    if ((t & 63) == 0) rs_s[t >> 6] = s2;
    __syncthreads();
    const float var = (rs_s[0] + rs_s[1] + rs_s[2] + rs_s[3]) * (1.f / 512.f);
    const float rstd = rsqrtf(var + 1e-5f);
    normed[(size_t)node * 512 + t]       = d0 * rstd * g[t] + b[t];
    normed[(size_t)node * 512 + 256 + t] = d1 * rstd * g[256 + t] + b[256 + t];
}

// ---------------- K8: out = elu(normed @ Wlin + blin + x) ----------------
__global__ __launch_bounds__(256) void out_gemm_k(
    const float* __restrict__ normed, const float* __restrict__ Wlin,
    const float* __restrict__ blin, const float* __restrict__ x,
    float* __restrict__ out, int n)
{
    __shared__ float as[64][68];
    __shared__ float bs2[64][64];
    const int t = threadIdx.x;
    const int bm = blockIdx.x;
    const int col0 = blockIdx.y * 64;
    const int ty = t >> 4, tx = t & 15;
    float acc[4][4] = {};
    for (int k0 = 0; k0 < 512; k0 += 64) {
        for (int i = t; i < 64 * 64; i += 256) {
            int r = i >> 6, k = i & 63;
            int row = bm * 64 + r;
            as[k][r] = (row < n) ? normed[(size_t)row * 512 + k0 + k] : 0.f;
        }
        for (int i = t; i < 64 * 64; i += 256) {
            int k = i >> 6, c = i & 63;
            bs2[k][c] = Wlin[(size_t)(k0 + k) * 128 + col0 + c];
        }
        __syncthreads();
        #pragma unroll 8
        for (int k = 0; k < 64; ++k) {
            float4 a = *(const float4*)&as[k][ty * 4];
            float4 b = *(const float4*)&bs2[k][tx * 4];
            acc[0][0] += a.x * b.x; acc[0][1] += a.x * b.y; acc[0][2] += a.x * b.z; acc[0][3] += a.x * b.w;
            acc[1][0] += a.y * b.x; acc[1][1] += a.y * b.y; acc[1][2] += a.y * b.z; acc[1][3] += a.y * b.w;
            acc[2][0] += a.z * b.x; acc[2][1] += a.z * b.y; acc[2][2] += a.z * b.z; acc[2][3] += a.z * b.w;
            acc[3][0] += a.w * b.x; acc[3][1] += a.w * b.y; acc[3][2] += a.w * b.z; acc[3][3] += a.w * b.w;
        }
        __syncthreads();
    }
    #pragma unroll
    for (int i = 0; i < 4; ++i) {
        int row = bm * 64 + ty * 4 + i;
        if (row < n) {
            int col = col0 + tx * 4;
            float z0 = acc[i][0] + blin[col + 0] + x[(size_t)row * 128 + col + 0];
            float z1 = acc[i][1] + blin[col + 1] + x[(size_t)row * 128 + col + 1];
            float z2 = acc[i][2] + blin[col + 2] + x[(size_t)row * 128 + col + 2];
            float z3 = acc[i][3] + blin[col + 3] + x[(size_t)row * 128 + col + 3];
            float4 o;
            o.x = z0 > 0.f ? z0 : expm1f(z0);
            o.y = z1 > 0.f ? z1 : expm1f(z1);
            o.z = z2 > 0.f ? z2 : expm1f(z2);
            o.w = z3 > 0.f ? z3 : expm1f(z3);
            *(float4*)&out[(size_t)row * 128 + col] = o;
        }
    }
}

extern "C" void kernel_launch(void* const* d_in, const int* in_sizes, int n_in,
                              void* d_out, int out_size, void* d_ws, size_t ws_size,
                              hipStream_t stream)
{
    const float* x   = (const float*)d_in[0];
    const int*   ei  = (const int*)d_in[1];
    const float* ea  = (const float*)d_in[2];
    const float* Wq  = (const float*)d_in[3];
    const float* bq  = (const float*)d_in[4];
    const float* Wk  = (const float*)d_in[5];
    const float* bk  = (const float*)d_in[6];
    const float* Wv  = (const float*)d_in[7];
    const float* bv  = (const float*)d_in[8];
    const float* We  = (const float*)d_in[9];
    const float* be  = (const float*)d_in[10];
    const float* Wsk = (const float*)d_in[11];
    const float* bsk = (const float*)d_in[12];
    const float* lng = (const float*)d_in[13];
    const float* lnb = (const float*)d_in[14];
    const float* Wl  = (const float*)d_in[15];
    const float* bl  = (const float*)d_in[16];
    float* out = (float*)d_out;

    const int n = in_sizes[0] / 128;
    const int E = in_sizes[1] / 2;

    float* qkvs  = (float*)d_ws;                    // n*2560
    float* wsum  = qkvs + (size_t)n * 2560;         // n*512 (reused as normed)
    float* vacc  = wsum + (size_t)n * 512;          // n*512 (becomes agg in place)
    float* alpha = vacc + (size_t)n * 512;          // E*4
    float* WqeT  = alpha + (size_t)E * 4;           // 128*512
    float* bqe   = WqeT + 128 * 512;                // 512
    int* deg       = (int*)(bqe + 512);
    int* row_start = deg + n;
    int* cursor    = row_start + n + 1;
    int* csr_eid   = cursor + n;
    int* csr_src   = csr_eid + E;

    hipMemsetAsync(deg, 0, (size_t)n * sizeof(int), stream);

    wqe_k<<<258, 256, 0, stream>>>(Wq, bq, We, WqeT, bqe);
    dim3 g1((n + 63) / 64, 40);
    node_gemm_k<<<g1, 256, 0, stream>>>(x, Wq, bq, Wk, bk, Wv, bv, Wsk, bsk, WqeT, bqe, qkvs, n);
    deg_count_k<<<(E + 255) / 256, 256, 0, stream>>>(ei + E, deg, E);
    scan_k<<<1, 1024, 0, stream>>>(deg, row_start, cursor, n);
    scatter_k<<<(E + 255) / 256, 256, 0, stream>>>(ei, cursor, csr_eid, csr_src, E);
    edge_k<<<(n + 3) / 4, 256, 0, stream>>>(qkvs, ea, be, row_start, csr_eid, csr_src,
                                            alpha, wsum, vacc, n);
    dim3 g6((n + 63) / 64, 8);
    final_gemm_k<<<g6, 256, 0, stream>>>(wsum, We, be, row_start, vacc, n);
    ln_k<<<n, 256, 0, stream>>>(vacc, qkvs, lng, lnb, wsum, n);
    dim3 g8((n + 63) / 64, 2);
    out_gemm_k<<<g8, 256, 0, stream>>>(wsum, Wl, bl, x, out, n);
}

// Round 3
// 278.470 us; speedup vs baseline: 5.3612x; 1.9092x over previous
//
#include <hip/hip_runtime.h>
#include <math.h>

// UniMP / TransformerConv block. bf16-MFMA GEMMs, f32 edge phase.
//   alpha = (q.k + ea.qe + q.be)/sqrt(D),  qe = x @ (Wq We^T per head)
//   agg   = sum attn*v[src] + (sum attn*ea) @ We_h + be_h
// qkvs layout per node: [q 512 | k 512 | v 512 | skip 512 | qe 512] stride 2560

typedef short bf16x8 __attribute__((ext_vector_type(8)));
typedef float f32x4 __attribute__((ext_vector_type(4)));

__device__ inline unsigned short f2bf(float f) {
    union { float f; unsigned u; } v; v.f = f;
    unsigned r = (v.u + 0x7FFFu + ((v.u >> 16) & 1u)) >> 16;
    return (unsigned short)r;
}

// ---------------- K0: WqeT[m,hc] = sum_d Wq[m,hd]*We[c,hd]; bqe[hc] = sum_d bq[hd]*We[c,hd]
__global__ __launch_bounds__(256) void wqe_k(
    const float* __restrict__ Wq, const float* __restrict__ bq,
    const float* __restrict__ We,
    float* __restrict__ WqeT, float* __restrict__ bqe)
{
    const int b = blockIdx.x;
    if (b < 256) {
        const int gid = b * 256 + threadIdx.x;      // 0..65535
        const int m = gid >> 9, hc = gid & 511;
        const int h = hc >> 7, c = hc & 127;
        const float* wq = &Wq[(size_t)m * 512 + h * 128];
        const float* we = &We[(size_t)c * 512 + h * 128];
        float s0 = 0.f, s1 = 0.f;
        #pragma unroll 8
        for (int d = 0; d < 128; d += 2) { s0 += wq[d] * we[d]; s1 += wq[d + 1] * we[d + 1]; }
        WqeT[(size_t)m * 512 + hc] = s0 + s1;
    } else {
        const int hc = (b - 256) * 256 + threadIdx.x;
        const int h = hc >> 7, c = hc & 127;
        const float* we = &We[(size_t)c * 512 + h * 128];
        const float* bb = &bq[h * 128];
        float s = 0.f;
        #pragma unroll 8
        for (int d = 0; d < 128; ++d) s += bb[d] * we[d];
        bqe[hc] = s;
    }
}

// ---------------- K0b: bf16 conversions + fragment-ready weight layouts ----------------
// Fragment layout for mfma_f32_16x16x32_bf16 B-operand: for tile (nt: 16 cols, kt: 32 k),
// lane l holds B[k = kt*32+(l>>4)*8+j][col = nt*16+(l&15)], j=0..7 contiguous (16B).
__global__ __launch_bounds__(256) void prep_k(
    const float* __restrict__ x,
    const float* __restrict__ Wq, const float* __restrict__ bq,
    const float* __restrict__ Wk, const float* __restrict__ bk,
    const float* __restrict__ Wv, const float* __restrict__ bv,
    const float* __restrict__ Ws, const float* __restrict__ bs,
    const float* __restrict__ WqeT, const float* __restrict__ bqe,
    const float* __restrict__ We, const float* __restrict__ Wlin,
    unsigned short* __restrict__ x_bf, unsigned short* __restrict__ Wfrag,
    unsigned short* __restrict__ Wefrag, unsigned short* __restrict__ Wlfrag,
    float* __restrict__ bcat, int n, int nb1)
{
    const int b = blockIdx.x, t = threadIdx.x;
    if (b < nb1) {                                  // x -> bf16, 4 elems/thread
        int i = (b * 256 + t) * 4;
        if (i < n * 128) {
            float4 v = *(const float4*)&x[i];
            unsigned short o[4] = { f2bf(v.x), f2bf(v.y), f2bf(v.z), f2bf(v.w) };
            *(uint2*)&x_bf[i] = *(uint2*)o;
        }
    } else if (b < nb1 + 160) {                     // Wfrag: [q|k|v|skip|qe] 128x2560
        int g = (b - nb1) * 256 + t;                // (nt*4+kt)*64+lane, nt<160
        int lane = g & 63, kt = (g >> 6) & 3, nt = g >> 8;
        int ncol = nt * 16 + (lane & 15);
        int k0 = kt * 32 + ((lane >> 4) << 3);
        const float* W; int c;
        if      (ncol < 512)  { W = Wq;   c = ncol; }
        else if (ncol < 1024) { W = Wk;   c = ncol - 512; }
        else if (ncol < 1536) { W = Wv;   c = ncol - 1024; }
        else if (ncol < 2048) { W = Ws;   c = ncol - 1536; }
        else                  { W = WqeT; c = ncol - 2048; }
        unsigned short o[8];
        #pragma unroll
        for (int j = 0; j < 8; ++j) o[j] = f2bf(W[(size_t)(k0 + j) * 512 + c]);
        *(uint4*)&Wfrag[(size_t)g * 8] = *(uint4*)o;
    } else if (b < nb1 + 192) {                     // Wefrag: We 128x512
        int g = (b - nb1 - 160) * 256 + t;          // nt<32, kt<4
        int lane = g & 63, kt = (g >> 6) & 3, nt = g >> 8;
        int ncol = nt * 16 + (lane & 15);
        int k0 = kt * 32 + ((lane >> 4) << 3);
        unsigned short o[8];
        #pragma unroll
        for (int j = 0; j < 8; ++j) o[j] = f2bf(We[(size_t)(k0 + j) * 512 + ncol]);
        *(uint4*)&Wefrag[(size_t)g * 8] = *(uint4*)o;
    } else if (b < nb1 + 224) {                     // Wlfrag: Wlin 512x128
        int g = (b - nb1 - 192) * 256 + t;          // (nt*16+kt)*64+lane, nt<8, kt<16
        int lane = g & 63, kt = (g >> 6) & 15, nt = g >> 10;
        int ncol = nt * 16 + (lane & 15);
        int k0 = kt * 32 + ((lane >> 4) << 3);
        unsigned short o[8];
        #pragma unroll
        for (int j = 0; j < 8; ++j) o[j] = f2bf(Wlin[(size_t)(k0 + j) * 128 + ncol]);
        *(uint4*)&Wlfrag[(size_t)g * 8] = *(uint4*)o;
    } else {                                        // bcat[2560]
        int c = (b - nb1 - 224) * 256 + t;
        if (c < 2560)
            bcat[c] = (c < 512) ? bq[c] : (c < 1024) ? bk[c - 512] : (c < 1536) ? bv[c - 1024]
                     : (c < 2048) ? bs[c - 1536] : bqe[c - 2048];
    }
}

// ---------------- K1: qkvs = x @ [Wq|Wk|Wv|Wskip|WqeT] + bcat (bf16 MFMA, no LDS) ---------
__global__ __launch_bounds__(256) void node_gemm_mfma(
    const unsigned short* __restrict__ x_bf, const unsigned short* __restrict__ Wfrag,
    const float* __restrict__ bcat, float* __restrict__ qkvs, int n)
{
    const int t = threadIdx.x, lane = t & 63, w = t >> 6;
    const int m0 = blockIdx.x * 64 + (w >> 1) * 32;
    const int n0 = blockIdx.y * 64 + (w & 1) * 32;
    const int lr = lane & 15, lk = (lane >> 4) << 3;
    f32x4 acc[2][2] = {};
    #pragma unroll
    for (int kt = 0; kt < 4; ++kt) {
        bf16x8 a[2], bf[2];
        #pragma unroll
        for (int mi = 0; mi < 2; ++mi) {
            int row = m0 + mi * 16 + lr; row = row < n ? row : n - 1;
            a[mi] = *(const bf16x8*)&x_bf[(size_t)row * 128 + kt * 32 + lk];
        }
        #pragma unroll
        for (int ni = 0; ni < 2; ++ni) {
            int nt = (n0 + ni * 16) >> 4;
            bf[ni] = *(const bf16x8*)&Wfrag[(size_t)((nt * 4 + kt) * 64 + lane) * 8];
        }
        #pragma unroll
        for (int mi = 0; mi < 2; ++mi)
            #pragma unroll
            for (int ni = 0; ni < 2; ++ni)
                acc[mi][ni] = __builtin_amdgcn_mfma_f32_16x16x32_bf16(a[mi], bf[ni], acc[mi][ni], 0, 0, 0);
    }
    #pragma unroll
    for (int mi = 0; mi < 2; ++mi)
        #pragma unroll
        for (int j = 0; j < 4; ++j) {
            int row = m0 + mi * 16 + (lane >> 4) * 4 + j;
            if (row < n) {
                #pragma unroll
                for (int ni = 0; ni < 2; ++ni) {
                    int col = n0 + ni * 16 + lr;
                    qkvs[(size_t)row * 2560 + col] = acc[mi][ni][j] + bcat[col];
                }
            }
        }
}

// ---------------- CSR build ----------------
__global__ void deg_count_k(const int* __restrict__ dst, int* __restrict__ deg, int E)
{
    int e = blockIdx.x * 256 + threadIdx.x;
    if (e < E) atomicAdd(&deg[dst[e]], 1);
}

__global__ __launch_bounds__(1024) void scan_k(const int* __restrict__ deg,
                                               int* __restrict__ row_start,
                                               int* __restrict__ cursor, int n)
{
    __shared__ int part[1024];
    const int t = threadIdx.x;
    const int c0 = t * 16;                  // supports n <= 16384
    int loc[16];
    int s = 0;
    #pragma unroll
    for (int i = 0; i < 16; ++i) {
        int idx = c0 + i;
        int dv = (idx < n) ? deg[idx] : 0;
        loc[i] = s; s += dv;
    }
    part[t] = s;
    __syncthreads();
    int incl = s;
    for (int off = 1; off < 1024; off <<= 1) {
        int other = (t >= off) ? part[t - off] : 0;
        __syncthreads();
        incl += other;
        part[t] = incl;
        __syncthreads();
    }
    const int base = incl - s;
    #pragma unroll
    for (int i = 0; i < 16; ++i) {
        int idx = c0 + i;
        if (idx < n) { row_start[idx] = base + loc[i]; cursor[idx] = base + loc[i]; }
    }
    if (t == 1023) row_start[n] = incl;
}

__global__ void scatter_k(const int* __restrict__ ei, int* __restrict__ cursor,
                          int* __restrict__ csr_eid, int* __restrict__ csr_src, int E)
{
    int e = blockIdx.x * 256 + threadIdx.x;
    if (e < E) {
        int dnode = ei[E + e];
        int p = atomicAdd(&cursor[dnode], 1);
        csr_eid[p] = e;
        csr_src[p] = ei[e];
    }
}

// ---------------- K5: per-node edge phase (one wave per node, all 4 heads) ----------------
__global__ __launch_bounds__(256) void edge_k(
    const float* __restrict__ qkvs, const float* __restrict__ ea,
    const float* __restrict__ be,
    const int* __restrict__ row_start, const int* __restrict__ csr_eid,
    const int* __restrict__ csr_src,
    float* __restrict__ alpha, unsigned short* __restrict__ wsum_bf,
    float* __restrict__ vacc, int n)
{
    const int t = threadIdx.x;
    const int lane = t & 63;
    const int node = blockIdx.x * 4 + (t >> 6);
    if (node >= n) return;
    const int rs = row_start[node];
    const int deg = row_start[node + 1] - rs;
    const int c2 = lane * 2;
    const float s = 0.08838834764831845f;   // 1/sqrt(128)
    const size_t nb = (size_t)node * 2560;

    float2 q2[4], qe2[4];
    #pragma unroll
    for (int h = 0; h < 4; ++h) {
        float2 a = *(const float2*)&qkvs[nb + h * 128 + c2];
        q2[h] = make_float2(a.x * s, a.y * s);
        float2 b = *(const float2*)&qkvs[nb + 2048 + h * 128 + c2];
        qe2[h] = make_float2(b.x * s, b.y * s);
    }
    float4 qbe;
    {
        float p[4];
        #pragma unroll
        for (int h = 0; h < 4; ++h) {
            float2 b2 = *(const float2*)&be[h * 128 + c2];
            p[h] = q2[h].x * b2.x + q2[h].y * b2.y;
        }
        #pragma unroll
        for (int o = 32; o > 0; o >>= 1) {
            p[0] += __shfl_xor(p[0], o); p[1] += __shfl_xor(p[1], o);
            p[2] += __shfl_xor(p[2], o); p[3] += __shfl_xor(p[3], o);
        }
        qbe = make_float4(p[0], p[1], p[2], p[3]);
    }

    float m4[4] = {-3e38f, -3e38f, -3e38f, -3e38f};
    float den4[4] = {0.f, 0.f, 0.f, 0.f};

    // ---- pass 1 ----
    for (int j0 = 0; j0 < deg; j0 += 64) {
        const int cnt = min(64, deg - j0);
        int my_eid = 0, my_src = 0;
        if (lane < cnt) { my_eid = csr_eid[rs + j0 + lane]; my_src = csr_src[rs + j0 + lane]; }
        for (int jj = 0; jj < cnt; ++jj) {
            const int eid = __shfl(my_eid, jj);
            const int src = __shfl(my_src, jj);
            const float2 eav = *(const float2*)&ea[(size_t)eid * 128 + c2];
            const size_t sb = (size_t)src * 2560 + 512;
            float p[4];
            #pragma unroll
            for (int h = 0; h < 4; ++h) {
                float2 k2 = *(const float2*)&qkvs[sb + h * 128 + c2];
                p[h] = q2[h].x * k2.x + q2[h].y * k2.y
                     + qe2[h].x * eav.x + qe2[h].y * eav.y;
            }
            #pragma unroll
            for (int o = 32; o > 0; o >>= 1) {
                p[0] += __shfl_xor(p[0], o); p[1] += __shfl_xor(p[1], o);
                p[2] += __shfl_xor(p[2], o); p[3] += __shfl_xor(p[3], o);
            }
            p[0] += qbe.x; p[1] += qbe.y; p[2] += qbe.z; p[3] += qbe.w;
            if (lane < 4) {
                float av = (lane == 0) ? p[0] : (lane == 1) ? p[1] : (lane == 2) ? p[2] : p[3];
                alpha[(size_t)(rs + j0 + jj) * 4 + lane] = av;
            }
            #pragma unroll
            for (int h = 0; h < 4; ++h) {
                float nm = fmaxf(m4[h], p[h]);
                den4[h] = den4[h] * expf(m4[h] - nm) + expf(p[h] - nm);
                m4[h] = nm;
            }
        }
    }
    float rden[4];
    #pragma unroll
    for (int h = 0; h < 4; ++h) rden[h] = (den4[h] > 0.f) ? 1.f / den4[h] : 0.f;

    // ---- pass 2 ----
    float2 ws2[4] = {{0,0},{0,0},{0,0},{0,0}};
    float2 va2[4] = {{0,0},{0,0},{0,0},{0,0}};
    for (int j0 = 0; j0 < deg; j0 += 64) {
        const int cnt = min(64, deg - j0);
        int my_eid = 0, my_src = 0;
        if (lane < cnt) { my_eid = csr_eid[rs + j0 + lane]; my_src = csr_src[rs + j0 + lane]; }
        for (int jj = 0; jj < cnt; ++jj) {
            const int eid = __shfl(my_eid, jj);
            const int src = __shfl(my_src, jj);
            const float4 a4 = *(const float4*)&alpha[(size_t)(rs + j0 + jj) * 4];
            float w[4];
            w[0] = expf(a4.x - m4[0]) * rden[0];
            w[1] = expf(a4.y - m4[1]) * rden[1];
            w[2] = expf(a4.z - m4[2]) * rden[2];
            w[3] = expf(a4.w - m4[3]) * rden[3];
            const float2 eav = *(const float2*)&ea[(size_t)eid * 128 + c2];
            const size_t sb = (size_t)src * 2560 + 1024;
            #pragma unroll
            for (int h = 0; h < 4; ++h) {
                float2 v2 = *(const float2*)&qkvs[sb + h * 128 + c2];
                va2[h].x += w[h] * v2.x; va2[h].y += w[h] * v2.y;
                ws2[h].x += w[h] * eav.x; ws2[h].y += w[h] * eav.y;
            }
        }
    }
    #pragma unroll
    for (int h = 0; h < 4; ++h) {
        unsigned short o[2] = { f2bf(ws2[h].x), f2bf(ws2[h].y) };
        *(unsigned int*)&wsum_bf[(size_t)node * 512 + h * 128 + c2] = *(unsigned int*)o;
        *(float2*)&vacc[(size_t)node * 512 + h * 128 + c2] = va2[h];
    }
}

// ---------------- K6: agg = vacc + wsum@We_h + hb*be + skip (bf16 MFMA) ----------------
__global__ __launch_bounds__(256) void final_gemm_mfma(
    const unsigned short* __restrict__ wsum_bf, const unsigned short* __restrict__ Wefrag,
    const float* __restrict__ be, const float* __restrict__ vacc,
    const float* __restrict__ qkvs, const int* __restrict__ row_start,
    float* __restrict__ agg, int n)
{
    const int t = threadIdx.x, lane = t & 63, w = t >> 6;
    const int m0 = blockIdx.x * 64 + (w >> 1) * 32;
    const int n0 = blockIdx.y * 64 + (w & 1) * 32;
    const int h = (blockIdx.y * 64) >> 7;
    const int lr = lane & 15, lk = (lane >> 4) << 3;
    f32x4 acc[2][2] = {};
    #pragma unroll
    for (int kt = 0; kt < 4; ++kt) {
        bf16x8 a[2], bf[2];
        #pragma unroll
        for (int mi = 0; mi < 2; ++mi) {
            int row = m0 + mi * 16 + lr; row = row < n ? row : n - 1;
            a[mi] = *(const bf16x8*)&wsum_bf[(size_t)row * 512 + h * 128 + kt * 32 + lk];
        }
        #pragma unroll
        for (int ni = 0; ni < 2; ++ni) {
            int nt = (n0 + ni * 16) >> 4;
            bf[ni] = *(const bf16x8*)&Wefrag[(size_t)((nt * 4 + kt) * 64 + lane) * 8];
        }
        #pragma unroll
        for (int mi = 0; mi < 2; ++mi)
            #pragma unroll
            for (int ni = 0; ni < 2; ++ni)
                acc[mi][ni] = __builtin_amdgcn_mfma_f32_16x16x32_bf16(a[mi], bf[ni], acc[mi][ni], 0, 0, 0);
    }
    #pragma unroll
    for (int mi = 0; mi < 2; ++mi)
        #pragma unroll
        for (int j = 0; j < 4; ++j) {
            int row = m0 + mi * 16 + (lane >> 4) * 4 + j;
            if (row < n) {
                const float hb = (row_start[row + 1] > row_start[row]) ? 1.f : 0.f;
                #pragma unroll
                for (int ni = 0; ni < 2; ++ni) {
                    int col = n0 + ni * 16 + lr;
                    agg[(size_t)row * 512 + col] = acc[mi][ni][j] + vacc[(size_t)row * 512 + col]
                        + hb * be[col] + qkvs[(size_t)row * 2560 + 1536 + col];
                }
            }
        }
}

// ---------------- K7: LayerNorm(agg) -> normed_bf ----------------
__global__ __launch_bounds__(256) void ln_k(
    const float* __restrict__ agg, const float* __restrict__ g, const float* __restrict__ b,
    unsigned short* __restrict__ normed_bf, int n)
{
    const int node = blockIdx.x;
    const int t = threadIdx.x;
    const float y0 = agg[(size_t)node * 512 + t];
    const float y1 = agg[(size_t)node * 512 + 256 + t];
    __shared__ float rs_s[4];
    float s = y0 + y1;
    #pragma unroll
    for (int o = 32; o > 0; o >>= 1) s += __shfl_xor(s, o);
    if ((t & 63) == 0) rs_s[t >> 6] = s;
    __syncthreads();
    const float mu = (rs_s[0] + rs_s[1] + rs_s[2] + rs_s[3]) * (1.f / 512.f);
    const float d0 = y0 - mu, d1 = y1 - mu;
    float s2 = d0 * d0 + d1 * d1;
    __syncthreads();
    #pragma unroll
    for (int o = 32; o > 0; o >>= 1) s2 += __shfl_xor(s2, o);
    if ((t & 63) == 0) rs_s[t >> 6] = s2;
    __syncthreads();
    const float var = (rs_s[0] + rs_s[1] + rs_s[2] + rs_s[3]) * (1.f / 512.f);
    const float rstd = rsqrtf(var + 1e-5f);
    normed_bf[(size_t)node * 512 + t]       = f2bf(d0 * rstd * g[t] + b[t]);
    normed_bf[(size_t)node * 512 + 256 + t] = f2bf(d1 * rstd * g[256 + t] + b[256 + t]);
}

// ---------------- K8: out = elu(normed @ Wlin + blin + x) (bf16 MFMA) ----------------
__global__ __launch_bounds__(256) void out_gemm_mfma(
    const unsigned short* __restrict__ normed_bf, const unsigned short* __restrict__ Wlfrag,
    const float* __restrict__ blin, const float* __restrict__ x,
    float* __restrict__ out, int n)
{
    const int t = threadIdx.x, lane = t & 63, w = t >> 6;
    const int m0 = blockIdx.x * 64 + (w >> 1) * 32;
    const int n0 = blockIdx.y * 64 + (w & 1) * 32;
    const int lr = lane & 15, lk = (lane >> 4) << 3;
    f32x4 acc[2][2] = {};
    #pragma unroll
    for (int kt = 0; kt < 16; ++kt) {
        bf16x8 a[2], bf[2];
        #pragma unroll
        for (int mi = 0; mi < 2; ++mi) {
            int row = m0 + mi * 16 + lr; row = row < n ? row : n - 1;
            a[mi] = *(const bf16x8*)&normed_bf[(size_t)row * 512 + kt * 32 + lk];
        }
        #pragma unroll
        for (int ni = 0; ni < 2; ++ni) {
            int nt = (n0 + ni * 16) >> 4;
            bf[ni] = *(const bf16x8*)&Wlfrag[(size_t)((nt * 16 + kt) * 64 + lane) * 8];
        }
        #pragma unroll
        for (int mi = 0; mi < 2; ++mi)
            #pragma unroll
            for (int ni = 0; ni < 2; ++ni)
                acc[mi][ni] = __builtin_amdgcn_mfma_f32_16x16x32_bf16(a[mi], bf[ni], acc[mi][ni], 0, 0, 0);
    }
    #pragma unroll
    for (int mi = 0; mi < 2; ++mi)
        #pragma unroll
        for (int j = 0; j < 4; ++j) {
            int row = m0 + mi * 16 + (lane >> 4) * 4 + j;
            if (row < n) {
                #pragma unroll
                for (int ni = 0; ni < 2; ++ni) {
                    int col = n0 + ni * 16 + lr;
                    float z = acc[mi][ni][j] + blin[col] + x[(size_t)row * 128 + col];
                    out[(size_t)row * 128 + col] = z > 0.f ? z : expm1f(z);
                }
            }
        }
}

extern "C" void kernel_launch(void* const* d_in, const int* in_sizes, int n_in,
                              void* d_out, int out_size, void* d_ws, size_t ws_size,
                              hipStream_t stream)
{
    const float* x   = (const float*)d_in[0];
    const int*   ei  = (const int*)d_in[1];
    const float* ea  = (const float*)d_in[2];
    const float* Wq  = (const float*)d_in[3];
    const float* bq  = (const float*)d_in[4];
    const float* Wk  = (const float*)d_in[5];
    const float* bk  = (const float*)d_in[6];
    const float* Wv  = (const float*)d_in[7];
    const float* bv  = (const float*)d_in[8];
    const float* We  = (const float*)d_in[9];
    const float* be  = (const float*)d_in[10];
    const float* Wsk = (const float*)d_in[11];
    const float* bsk = (const float*)d_in[12];
    const float* lng = (const float*)d_in[13];
    const float* lnb = (const float*)d_in[14];
    const float* Wl  = (const float*)d_in[15];
    const float* bl  = (const float*)d_in[16];
    float* out = (float*)d_out;

    const int n = in_sizes[0] / 128;
    const int E = in_sizes[1] / 2;

    float* qkvs  = (float*)d_ws;                    // n*2560
    float* vacc  = qkvs + (size_t)n * 2560;         // n*512
    float* alpha = vacc + (size_t)n * 512;          // E*4
    float* WqeT  = alpha + (size_t)E * 4;           // 128*512
    float* bqe   = WqeT + 128 * 512;                // 512
    float* bcat  = bqe + 512;                       // 2560
    unsigned short* x_bf    = (unsigned short*)(bcat + 2560);   // n*128
    unsigned short* wsum_bf = x_bf + (size_t)n * 128;           // n*512 (reused as normed)
    unsigned short* Wfrag   = wsum_bf + (size_t)n * 512;        // 128*2560
    unsigned short* Wefrag  = Wfrag + 128 * 2560;               // 128*512
    unsigned short* Wlfrag  = Wefrag + 128 * 512;               // 512*128
    int* deg       = (int*)(Wlfrag + 512 * 128);
    int* row_start = deg + n;
    int* cursor    = row_start + n + 1;
    int* csr_eid   = cursor + n;
    int* csr_src   = csr_eid + E;

    hipMemsetAsync(deg, 0, (size_t)n * sizeof(int), stream);

    wqe_k<<<258, 256, 0, stream>>>(Wq, bq, We, WqeT, bqe);
    const int nb1 = (n * 32 + 255) / 256;           // x-conversion blocks (4 elems/thread)
    prep_k<<<nb1 + 234, 256, 0, stream>>>(x, Wq, bq, Wk, bk, Wv, bv, Wsk, bsk, WqeT, bqe,
                                          We, Wl, x_bf, Wfrag, Wefrag, Wlfrag, bcat, n, nb1);
    dim3 g1((n + 63) / 64, 40);
    node_gemm_mfma<<<g1, 256, 0, stream>>>(x_bf, Wfrag, bcat, qkvs, n);
    deg_count_k<<<(E + 255) / 256, 256, 0, stream>>>(ei + E, deg, E);
    scan_k<<<1, 1024, 0, stream>>>(deg, row_start, cursor, n);
    scatter_k<<<(E + 255) / 256, 256, 0, stream>>>(ei, cursor, csr_eid, csr_src, E);
    edge_k<<<(n + 3) / 4, 256, 0, stream>>>(qkvs, ea, be, row_start, csr_eid, csr_src,
                                            alpha, wsum_bf, vacc, n);
    dim3 g6((n + 63) / 64, 8);
    final_gemm_mfma<<<g6, 256, 0, stream>>>(wsum_bf, Wefrag, be, vacc, qkvs, row_start, vacc, n);
    ln_k<<<n, 256, 0, stream>>>(vacc, lng, lnb, wsum_bf, n);
    dim3 g8((n + 63) / 64, 2);
    out_gemm_mfma<<<g8, 256, 0, stream>>>(wsum_bf, Wlfrag, bl, x, out, n);
}

// Round 4
// 212.928 us; speedup vs baseline: 7.0115x; 1.3078x over previous
//
#include <hip/hip_runtime.h>
#include <math.h>

// UniMP / TransformerConv block. bf16-MFMA GEMMs, single-pass flash-style edge phase.
//   alpha = (q.k + ea.qe + q.be)/sqrt(D),  qe = x @ (Wq We^T per head)
//   agg   = sum attn*v[src] + (sum attn*ea) @ We_h + be_h
// Node tensors: qs f32 [n][1024] = [q|skip], kvq bf16 [n][1536] = [k|v|qe]

typedef short bf16x8 __attribute__((ext_vector_type(8)));
typedef unsigned short u16x8 __attribute__((ext_vector_type(8)));
typedef float f32x4 __attribute__((ext_vector_type(4)));

__device__ inline unsigned short f2bf(float f) {
    union { float f; unsigned u; } v; v.f = f;
    unsigned r = (v.u + 0x7FFFu + ((v.u >> 16) & 1u)) >> 16;
    return (unsigned short)r;
}
__device__ inline float bf2f(unsigned short u) {
    union { unsigned u; float f; } v; v.u = ((unsigned)u) << 16; return v.f;
}

// ---------------- K0: WqeT[m,hc] = sum_d Wq[m,hd]*We[c,hd]; bqe[hc] = sum_d bq[hd]*We[c,hd]
__global__ __launch_bounds__(256) void wqe_k(
    const float* __restrict__ Wq, const float* __restrict__ bq,
    const float* __restrict__ We,
    float* __restrict__ WqeT, float* __restrict__ bqe)
{
    const int b = blockIdx.x;
    if (b < 256) {
        const int gid = b * 256 + threadIdx.x;      // 0..65535
        const int m = gid >> 9, hc = gid & 511;
        const int h = hc >> 7, c = hc & 127;
        const float* wq = &Wq[(size_t)m * 512 + h * 128];
        const float* we = &We[(size_t)c * 512 + h * 128];
        float s0 = 0.f, s1 = 0.f;
        #pragma unroll 8
        for (int d = 0; d < 128; d += 2) { s0 += wq[d] * we[d]; s1 += wq[d + 1] * we[d + 1]; }
        WqeT[(size_t)m * 512 + hc] = s0 + s1;
    } else {
        const int hc = (b - 256) * 256 + threadIdx.x;
        const int h = hc >> 7, c = hc & 127;
        const float* we = &We[(size_t)c * 512 + h * 128];
        const float* bb = &bq[h * 128];
        float s = 0.f;
        #pragma unroll 8
        for (int d = 0; d < 128; ++d) s += bb[d] * we[d];
        bqe[hc] = s;
    }
}

// ---------------- K0b: bf16 conversions + fragment-ready weight layouts ----------------
__global__ __launch_bounds__(256) void prep_k(
    const float* __restrict__ x,
    const float* __restrict__ Wq, const float* __restrict__ bq,
    const float* __restrict__ Wk, const float* __restrict__ bk,
    const float* __restrict__ Wv, const float* __restrict__ bv,
    const float* __restrict__ Ws, const float* __restrict__ bs,
    const float* __restrict__ WqeT, const float* __restrict__ bqe,
    const float* __restrict__ We, const float* __restrict__ Wlin,
    unsigned short* __restrict__ x_bf, unsigned short* __restrict__ Wfrag,
    unsigned short* __restrict__ Wefrag, unsigned short* __restrict__ Wlfrag,
    float* __restrict__ bcat, int n, int nb1)
{
    const int b = blockIdx.x, t = threadIdx.x;
    if (b < nb1) {                                  // x -> bf16, 4 elems/thread
        int i = (b * 256 + t) * 4;
        if (i < n * 128) {
            float4 v = *(const float4*)&x[i];
            unsigned short o[4] = { f2bf(v.x), f2bf(v.y), f2bf(v.z), f2bf(v.w) };
            *(uint2*)&x_bf[i] = *(uint2*)o;
        }
    } else if (b < nb1 + 160) {                     // Wfrag: [q|k|v|skip|qe] 128x2560
        int g = (b - nb1) * 256 + t;                // (nt*4+kt)*64+lane, nt<160
        int lane = g & 63, kt = (g >> 6) & 3, nt = g >> 8;
        int ncol = nt * 16 + (lane & 15);
        int k0 = kt * 32 + ((lane >> 4) << 3);
        const float* W; int c;
        if      (ncol < 512)  { W = Wq;   c = ncol; }
        else if (ncol < 1024) { W = Wk;   c = ncol - 512; }
        else if (ncol < 1536) { W = Wv;   c = ncol - 1024; }
        else if (ncol < 2048) { W = Ws;   c = ncol - 1536; }
        else                  { W = WqeT; c = ncol - 2048; }
        unsigned short o[8];
        #pragma unroll
        for (int j = 0; j < 8; ++j) o[j] = f2bf(W[(size_t)(k0 + j) * 512 + c]);
        *(uint4*)&Wfrag[(size_t)g * 8] = *(uint4*)o;
    } else if (b < nb1 + 192) {                     // Wefrag: We 128x512
        int g = (b - nb1 - 160) * 256 + t;          // nt<32, kt<4
        int lane = g & 63, kt = (g >> 6) & 3, nt = g >> 8;
        int ncol = nt * 16 + (lane & 15);
        int k0 = kt * 32 + ((lane >> 4) << 3);
        unsigned short o[8];
        #pragma unroll
        for (int j = 0; j < 8; ++j) o[j] = f2bf(We[(size_t)(k0 + j) * 512 + ncol]);
        *(uint4*)&Wefrag[(size_t)g * 8] = *(uint4*)o;
    } else if (b < nb1 + 224) {                     // Wlfrag: Wlin 512x128
        int g = (b - nb1 - 192) * 256 + t;          // (nt*16+kt)*64+lane, nt<8, kt<16
        int lane = g & 63, kt = (g >> 6) & 15, nt = g >> 10;
        int ncol = nt * 16 + (lane & 15);
        int k0 = kt * 32 + ((lane >> 4) << 3);
        unsigned short o[8];
        #pragma unroll
        for (int j = 0; j < 8; ++j) o[j] = f2bf(Wlin[(size_t)(k0 + j) * 128 + ncol]);
        *(uint4*)&Wlfrag[(size_t)g * 8] = *(uint4*)o;
    } else {                                        // bcat[2560]
        int c = (b - nb1 - 224) * 256 + t;
        if (c < 2560)
            bcat[c] = (c < 512) ? bq[c] : (c < 1024) ? bk[c - 512] : (c < 1536) ? bv[c - 1024]
                     : (c < 2048) ? bs[c - 1536] : bqe[c - 2048];
    }
}

// ---------------- K1: [q|k|v|skip|qe] = x @ W + b (bf16 MFMA, no LDS) ----------------
// q,skip -> qs f32 [n][1024]; k,v,qe -> kvq bf16 [n][1536]
__global__ __launch_bounds__(256) void node_gemm_mfma(
    const unsigned short* __restrict__ x_bf, const unsigned short* __restrict__ Wfrag,
    const float* __restrict__ bcat, float* __restrict__ qs,
    unsigned short* __restrict__ kvq, int n)
{
    const int t = threadIdx.x, lane = t & 63, w = t >> 6;
    const int m0 = blockIdx.x * 64 + (w >> 1) * 32;
    const int n0 = blockIdx.y * 64 + (w & 1) * 32;
    const int lr = lane & 15, lk = (lane >> 4) << 3;
    f32x4 acc[2][2] = {};
    #pragma unroll
    for (int kt = 0; kt < 4; ++kt) {
        bf16x8 a[2], bf[2];
        #pragma unroll
        for (int mi = 0; mi < 2; ++mi) {
            int row = m0 + mi * 16 + lr; row = row < n ? row : n - 1;
            a[mi] = *(const bf16x8*)&x_bf[(size_t)row * 128 + kt * 32 + lk];
        }
        #pragma unroll
        for (int ni = 0; ni < 2; ++ni) {
            int nt = (n0 + ni * 16) >> 4;
            bf[ni] = *(const bf16x8*)&Wfrag[(size_t)((nt * 4 + kt) * 64 + lane) * 8];
        }
        #pragma unroll
        for (int mi = 0; mi < 2; ++mi)
            #pragma unroll
            for (int ni = 0; ni < 2; ++ni)
                acc[mi][ni] = __builtin_amdgcn_mfma_f32_16x16x32_bf16(a[mi], bf[ni], acc[mi][ni], 0, 0, 0);
    }
    #pragma unroll
    for (int mi = 0; mi < 2; ++mi)
        #pragma unroll
        for (int j = 0; j < 4; ++j) {
            int row = m0 + mi * 16 + (lane >> 4) * 4 + j;
            if (row < n) {
                #pragma unroll
                for (int ni = 0; ni < 2; ++ni) {
                    int col = n0 + ni * 16 + lr;
                    float val = acc[mi][ni][j] + bcat[col];
                    if (col < 512)        qs[(size_t)row * 1024 + col] = val;          // q
                    else if (col < 1536)  kvq[(size_t)row * 1536 + col - 512] = f2bf(val);  // k,v
                    else if (col < 2048)  qs[(size_t)row * 1024 + col - 1024] = val;   // skip
                    else                  kvq[(size_t)row * 1536 + col - 1024] = f2bf(val); // qe
                }
            }
        }
}

// ---------------- CSR build ----------------
__global__ void deg_count_k(const int* __restrict__ dst, int* __restrict__ deg, int E)
{
    int e = blockIdx.x * 256 + threadIdx.x;
    if (e < E) atomicAdd(&deg[dst[e]], 1);
}

__global__ __launch_bounds__(1024) void scan_k(const int* __restrict__ deg,
                                               int* __restrict__ row_start,
                                               int* __restrict__ cursor, int n)
{
    __shared__ int part[1024];
    const int t = threadIdx.x;
    const int c0 = t * 16;                  // supports n <= 16384
    int loc[16];
    int s = 0;
    #pragma unroll
    for (int i = 0; i < 16; ++i) {
        int idx = c0 + i;
        int dv = (idx < n) ? deg[idx] : 0;
        loc[i] = s; s += dv;
    }
    part[t] = s;
    __syncthreads();
    int incl = s;
    for (int off = 1; off < 1024; off <<= 1) {
        int other = (t >= off) ? part[t - off] : 0;
        __syncthreads();
        incl += other;
        part[t] = incl;
        __syncthreads();
    }
    const int base = incl - s;
    #pragma unroll
    for (int i = 0; i < 16; ++i) {
        int idx = c0 + i;
        if (idx < n) { row_start[idx] = base + loc[i]; cursor[idx] = base + loc[i]; }
    }
    if (t == 1023) row_start[n] = incl;
}

__global__ void scatter_k(const int* __restrict__ ei, int* __restrict__ cursor,
                          int2* __restrict__ csr, int E)
{
    int e = blockIdx.x * 256 + threadIdx.x;
    if (e < E) {
        int dnode = ei[E + e];
        int p = atomicAdd(&cursor[dnode], 1);
        csr[p] = make_int2(e, ei[e]);   // (eid, src)
    }
}

// ---------------- K5: single-pass flash-style edge phase ----------------
// One wave per node. 4 lane-groups x 16 lanes: group g owns head g, lane owns 8 dims.
__global__ __launch_bounds__(256) void edge_k(
    const float* __restrict__ qs, const unsigned short* __restrict__ kvq,
    const float* __restrict__ ea, const float* __restrict__ be,
    const int* __restrict__ row_start, const int2* __restrict__ csr,
    unsigned short* __restrict__ wsum_bf, float* __restrict__ vacc, int n)
{
    const int t = threadIdx.x;
    const int lane = t & 63;
    const int node = blockIdx.x * 4 + (t >> 6);
    if (node >= n) return;
    const int g = lane >> 4;            // head
    const int sl = (lane & 15) * 8;     // dim slice within head
    const int rs = row_start[node];
    const int deg = row_start[node + 1] - rs;
    const float s = 0.08838834764831845f;   // 1/sqrt(128)

    // per-lane scaled q, qe; group-uniform qbe = (q*s).be_h
    float q8[8], qe8[8];
    {
        const float* qp = &qs[(size_t)node * 1024 + g * 128 + sl];
        float4 a = *(const float4*)qp, b2 = *(const float4*)(qp + 4);
        q8[0]=a.x*s;  q8[1]=a.y*s;  q8[2]=a.z*s;  q8[3]=a.w*s;
        q8[4]=b2.x*s; q8[5]=b2.y*s; q8[6]=b2.z*s; q8[7]=b2.w*s;
        u16x8 u = *(const u16x8*)&kvq[(size_t)node * 1536 + 1024 + g * 128 + sl];
        #pragma unroll
        for (int i = 0; i < 8; ++i) qe8[i] = bf2f(u[i]) * s;
    }
    float qbe;
    {
        const float* bp = &be[g * 128 + sl];
        float pb = 0.f;
        #pragma unroll
        for (int i = 0; i < 8; ++i) pb += q8[i] * bp[i];
        #pragma unroll
        for (int o = 1; o <= 8; o <<= 1) pb += __shfl_xor(pb, o);
        qbe = pb;
    }

    float m = -3.0e38f, den = 0.f;
    float va[8] = {}, ws[8] = {};

    for (int j0 = 0; j0 < deg; j0 += 64) {
        const int cnt = min(64, deg - j0);
        int2 my = make_int2(0, 0);
        if (lane < cnt) my = csr[rs + j0 + lane];
        for (int jj = 0; jj < cnt; jj += 2) {
            const bool two = (jj + 1 < cnt);
            const int j1 = two ? jj + 1 : jj;
            const int eid0 = __shfl(my.x, jj), src0 = __shfl(my.y, jj);
            const int eid1 = __shfl(my.x, j1), src1 = __shfl(my.y, j1);
            // loads (independent chains)
            const float* ep0 = &ea[(size_t)eid0 * 128 + sl];
            const float* ep1 = &ea[(size_t)eid1 * 128 + sl];
            float ef0[8], ef1[8];
            #pragma unroll
            for (int i = 0; i < 8; ++i) { ef0[i] = ep0[i]; ef1[i] = ep1[i]; }
            const u16x8 k0 = *(const u16x8*)&kvq[(size_t)src0 * 1536 + g * 128 + sl];
            const u16x8 v0 = *(const u16x8*)&kvq[(size_t)src0 * 1536 + 512 + g * 128 + sl];
            const u16x8 k1 = *(const u16x8*)&kvq[(size_t)src1 * 1536 + g * 128 + sl];
            const u16x8 v1 = *(const u16x8*)&kvq[(size_t)src1 * 1536 + 512 + g * 128 + sl];
            float p0 = 0.f, p1 = 0.f;
            #pragma unroll
            for (int i = 0; i < 8; ++i) {
                p0 += q8[i] * bf2f(k0[i]) + qe8[i] * ef0[i];
                p1 += q8[i] * bf2f(k1[i]) + qe8[i] * ef1[i];
            }
            #pragma unroll
            for (int o = 1; o <= 8; o <<= 1) {
                p0 += __shfl_xor(p0, o);
                p1 += __shfl_xor(p1, o);
            }
            const float a0 = p0 + qbe;
            const float a1 = two ? (p1 + qbe) : -3.0e38f;   // dummy tail: w=0
            // online update, deferred-max (THR=8)
            if (a0 > m + 8.f) {
                const float sc = __expf(m - a0);
                den *= sc;
                #pragma unroll
                for (int i = 0; i < 8; ++i) { va[i] *= sc; ws[i] *= sc; }
                m = a0;
            }
            {
                const float w0 = __expf(a0 - m);
                den += w0;
                #pragma unroll
                for (int i = 0; i < 8; ++i) { va[i] += w0 * bf2f(v0[i]); ws[i] += w0 * ef0[i]; }
            }
            if (a1 > m + 8.f) {
                const float sc = __expf(m - a1);
                den *= sc;
                #pragma unroll
                for (int i = 0; i < 8; ++i) { va[i] *= sc; ws[i] *= sc; }
                m = a1;
            }
            {
                const float w1 = __expf(a1 - m);
                den += w1;
                #pragma unroll
                for (int i = 0; i < 8; ++i) { va[i] += w1 * bf2f(v1[i]); ws[i] += w1 * ef1[i]; }
            }
        }
    }

    const float rden = (den > 0.f) ? 1.f / den : 0.f;
    float4 o0, o1;
    o0.x = va[0]*rden; o0.y = va[1]*rden; o0.z = va[2]*rden; o0.w = va[3]*rden;
    o1.x = va[4]*rden; o1.y = va[5]*rden; o1.z = va[6]*rden; o1.w = va[7]*rden;
    float* vp = &vacc[(size_t)node * 512 + g * 128 + sl];
    *(float4*)vp = o0; *(float4*)(vp + 4) = o1;
    unsigned short wo[8];
    #pragma unroll
    for (int i = 0; i < 8; ++i) wo[i] = f2bf(ws[i] * rden);
    *(uint4*)&wsum_bf[(size_t)node * 512 + g * 128 + sl] = *(uint4*)wo;
}

// ---------------- K6: agg = vacc + wsum@We_h + hb*be + skip (bf16 MFMA) ----------------
__global__ __launch_bounds__(256) void final_gemm_mfma(
    const unsigned short* __restrict__ wsum_bf, const unsigned short* __restrict__ Wefrag,
    const float* __restrict__ be, const float* __restrict__ vacc,
    const float* __restrict__ qs, const int* __restrict__ row_start,
    float* __restrict__ agg, int n)
{
    const int t = threadIdx.x, lane = t & 63, w = t >> 6;
    const int m0 = blockIdx.x * 64 + (w >> 1) * 32;
    const int n0 = blockIdx.y * 64 + (w & 1) * 32;
    const int h = (blockIdx.y * 64) >> 7;
    const int lr = lane & 15, lk = (lane >> 4) << 3;
    f32x4 acc[2][2] = {};
    #pragma unroll
    for (int kt = 0; kt < 4; ++kt) {
        bf16x8 a[2], bf[2];
        #pragma unroll
        for (int mi = 0; mi < 2; ++mi) {
            int row = m0 + mi * 16 + lr; row = row < n ? row : n - 1;
            a[mi] = *(const bf16x8*)&wsum_bf[(size_t)row * 512 + h * 128 + kt * 32 + lk];
        }
        #pragma unroll
        for (int ni = 0; ni < 2; ++ni) {
            int nt = (n0 + ni * 16) >> 4;
            bf[ni] = *(const bf16x8*)&Wefrag[(size_t)((nt * 4 + kt) * 64 + lane) * 8];
        }
        #pragma unroll
        for (int mi = 0; mi < 2; ++mi)
            #pragma unroll
            for (int ni = 0; ni < 2; ++ni)
                acc[mi][ni] = __builtin_amdgcn_mfma_f32_16x16x32_bf16(a[mi], bf[ni], acc[mi][ni], 0, 0, 0);
    }
    #pragma unroll
    for (int mi = 0; mi < 2; ++mi)
        #pragma unroll
        for (int j = 0; j < 4; ++j) {
            int row = m0 + mi * 16 + (lane >> 4) * 4 + j;
            if (row < n) {
                const float hb = (row_start[row + 1] > row_start[row]) ? 1.f : 0.f;
                #pragma unroll
                for (int ni = 0; ni < 2; ++ni) {
                    int col = n0 + ni * 16 + lr;
                    agg[(size_t)row * 512 + col] = acc[mi][ni][j] + vacc[(size_t)row * 512 + col]
                        + hb * be[col] + qs[(size_t)row * 1024 + 512 + col];
                }
            }
        }
}

// ---------------- K7: LayerNorm(agg) -> normed_bf ----------------
__global__ __launch_bounds__(256) void ln_k(
    const float* __restrict__ agg, const float* __restrict__ g, const float* __restrict__ b,
    unsigned short* __restrict__ normed_bf, int n)
{
    const int node = blockIdx.x;
    const int t = threadIdx.x;
    const float y0 = agg[(size_t)node * 512 + t];
    const float y1 = agg[(size_t)node * 512 + 256 + t];
    __shared__ float rs_s[4];
    float s = y0 + y1;
    #pragma unroll
    for (int o = 32; o > 0; o >>= 1) s += __shfl_xor(s, o);
    if ((t & 63) == 0) rs_s[t >> 6] = s;
    __syncthreads();
    const float mu = (rs_s[0] + rs_s[1] + rs_s[2] + rs_s[3]) * (1.f / 512.f);
    const float d0 = y0 - mu, d1 = y1 - mu;
    float s2 = d0 * d0 + d1 * d1;
    __syncthreads();
    #pragma unroll
    for (int o = 32; o > 0; o >>= 1) s2 += __shfl_xor(s2, o);
    if ((t & 63) == 0) rs_s[t >> 6] = s2;
    __syncthreads();
    const float var = (rs_s[0] + rs_s[1] + rs_s[2] + rs_s[3]) * (1.f / 512.f);
    const float rstd = rsqrtf(var + 1e-5f);
    normed_bf[(size_t)node * 512 + t]       = f2bf(d0 * rstd * g[t] + b[t]);
    normed_bf[(size_t)node * 512 + 256 + t] = f2bf(d1 * rstd * g[256 + t] + b[256 + t]);
}

// ---------------- K8: out = elu(normed @ Wlin + blin + x) (bf16 MFMA) ----------------
__global__ __launch_bounds__(256) void out_gemm_mfma(
    const unsigned short* __restrict__ normed_bf, const unsigned short* __restrict__ Wlfrag,
    const float* __restrict__ blin, const float* __restrict__ x,
    float* __restrict__ out, int n)
{
    const int t = threadIdx.x, lane = t & 63, w = t >> 6;
    const int m0 = blockIdx.x * 64 + (w >> 1) * 32;
    const int n0 = blockIdx.y * 64 + (w & 1) * 32;
    const int lr = lane & 15, lk = (lane >> 4) << 3;
    f32x4 acc[2][2] = {};
    #pragma unroll
    for (int kt = 0; kt < 16; ++kt) {
        bf16x8 a[2], bf[2];
        #pragma unroll
        for (int mi = 0; mi < 2; ++mi) {
            int row = m0 + mi * 16 + lr; row = row < n ? row : n - 1;
            a[mi] = *(const bf16x8*)&normed_bf[(size_t)row * 512 + kt * 32 + lk];
        }
        #pragma unroll
        for (int ni = 0; ni < 2; ++ni) {
            int nt = (n0 + ni * 16) >> 4;
            bf[ni] = *(const bf16x8*)&Wlfrag[(size_t)((nt * 16 + kt) * 64 + lane) * 8];
        }
        #pragma unroll
        for (int mi = 0; mi < 2; ++mi)
            #pragma unroll
            for (int ni = 0; ni < 2; ++ni)
                acc[mi][ni] = __builtin_amdgcn_mfma_f32_16x16x32_bf16(a[mi], bf[ni], acc[mi][ni], 0, 0, 0);
    }
    #pragma unroll
    for (int mi = 0; mi < 2; ++mi)
        #pragma unroll
        for (int j = 0; j < 4; ++j) {
            int row = m0 + mi * 16 + (lane >> 4) * 4 + j;
            if (row < n) {
                #pragma unroll
                for (int ni = 0; ni < 2; ++ni) {
                    int col = n0 + ni * 16 + lr;
                    float z = acc[mi][ni][j] + blin[col] + x[(size_t)row * 128 + col];
                    out[(size_t)row * 128 + col] = z > 0.f ? z : expm1f(z);
                }
            }
        }
}

extern "C" void kernel_launch(void* const* d_in, const int* in_sizes, int n_in,
                              void* d_out, int out_size, void* d_ws, size_t ws_size,
                              hipStream_t stream)
{
    const float* x   = (const float*)d_in[0];
    const int*   ei  = (const int*)d_in[1];
    const float* ea  = (const float*)d_in[2];
    const float* Wq  = (const float*)d_in[3];
    const float* bq  = (const float*)d_in[4];
    const float* Wk  = (const float*)d_in[5];
    const float* bk  = (const float*)d_in[6];
    const float* Wv  = (const float*)d_in[7];
    const float* bv  = (const float*)d_in[8];
    const float* We  = (const float*)d_in[9];
    const float* be  = (const float*)d_in[10];
    const float* Wsk = (const float*)d_in[11];
    const float* bsk = (const float*)d_in[12];
    const float* lng = (const float*)d_in[13];
    const float* lnb = (const float*)d_in[14];
    const float* Wl  = (const float*)d_in[15];
    const float* bl  = (const float*)d_in[16];
    float* out = (float*)d_out;

    const int n = in_sizes[0] / 128;
    const int E = in_sizes[1] / 2;

    float* qs    = (float*)d_ws;                    // n*1024 (q | skip)
    float* vacc  = qs + (size_t)n * 1024;           // n*512
    float* WqeT  = vacc + (size_t)n * 512;          // 128*512
    float* bqe   = WqeT + 128 * 512;                // 512
    float* bcat  = bqe + 512;                       // 2560
    unsigned short* x_bf    = (unsigned short*)(bcat + 2560);   // n*128
    unsigned short* wsum_bf = x_bf + (size_t)n * 128;           // n*512 (reused as normed)
    unsigned short* kvq     = wsum_bf + (size_t)n * 512;        // n*1536 (k|v|qe)
    unsigned short* Wfrag   = kvq + (size_t)n * 1536;           // 128*2560
    unsigned short* Wefrag  = Wfrag + 128 * 2560;               // 128*512
    unsigned short* Wlfrag  = Wefrag + 128 * 512;               // 512*128
    int2* csr = (int2*)(((uintptr_t)(Wlfrag + 512 * 128) + 7) & ~(uintptr_t)7);  // E pairs
    int* deg       = (int*)(csr + E);
    int* row_start = deg + n;
    int* cursor    = row_start + n + 1;

    hipMemsetAsync(deg, 0, (size_t)n * sizeof(int), stream);

    wqe_k<<<258, 256, 0, stream>>>(Wq, bq, We, WqeT, bqe);
    const int nb1 = (n * 32 + 255) / 256;           // x-conversion blocks (4 elems/thread)
    prep_k<<<nb1 + 234, 256, 0, stream>>>(x, Wq, bq, Wk, bk, Wv, bv, Wsk, bsk, WqeT, bqe,
                                          We, Wl, x_bf, Wfrag, Wefrag, Wlfrag, bcat, n, nb1);
    dim3 g1((n + 63) / 64, 40);
    node_gemm_mfma<<<g1, 256, 0, stream>>>(x_bf, Wfrag, bcat, qs, kvq, n);
    deg_count_k<<<(E + 255) / 256, 256, 0, stream>>>(ei + E, deg, E);
    scan_k<<<1, 1024, 0, stream>>>(deg, row_start, cursor, n);
    scatter_k<<<(E + 255) / 256, 256, 0, stream>>>(ei, cursor, csr, E);
    edge_k<<<(n + 3) / 4, 256, 0, stream>>>(qs, kvq, ea, be, row_start, csr,
                                            wsum_bf, vacc, n);
    dim3 g6((n + 63) / 64, 8);
    final_gemm_mfma<<<g6, 256, 0, stream>>>(wsum_bf, Wefrag, be, vacc, qs, row_start, vacc, n);
    ln_k<<<n, 256, 0, stream>>>(vacc, lng, lnb, wsum_bf, n);
    dim3 g8((n + 63) / 64, 2);
    out_gemm_mfma<<<g8, 256, 0, stream>>>(wsum_bf, Wlfrag, bl, x, out, n);
}

// Round 5
// 196.148 us; speedup vs baseline: 7.6113x; 1.0855x over previous
//
#include <hip/hip_runtime.h>
#include <math.h>

// UniMP / TransformerConv block. bf16-MFMA GEMMs, single-pass flash-style edge phase,
// fused tail (final-GEMM + LayerNorm + out-GEMM + ELU in one kernel).
//   alpha = (q.k + ea.qe + q.be)/sqrt(D),  qe = x @ (Wq We^T per head)
//   agg   = sum attn*v[src] + (sum attn*ea) @ We_h + be_h
// Node tensors: qs f32 [n][1024] = [q|skip], kvq bf16 [n][1536] = [k|v|qe]

typedef short bf16x8 __attribute__((ext_vector_type(8)));
typedef unsigned short u16x8 __attribute__((ext_vector_type(8)));
typedef float f32x4 __attribute__((ext_vector_type(4)));

__device__ inline unsigned short f2bf(float f) {
    union { float f; unsigned u; } v; v.f = f;
    unsigned r = (v.u + 0x7FFFu + ((v.u >> 16) & 1u)) >> 16;
    return (unsigned short)r;
}
__device__ inline float bf2f(unsigned short u) {
    union { unsigned u; float f; } v; v.u = ((unsigned)u) << 16; return v.f;
}

// ---------------- K0: WqeT[m,hc] = sum_d Wq[m,hd]*We[c,hd]; bqe[hc] = sum_d bq[hd]*We[c,hd]
__global__ __launch_bounds__(256) void wqe_k(
    const float* __restrict__ Wq, const float* __restrict__ bq,
    const float* __restrict__ We,
    float* __restrict__ WqeT, float* __restrict__ bqe)
{
    const int b = blockIdx.x;
    if (b < 256) {
        const int gid = b * 256 + threadIdx.x;      // 0..65535
        const int m = gid >> 9, hc = gid & 511;
        const int h = hc >> 7, c = hc & 127;
        const float* wq = &Wq[(size_t)m * 512 + h * 128];
        const float* we = &We[(size_t)c * 512 + h * 128];
        float s0 = 0.f, s1 = 0.f;
        #pragma unroll 8
        for (int d = 0; d < 128; d += 2) { s0 += wq[d] * we[d]; s1 += wq[d + 1] * we[d + 1]; }
        WqeT[(size_t)m * 512 + hc] = s0 + s1;
    } else {
        const int hc = (b - 256) * 256 + threadIdx.x;
        const int h = hc >> 7, c = hc & 127;
        const float* we = &We[(size_t)c * 512 + h * 128];
        const float* bb = &bq[h * 128];
        float s = 0.f;
        #pragma unroll 8
        for (int d = 0; d < 128; ++d) s += bb[d] * we[d];
        bqe[hc] = s;
    }
}

// ---------------- K0b: bf16 conversions + fragment-ready weight layouts ----------------
__global__ __launch_bounds__(256) void prep_k(
    const float* __restrict__ x,
    const float* __restrict__ Wq, const float* __restrict__ bq,
    const float* __restrict__ Wk, const float* __restrict__ bk,
    const float* __restrict__ Wv, const float* __restrict__ bv,
    const float* __restrict__ Ws, const float* __restrict__ bs,
    const float* __restrict__ WqeT, const float* __restrict__ bqe,
    const float* __restrict__ We, const float* __restrict__ Wlin,
    unsigned short* __restrict__ x_bf, unsigned short* __restrict__ Wfrag,
    unsigned short* __restrict__ Wefrag, unsigned short* __restrict__ Wlfrag,
    float* __restrict__ bcat, int n, int nb1)
{
    const int b = blockIdx.x, t = threadIdx.x;
    if (b < nb1) {                                  // x -> bf16, 4 elems/thread
        int i = (b * 256 + t) * 4;
        if (i < n * 128) {
            float4 v = *(const float4*)&x[i];
            unsigned short o[4] = { f2bf(v.x), f2bf(v.y), f2bf(v.z), f2bf(v.w) };
            *(uint2*)&x_bf[i] = *(uint2*)o;
        }
    } else if (b < nb1 + 160) {                     // Wfrag: [q|k|v|skip|qe] 128x2560
        int g = (b - nb1) * 256 + t;                // (nt*4+kt)*64+lane, nt<160
        int lane = g & 63, kt = (g >> 6) & 3, nt = g >> 8;
        int ncol = nt * 16 + (lane & 15);
        int k0 = kt * 32 + ((lane >> 4) << 3);
        const float* W; int c;
        if      (ncol < 512)  { W = Wq;   c = ncol; }
        else if (ncol < 1024) { W = Wk;   c = ncol - 512; }
        else if (ncol < 1536) { W = Wv;   c = ncol - 1024; }
        else if (ncol < 2048) { W = Ws;   c = ncol - 1536; }
        else                  { W = WqeT; c = ncol - 2048; }
        unsigned short o[8];
        #pragma unroll
        for (int j = 0; j < 8; ++j) o[j] = f2bf(W[(size_t)(k0 + j) * 512 + c]);
        *(uint4*)&Wfrag[(size_t)g * 8] = *(uint4*)o;
    } else if (b < nb1 + 192) {                     // Wefrag: We 128x512
        int g = (b - nb1 - 160) * 256 + t;          // nt<32, kt<4
        int lane = g & 63, kt = (g >> 6) & 3, nt = g >> 8;
        int ncol = nt * 16 + (lane & 15);
        int k0 = kt * 32 + ((lane >> 4) << 3);
        unsigned short o[8];
        #pragma unroll
        for (int j = 0; j < 8; ++j) o[j] = f2bf(We[(size_t)(k0 + j) * 512 + ncol]);
        *(uint4*)&Wefrag[(size_t)g * 8] = *(uint4*)o;
    } else if (b < nb1 + 224) {                     // Wlfrag: Wlin 512x128
        int g = (b - nb1 - 192) * 256 + t;          // (nt*16+kt)*64+lane, nt<8, kt<16
        int lane = g & 63, kt = (g >> 6) & 15, nt = g >> 10;
        int ncol = nt * 16 + (lane & 15);
        int k0 = kt * 32 + ((lane >> 4) << 3);
        unsigned short o[8];
        #pragma unroll
        for (int j = 0; j < 8; ++j) o[j] = f2bf(Wlin[(size_t)(k0 + j) * 128 + ncol]);
        *(uint4*)&Wlfrag[(size_t)g * 8] = *(uint4*)o;
    } else {                                        // bcat[2560]
        int c = (b - nb1 - 224) * 256 + t;
        if (c < 2560)
            bcat[c] = (c < 512) ? bq[c] : (c < 1024) ? bk[c - 512] : (c < 1536) ? bv[c - 1024]
                     : (c < 2048) ? bs[c - 1536] : bqe[c - 2048];
    }
}

// ---------------- K1: [q|k|v|skip|qe] = x @ W + b (bf16 MFMA, no LDS) ----------------
// q,skip -> qs f32 [n][1024]; k,v,qe -> kvq bf16 [n][1536]
__global__ __launch_bounds__(256) void node_gemm_mfma(
    const unsigned short* __restrict__ x_bf, const unsigned short* __restrict__ Wfrag,
    const float* __restrict__ bcat, float* __restrict__ qs,
    unsigned short* __restrict__ kvq, int n)
{
    const int t = threadIdx.x, lane = t & 63, w = t >> 6;
    const int m0 = blockIdx.x * 64 + (w >> 1) * 32;
    const int n0 = blockIdx.y * 64 + (w & 1) * 32;
    const int lr = lane & 15, lk = (lane >> 4) << 3;
    f32x4 acc[2][2] = {};
    #pragma unroll
    for (int kt = 0; kt < 4; ++kt) {
        bf16x8 a[2], bf[2];
        #pragma unroll
        for (int mi = 0; mi < 2; ++mi) {
            int row = m0 + mi * 16 + lr; row = row < n ? row : n - 1;
            a[mi] = *(const bf16x8*)&x_bf[(size_t)row * 128 + kt * 32 + lk];
        }
        #pragma unroll
        for (int ni = 0; ni < 2; ++ni) {
            int nt = (n0 + ni * 16) >> 4;
            bf[ni] = *(const bf16x8*)&Wfrag[(size_t)((nt * 4 + kt) * 64 + lane) * 8];
        }
        #pragma unroll
        for (int mi = 0; mi < 2; ++mi)
            #pragma unroll
            for (int ni = 0; ni < 2; ++ni)
                acc[mi][ni] = __builtin_amdgcn_mfma_f32_16x16x32_bf16(a[mi], bf[ni], acc[mi][ni], 0, 0, 0);
    }
    #pragma unroll
    for (int mi = 0; mi < 2; ++mi)
        #pragma unroll
        for (int j = 0; j < 4; ++j) {
            int row = m0 + mi * 16 + (lane >> 4) * 4 + j;
            if (row < n) {
                #pragma unroll
                for (int ni = 0; ni < 2; ++ni) {
                    int col = n0 + ni * 16 + lr;
                    float val = acc[mi][ni][j] + bcat[col];
                    if (col < 512)        qs[(size_t)row * 1024 + col] = val;          // q
                    else if (col < 1536)  kvq[(size_t)row * 1536 + col - 512] = f2bf(val);  // k,v
                    else if (col < 2048)  qs[(size_t)row * 1024 + col - 1024] = val;   // skip
                    else                  kvq[(size_t)row * 1536 + col - 1024] = f2bf(val); // qe
                }
            }
        }
}

// ---------------- CSR build ----------------
__global__ void deg_count_k(const int* __restrict__ dst, int* __restrict__ deg, int E)
{
    int e = blockIdx.x * 256 + threadIdx.x;
    if (e < E) atomicAdd(&deg[dst[e]], 1);
}

__global__ __launch_bounds__(1024) void scan_k(const int* __restrict__ deg,
                                               int* __restrict__ row_start,
                                               int* __restrict__ cursor, int n)
{
    __shared__ int part[1024];
    const int t = threadIdx.x;
    const int c0 = t * 16;                  // supports n <= 16384
    int loc[16];
    int s = 0;
    #pragma unroll
    for (int i = 0; i < 16; ++i) {
        int idx = c0 + i;
        int dv = (idx < n) ? deg[idx] : 0;
        loc[i] = s; s += dv;
    }
    part[t] = s;
    __syncthreads();
    int incl = s;
    for (int off = 1; off < 1024; off <<= 1) {
        int other = (t >= off) ? part[t - off] : 0;
        __syncthreads();
        incl += other;
        part[t] = incl;
        __syncthreads();
    }
    const int base = incl - s;
    #pragma unroll
    for (int i = 0; i < 16; ++i) {
        int idx = c0 + i;
        if (idx < n) { row_start[idx] = base + loc[i]; cursor[idx] = base + loc[i]; }
    }
    if (t == 1023) row_start[n] = incl;
}

__global__ void scatter_k(const int* __restrict__ ei, int* __restrict__ cursor,
                          int2* __restrict__ csr, int E)
{
    int e = blockIdx.x * 256 + threadIdx.x;
    if (e < E) {
        int dnode = ei[E + e];
        int p = atomicAdd(&cursor[dnode], 1);
        csr[p] = make_int2(e, ei[e]);   // (eid, src)
    }
}

// ---------------- K5: single-pass flash-style edge phase, unroll-4 ----------------
// One wave per node. 4 lane-groups x 16 lanes: group g owns head g, lane owns 8 dims.
__global__ __launch_bounds__(256) void edge_k(
    const float* __restrict__ qs, const unsigned short* __restrict__ kvq,
    const float* __restrict__ ea, const float* __restrict__ be,
    const int* __restrict__ row_start, const int2* __restrict__ csr,
    unsigned short* __restrict__ wsum_bf, unsigned short* __restrict__ vacc_bf, int n)
{
    const int t = threadIdx.x;
    const int lane = t & 63;
    const int node = blockIdx.x * 4 + (t >> 6);
    if (node >= n) return;
    const int g = lane >> 4;            // head
    const int sl = (lane & 15) * 8;     // dim slice within head
    const int rs = row_start[node];
    const int deg = row_start[node + 1] - rs;
    const float s = 0.08838834764831845f;   // 1/sqrt(128)

    // per-lane scaled q, qe; group-uniform qbe = (q*s).be_h
    float q8[8], qe8[8];
    {
        const float* qp = &qs[(size_t)node * 1024 + g * 128 + sl];
        float4 a = *(const float4*)qp, b2 = *(const float4*)(qp + 4);
        q8[0]=a.x*s;  q8[1]=a.y*s;  q8[2]=a.z*s;  q8[3]=a.w*s;
        q8[4]=b2.x*s; q8[5]=b2.y*s; q8[6]=b2.z*s; q8[7]=b2.w*s;
        u16x8 u = *(const u16x8*)&kvq[(size_t)node * 1536 + 1024 + g * 128 + sl];
        #pragma unroll
        for (int i = 0; i < 8; ++i) qe8[i] = bf2f(u[i]) * s;
    }
    float qbe;
    {
        const float* bp = &be[g * 128 + sl];
        float pb = 0.f;
        #pragma unroll
        for (int i = 0; i < 8; ++i) pb += q8[i] * bp[i];
        #pragma unroll
        for (int o = 1; o <= 8; o <<= 1) pb += __shfl_xor(pb, o);
        qbe = pb;
    }

    float m = -3.0e38f, den = 0.f;
    float va[8] = {}, ws[8] = {};

    for (int j0 = 0; j0 < deg; j0 += 64) {
        const int cnt = min(64, deg - j0);
        int2 my = make_int2(0, 0);
        if (lane < cnt) my = csr[rs + j0 + lane];
        for (int jj = 0; jj < cnt; jj += 4) {
            int srcv[4], eidv[4]; bool act[4];
            #pragma unroll
            for (int u = 0; u < 4; ++u) {
                int idx = jj + u;
                act[u] = idx < cnt;
                int li = act[u] ? idx : (cnt - 1);
                eidv[u] = __shfl(my.x, li);
                srcv[u] = __shfl(my.y, li);
            }
            // 16 independent 16B loads issue together
            float ef[4][8];
            u16x8 kk[4], vv[4];
            #pragma unroll
            for (int u = 0; u < 4; ++u) {
                const float* ep = &ea[(size_t)eidv[u] * 128 + sl];
                float4 A = *(const float4*)ep, B = *(const float4*)(ep + 4);
                ef[u][0]=A.x; ef[u][1]=A.y; ef[u][2]=A.z; ef[u][3]=A.w;
                ef[u][4]=B.x; ef[u][5]=B.y; ef[u][6]=B.z; ef[u][7]=B.w;
                kk[u] = *(const u16x8*)&kvq[(size_t)srcv[u] * 1536 + g * 128 + sl];
                vv[u] = *(const u16x8*)&kvq[(size_t)srcv[u] * 1536 + 512 + g * 128 + sl];
            }
            float p[4] = {0.f, 0.f, 0.f, 0.f};
            #pragma unroll
            for (int i = 0; i < 8; ++i) {
                p[0] += q8[i] * bf2f(kk[0][i]) + qe8[i] * ef[0][i];
                p[1] += q8[i] * bf2f(kk[1][i]) + qe8[i] * ef[1][i];
                p[2] += q8[i] * bf2f(kk[2][i]) + qe8[i] * ef[2][i];
                p[3] += q8[i] * bf2f(kk[3][i]) + qe8[i] * ef[3][i];
            }
            #pragma unroll
            for (int o = 1; o <= 8; o <<= 1) {
                p[0] += __shfl_xor(p[0], o); p[1] += __shfl_xor(p[1], o);
                p[2] += __shfl_xor(p[2], o); p[3] += __shfl_xor(p[3], o);
            }
            float aval[4];
            #pragma unroll
            for (int u = 0; u < 4; ++u) aval[u] = act[u] ? (p[u] + qbe) : -3.0e38f;
            // online updates, deferred-max (THR=8)
            #pragma unroll
            for (int u = 0; u < 4; ++u) {
                const float a = aval[u];
                if (a > m + 8.f) {
                    const float sc = __expf(m - a);
                    den *= sc;
                    #pragma unroll
                    for (int i = 0; i < 8; ++i) { va[i] *= sc; ws[i] *= sc; }
                    m = a;
                }
                const float wgt = __expf(a - m);
                den += wgt;
                #pragma unroll
                for (int i = 0; i < 8; ++i) { va[i] += wgt * bf2f(vv[u][i]); ws[i] += wgt * ef[u][i]; }
            }
        }
    }

    const float rden = (den > 0.f) ? 1.f / den : 0.f;
    unsigned short vo[8], wo[8];
    #pragma unroll
    for (int i = 0; i < 8; ++i) { vo[i] = f2bf(va[i] * rden); wo[i] = f2bf(ws[i] * rden); }
    *(uint4*)&vacc_bf[(size_t)node * 512 + g * 128 + sl] = *(uint4*)vo;
    *(uint4*)&wsum_bf[(size_t)node * 512 + g * 128 + sl] = *(uint4*)wo;
}

// ---------------- K6: fused tail: y = vacc + wsum@We_h + hb*be + skip; LN; out-GEMM; ELU --
// 16 rows/block, 4 waves; wave w = head w for stage 1, cols [w*32,w*32+32) for stage 2.
__global__ __launch_bounds__(256) void tail_k(
    const unsigned short* __restrict__ wsum_bf, const unsigned short* __restrict__ Wefrag,
    const float* __restrict__ be, const unsigned short* __restrict__ vacc_bf,
    const float* __restrict__ qs, const int* __restrict__ row_start,
    const unsigned short* __restrict__ Wlfrag, const float* __restrict__ lng,
    const float* __restrict__ lnb, const float* __restrict__ blin,
    const float* __restrict__ x, float* __restrict__ out, int n)
{
    const int t = threadIdx.x, lane = t & 63, w = t >> 6;
    const int r0 = blockIdx.x * 16;
    const int lr = lane & 15, lk = (lane >> 4) << 3;
    __shared__ unsigned short nlds[16][520];        // normed bf16, +8 pad (16B-aligned rows)
    __shared__ float red_s[4][16], red_q[4][16], mval[16], rval[16];

    // ---- stage 1: wave w computes 16 rows x head-w cols of y
    f32x4 acc[8] = {};
    #pragma unroll
    for (int kt = 0; kt < 4; ++kt) {
        int row = r0 + lr; row = row < n ? row : n - 1;
        bf16x8 a = *(const bf16x8*)&wsum_bf[(size_t)row * 512 + w * 128 + kt * 32 + lk];
        #pragma unroll
        for (int ni = 0; ni < 8; ++ni) {
            bf16x8 bfr = *(const bf16x8*)&Wefrag[(size_t)(((w * 8 + ni) * 4 + kt) * 64 + lane) * 8];
            acc[ni] = __builtin_amdgcn_mfma_f32_16x16x32_bf16(a, bfr, acc[ni], 0, 0, 0);
        }
    }
    float g8[8], b8[8];
    #pragma unroll
    for (int ni = 0; ni < 8; ++ni) { int col = w * 128 + ni * 16 + lr; g8[ni] = lng[col]; b8[ni] = lnb[col]; }
    float sum_[4], sq_[4];
    #pragma unroll
    for (int j = 0; j < 4; ++j) {
        int row = r0 + (lane >> 4) * 4 + j;
        int rowc = row < n ? row : n - 1;
        const float hb = (row_start[rowc + 1] > row_start[rowc]) ? 1.f : 0.f;
        float s = 0.f, q = 0.f;
        #pragma unroll
        for (int ni = 0; ni < 8; ++ni) {
            int col = w * 128 + ni * 16 + lr;
            float y = acc[ni][j] + bf2f(vacc_bf[(size_t)rowc * 512 + col]) + hb * be[col]
                    + qs[(size_t)rowc * 1024 + 512 + col];
            acc[ni][j] = y;
            s += y; q += y * y;
        }
        sum_[j] = s; sq_[j] = q;
    }
    #pragma unroll
    for (int o = 1; o <= 8; o <<= 1) {
        #pragma unroll
        for (int j = 0; j < 4; ++j) { sum_[j] += __shfl_xor(sum_[j], o); sq_[j] += __shfl_xor(sq_[j], o); }
    }
    if (lr == 0) {
        #pragma unroll
        for (int j = 0; j < 4; ++j) {
            red_s[w][(lane >> 4) * 4 + j] = sum_[j];
            red_q[w][(lane >> 4) * 4 + j] = sq_[j];
        }
    }
    __syncthreads();
    if (t < 16) {
        float S = red_s[0][t] + red_s[1][t] + red_s[2][t] + red_s[3][t];
        float Q = red_q[0][t] + red_q[1][t] + red_q[2][t] + red_q[3][t];
        float mu = S * (1.f / 512.f);
        float var = Q * (1.f / 512.f) - mu * mu;
        mval[t] = mu;
        rval[t] = rsqrtf(fmaxf(var, 0.f) + 1e-5f);
    }
    __syncthreads();
    #pragma unroll
    for (int j = 0; j < 4; ++j) {
        int rowl = (lane >> 4) * 4 + j;
        float mu = mval[rowl], rv = rval[rowl];
        #pragma unroll
        for (int ni = 0; ni < 8; ++ni) {
            int col = w * 128 + ni * 16 + lr;
            nlds[rowl][col] = f2bf((acc[ni][j] - mu) * rv * g8[ni] + b8[ni]);
        }
    }
    __syncthreads();
    // ---- stage 2: out = elu(nlds @ Wlin + blin + x), wave w covers cols [w*32, w*32+32)
    f32x4 acc2[2] = {};
    #pragma unroll
    for (int kt = 0; kt < 16; ++kt) {
        bf16x8 a2 = *(const bf16x8*)&nlds[lr][kt * 32 + lk];
        #pragma unroll
        for (int ni = 0; ni < 2; ++ni) {
            bf16x8 bfr = *(const bf16x8*)&Wlfrag[(size_t)(((w * 2 + ni) * 16 + kt) * 64 + lane) * 8];
            acc2[ni] = __builtin_amdgcn_mfma_f32_16x16x32_bf16(a2, bfr, acc2[ni], 0, 0, 0);
        }
    }
    #pragma unroll
    for (int j = 0; j < 4; ++j) {
        int row = r0 + (lane >> 4) * 4 + j;
        if (row < n) {
            #pragma unroll
            for (int ni = 0; ni < 2; ++ni) {
                int col = w * 32 + ni * 16 + lr;
                float z = acc2[ni][j] + blin[col] + x[(size_t)row * 128 + col];
                out[(size_t)row * 128 + col] = z > 0.f ? z : expm1f(z);
            }
        }
    }
}

extern "C" void kernel_launch(void* const* d_in, const int* in_sizes, int n_in,
                              void* d_out, int out_size, void* d_ws, size_t ws_size,
                              hipStream_t stream)
{
    const float* x   = (const float*)d_in[0];
    const int*   ei  = (const int*)d_in[1];
    const float* ea  = (const float*)d_in[2];
    const float* Wq  = (const float*)d_in[3];
    const float* bq  = (const float*)d_in[4];
    const float* Wk  = (const float*)d_in[5];
    const float* bk  = (const float*)d_in[6];
    const float* Wv  = (const float*)d_in[7];
    const float* bv  = (const float*)d_in[8];
    const float* We  = (const float*)d_in[9];
    const float* be  = (const float*)d_in[10];
    const float* Wsk = (const float*)d_in[11];
    const float* bsk = (const float*)d_in[12];
    const float* lng = (const float*)d_in[13];
    const float* lnb = (const float*)d_in[14];
    const float* Wl  = (const float*)d_in[15];
    const float* bl  = (const float*)d_in[16];
    float* out = (float*)d_out;

    const int n = in_sizes[0] / 128;
    const int E = in_sizes[1] / 2;

    float* qs    = (float*)d_ws;                    // n*1024 (q | skip)
    float* WqeT  = qs + (size_t)n * 1024;           // 128*512
    float* bqe   = WqeT + 128 * 512;                // 512
    float* bcat  = bqe + 512;                       // 2560
    unsigned short* x_bf    = (unsigned short*)(bcat + 2560);   // n*128
    unsigned short* wsum_bf = x_bf + (size_t)n * 128;           // n*512
    unsigned short* vacc_bf = wsum_bf + (size_t)n * 512;        // n*512
    unsigned short* kvq     = vacc_bf + (size_t)n * 512;        // n*1536 (k|v|qe)
    unsigned short* Wfrag   = kvq + (size_t)n * 1536;           // 128*2560
    unsigned short* Wefrag  = Wfrag + 128 * 2560;               // 128*512
    unsigned short* Wlfrag  = Wefrag + 128 * 512;               // 512*128
    int2* csr = (int2*)(((uintptr_t)(Wlfrag + 512 * 128) + 7) & ~(uintptr_t)7);  // E pairs
    int* deg       = (int*)(csr + E);
    int* row_start = deg + n;
    int* cursor    = row_start + n + 1;

    hipMemsetAsync(deg, 0, (size_t)n * sizeof(int), stream);

    wqe_k<<<258, 256, 0, stream>>>(Wq, bq, We, WqeT, bqe);
    const int nb1 = (n * 32 + 255) / 256;           // x-conversion blocks (4 elems/thread)
    prep_k<<<nb1 + 234, 256, 0, stream>>>(x, Wq, bq, Wk, bk, Wv, bv, Wsk, bsk, WqeT, bqe,
                                          We, Wl, x_bf, Wfrag, Wefrag, Wlfrag, bcat, n, nb1);
    dim3 g1((n + 63) / 64, 40);
    node_gemm_mfma<<<g1, 256, 0, stream>>>(x_bf, Wfrag, bcat, qs, kvq, n);
    deg_count_k<<<(E + 255) / 256, 256, 0, stream>>>(ei + E, deg, E);
    scan_k<<<1, 1024, 0, stream>>>(deg, row_start, cursor, n);
    scatter_k<<<(E + 255) / 256, 256, 0, stream>>>(ei, cursor, csr, E);
    edge_k<<<(n + 3) / 4, 256, 0, stream>>>(qs, kvq, ea, be, row_start, csr,
                                            wsum_bf, vacc_bf, n);
    tail_k<<<(n + 15) / 16, 256, 0, stream>>>(wsum_bf, Wefrag, be, vacc_bf, qs, row_start,
                                              Wlfrag, lng, lnb, bl, x, out, n);
}

// Round 6
// 181.220 us; speedup vs baseline: 8.2383x; 1.0824x over previous
//
#include <hip/hip_runtime.h>
#include <math.h>

// UniMP / TransformerConv block. bf16-MFMA GEMMs, single-pass flash-style edge phase
// (2 waves per node + LDS online-softmax merge), fused tail (GEMM+LN+GEMM+ELU).
//   alpha = q_s.k + ea.qe_s + q_s.be   (scale 1/sqrt(D) folded into Wq/WqeT/bqe)
//   agg   = sum attn*v[src] + (sum attn*ea) @ We_h + be_h
// Node tensors: qs f32 [n][512] = skip, kvq bf16 [n][2048] = [q|k|v|qe]

typedef short bf16x8 __attribute__((ext_vector_type(8)));
typedef unsigned short u16x8 __attribute__((ext_vector_type(8)));
typedef float f32x4 __attribute__((ext_vector_type(4)));

#define SCALE 0.08838834764831845f  // 1/sqrt(128)

__device__ inline unsigned short f2bf(float f) {
    union { float f; unsigned u; } v; v.f = f;
    unsigned r = (v.u + 0x7FFFu + ((v.u >> 16) & 1u)) >> 16;
    return (unsigned short)r;
}
__device__ inline float bf2f(unsigned short u) {
    union { unsigned u; float f; } v; v.u = ((unsigned)u) << 16; return v.f;
}

// ---------------- K0: WqeT[m,hc] = s*sum_d Wq[m,hd]*We[c,hd]; bqe[hc] = s*sum_d bq[hd]*We[c,hd]
__global__ __launch_bounds__(256) void wqe_k(
    const float* __restrict__ Wq, const float* __restrict__ bq,
    const float* __restrict__ We,
    float* __restrict__ WqeT, float* __restrict__ bqe)
{
    const int b = blockIdx.x;
    if (b < 256) {
        const int gid = b * 256 + threadIdx.x;      // 0..65535
        const int m = gid >> 9, hc = gid & 511;
        const int h = hc >> 7, c = hc & 127;
        const float* wq = &Wq[(size_t)m * 512 + h * 128];
        const float* we = &We[(size_t)c * 512 + h * 128];
        float s0 = 0.f, s1 = 0.f;
        #pragma unroll 8
        for (int d = 0; d < 128; d += 2) { s0 += wq[d] * we[d]; s1 += wq[d + 1] * we[d + 1]; }
        WqeT[(size_t)m * 512 + hc] = (s0 + s1) * SCALE;
    } else {
        const int hc = (b - 256) * 256 + threadIdx.x;
        const int h = hc >> 7, c = hc & 127;
        const float* we = &We[(size_t)c * 512 + h * 128];
        const float* bb = &bq[h * 128];
        float s = 0.f;
        #pragma unroll 8
        for (int d = 0; d < 128; ++d) s += bb[d] * we[d];
        bqe[hc] = s * SCALE;
    }
}

// ---------------- K0b: bf16 conversions + fragment-ready weight layouts ----------------
__global__ __launch_bounds__(256) void prep_k(
    const float* __restrict__ x,
    const float* __restrict__ Wq, const float* __restrict__ bq,
    const float* __restrict__ Wk, const float* __restrict__ bk,
    const float* __restrict__ Wv, const float* __restrict__ bv,
    const float* __restrict__ Ws, const float* __restrict__ bs,
    const float* __restrict__ WqeT, const float* __restrict__ bqe,
    const float* __restrict__ We, const float* __restrict__ Wlin,
    unsigned short* __restrict__ x_bf, unsigned short* __restrict__ Wfrag,
    unsigned short* __restrict__ Wefrag, unsigned short* __restrict__ Wlfrag,
    float* __restrict__ bcat, int n, int nb1)
{
    const int b = blockIdx.x, t = threadIdx.x;
    if (b < nb1) {                                  // x -> bf16, 4 elems/thread
        int i = (b * 256 + t) * 4;
        if (i < n * 128) {
            float4 v = *(const float4*)&x[i];
            unsigned short o[4] = { f2bf(v.x), f2bf(v.y), f2bf(v.z), f2bf(v.w) };
            *(uint2*)&x_bf[i] = *(uint2*)o;
        }
    } else if (b < nb1 + 160) {                     // Wfrag: [q|k|v|skip|qe] 128x2560
        int g = (b - nb1) * 256 + t;                // (nt*4+kt)*64+lane, nt<160
        int lane = g & 63, kt = (g >> 6) & 3, nt = g >> 8;
        int ncol = nt * 16 + (lane & 15);
        int k0 = kt * 32 + ((lane >> 4) << 3);
        const float* W; int c; float sc = 1.f;
        if      (ncol < 512)  { W = Wq;   c = ncol; sc = SCALE; }
        else if (ncol < 1024) { W = Wk;   c = ncol - 512; }
        else if (ncol < 1536) { W = Wv;   c = ncol - 1024; }
        else if (ncol < 2048) { W = Ws;   c = ncol - 1536; }
        else                  { W = WqeT; c = ncol - 2048; }
        unsigned short o[8];
        #pragma unroll
        for (int j = 0; j < 8; ++j) o[j] = f2bf(W[(size_t)(k0 + j) * 512 + c] * sc);
        *(uint4*)&Wfrag[(size_t)g * 8] = *(uint4*)o;
    } else if (b < nb1 + 192) {                     // Wefrag: We 128x512
        int g = (b - nb1 - 160) * 256 + t;          // nt<32, kt<4
        int lane = g & 63, kt = (g >> 6) & 3, nt = g >> 8;
        int ncol = nt * 16 + (lane & 15);
        int k0 = kt * 32 + ((lane >> 4) << 3);
        unsigned short o[8];
        #pragma unroll
        for (int j = 0; j < 8; ++j) o[j] = f2bf(We[(size_t)(k0 + j) * 512 + ncol]);
        *(uint4*)&Wefrag[(size_t)g * 8] = *(uint4*)o;
    } else if (b < nb1 + 224) {                     // Wlfrag: Wlin 512x128
        int g = (b - nb1 - 192) * 256 + t;          // (nt*16+kt)*64+lane, nt<8, kt<16
        int lane = g & 63, kt = (g >> 6) & 15, nt = g >> 10;
        int ncol = nt * 16 + (lane & 15);
        int k0 = kt * 32 + ((lane >> 4) << 3);
        unsigned short o[8];
        #pragma unroll
        for (int j = 0; j < 8; ++j) o[j] = f2bf(Wlin[(size_t)(k0 + j) * 128 + ncol]);
        *(uint4*)&Wlfrag[(size_t)g * 8] = *(uint4*)o;
    } else {                                        // bcat[2560]
        int c = (b - nb1 - 224) * 256 + t;
        if (c < 2560)
            bcat[c] = (c < 512) ? bq[c] * SCALE : (c < 1024) ? bk[c - 512]
                     : (c < 1536) ? bv[c - 1024] : (c < 2048) ? bs[c - 1536] : bqe[c - 2048];
    }
}

// ---------------- K1: [q|k|v|skip|qe] = x @ W + b (bf16 MFMA, no LDS) ----------------
// skip -> qs f32 [n][512]; q,k,v,qe -> kvq bf16 [n][2048]
__global__ __launch_bounds__(256) void node_gemm_mfma(
    const unsigned short* __restrict__ x_bf, const unsigned short* __restrict__ Wfrag,
    const float* __restrict__ bcat, float* __restrict__ qs,
    unsigned short* __restrict__ kvq, int n)
{
    const int t = threadIdx.x, lane = t & 63, w = t >> 6;
    const int m0 = blockIdx.x * 64 + (w >> 1) * 32;
    const int n0 = blockIdx.y * 64 + (w & 1) * 32;
    const int lr = lane & 15, lk = (lane >> 4) << 3;
    f32x4 acc[2][2] = {};
    #pragma unroll
    for (int kt = 0; kt < 4; ++kt) {
        bf16x8 a[2], bf[2];
        #pragma unroll
        for (int mi = 0; mi < 2; ++mi) {
            int row = m0 + mi * 16 + lr; row = row < n ? row : n - 1;
            a[mi] = *(const bf16x8*)&x_bf[(size_t)row * 128 + kt * 32 + lk];
        }
        #pragma unroll
        for (int ni = 0; ni < 2; ++ni) {
            int nt = (n0 + ni * 16) >> 4;
            bf[ni] = *(const bf16x8*)&Wfrag[(size_t)((nt * 4 + kt) * 64 + lane) * 8];
        }
        #pragma unroll
        for (int mi = 0; mi < 2; ++mi)
            #pragma unroll
            for (int ni = 0; ni < 2; ++ni)
                acc[mi][ni] = __builtin_amdgcn_mfma_f32_16x16x32_bf16(a[mi], bf[ni], acc[mi][ni], 0, 0, 0);
    }
    #pragma unroll
    for (int mi = 0; mi < 2; ++mi)
        #pragma unroll
        for (int j = 0; j < 4; ++j) {
            int row = m0 + mi * 16 + (lane >> 4) * 4 + j;
            if (row < n) {
                #pragma unroll
                for (int ni = 0; ni < 2; ++ni) {
                    int col = n0 + ni * 16 + lr;
                    float val = acc[mi][ni][j] + bcat[col];
                    if (col < 1536)       kvq[(size_t)row * 2048 + col] = f2bf(val);        // q,k,v
                    else if (col < 2048)  qs[(size_t)row * 512 + col - 1536] = val;         // skip
                    else                  kvq[(size_t)row * 2048 + col - 512] = f2bf(val);  // qe
                }
            }
        }
}

// ---------------- CSR build ----------------
__global__ void deg_count_k(const int* __restrict__ dst, int* __restrict__ deg, int E)
{
    int e = blockIdx.x * 256 + threadIdx.x;
    if (e < E) atomicAdd(&deg[dst[e]], 1);
}

__global__ __launch_bounds__(1024) void scan_k(const int* __restrict__ deg,
                                               int* __restrict__ row_start,
                                               int* __restrict__ cursor, int n)
{
    __shared__ int part[1024];
    const int t = threadIdx.x;
    const int c0 = t * 16;                  // supports n <= 16384
    int loc[16];
    int s = 0;
    #pragma unroll
    for (int i = 0; i < 16; ++i) {
        int idx = c0 + i;
        int dv = (idx < n) ? deg[idx] : 0;
        loc[i] = s; s += dv;
    }
    part[t] = s;
    __syncthreads();
    int incl = s;
    for (int off = 1; off < 1024; off <<= 1) {
        int other = (t >= off) ? part[t - off] : 0;
        __syncthreads();
        incl += other;
        part[t] = incl;
        __syncthreads();
    }
    const int base = incl - s;
    #pragma unroll
    for (int i = 0; i < 16; ++i) {
        int idx = c0 + i;
        if (idx < n) { row_start[idx] = base + loc[i]; cursor[idx] = base + loc[i]; }
    }
    if (t == 1023) row_start[n] = incl;
}

__global__ void scatter_k(const int* __restrict__ ei, int* __restrict__ cursor,
                          int2* __restrict__ csr, int E)
{
    int e = blockIdx.x * 256 + threadIdx.x;
    if (e < E) {
        int dnode = ei[E + e];
        int p = atomicAdd(&cursor[dnode], 1);
        csr[p] = make_int2(e, ei[e]);   // (eid, src)
    }
}

// ---------------- K5: flash-style edge phase, 2 waves per node + LDS merge ----------------
// Block = 4 waves = 2 nodes. Wave pair (slot, half). 4 lane-groups x 16 lanes per wave:
// group g owns head g, lane owns 8 dims. Each half processes a contiguous edge range.
__global__ __launch_bounds__(256) void edge_k(
    const unsigned short* __restrict__ kvq, const float* __restrict__ ea,
    const float* __restrict__ be,
    const int* __restrict__ row_start, const int2* __restrict__ csr,
    unsigned short* __restrict__ wsum_bf, unsigned short* __restrict__ vacc_bf, int n)
{
    const int t = threadIdx.x, lane = t & 63, w = t >> 6;
    const int slot = w >> 1, half = w & 1;
    const int node = blockIdx.x * 2 + slot;
    const bool nvalid = node < n;
    const int nodec = nvalid ? node : 0;
    const int g = lane >> 4;            // head
    const int l15 = lane & 15;
    const int sl = l15 * 8;             // dim slice within head

    __shared__ float lds_m[2][4], lds_den[2][4];
    __shared__ float lds_va[2][4][128], lds_ws[2][4][128];

    int rs = 0, deg = 0;
    if (nvalid) { rs = row_start[node]; deg = row_start[node + 1] - rs; }
    const int dh = (deg + 1) >> 1;
    const int lo = half ? dh : 0;
    const int myc = half ? (deg - dh) : dh;

    // per-lane q_s, qe_s (pre-scaled, bf16)
    float q8[8], qe8[8];
    {
        const u16x8 uq  = *(const u16x8*)&kvq[(size_t)nodec * 2048 + g * 128 + sl];
        const u16x8 uqe = *(const u16x8*)&kvq[(size_t)nodec * 2048 + 1536 + g * 128 + sl];
        #pragma unroll
        for (int i = 0; i < 8; ++i) { q8[i] = bf2f(uq[i]); qe8[i] = bf2f(uqe[i]); }
    }
    float qbe;
    {
        const float* bp = &be[g * 128 + sl];
        float pb = 0.f;
        #pragma unroll
        for (int i = 0; i < 8; ++i) pb += q8[i] * bp[i];
        #pragma unroll
        for (int o = 1; o <= 8; o <<= 1) pb += __shfl_xor(pb, o);
        qbe = pb;
    }

    float m = -3.0e38f, den = 0.f;
    float va[8] = {}, ws[8] = {};

    for (int j0 = 0; j0 < myc; j0 += 64) {
        const int cnt = min(64, myc - j0);
        int2 my = make_int2(0, 0);
        if (lane < cnt) my = csr[rs + lo + j0 + lane];
        for (int jj = 0; jj < cnt; jj += 2) {
            const bool two = (jj + 1 < cnt);
            const int j1 = two ? jj + 1 : jj;
            const int eid0 = __shfl(my.x, jj), src0 = __shfl(my.y, jj);
            const int eid1 = __shfl(my.x, j1), src1 = __shfl(my.y, j1);
            // loads (independent chains)
            const float* ep0 = &ea[(size_t)eid0 * 128 + sl];
            const float* ep1 = &ea[(size_t)eid1 * 128 + sl];
            float4 eA0 = *(const float4*)ep0, eB0 = *(const float4*)(ep0 + 4);
            float4 eA1 = *(const float4*)ep1, eB1 = *(const float4*)(ep1 + 4);
            const u16x8 k0 = *(const u16x8*)&kvq[(size_t)src0 * 2048 + 512 + g * 128 + sl];
            const u16x8 v0 = *(const u16x8*)&kvq[(size_t)src0 * 2048 + 1024 + g * 128 + sl];
            const u16x8 k1 = *(const u16x8*)&kvq[(size_t)src1 * 2048 + 512 + g * 128 + sl];
            const u16x8 v1 = *(const u16x8*)&kvq[(size_t)src1 * 2048 + 1024 + g * 128 + sl];
            float ef0[8] = {eA0.x, eA0.y, eA0.z, eA0.w, eB0.x, eB0.y, eB0.z, eB0.w};
            float ef1[8] = {eA1.x, eA1.y, eA1.z, eA1.w, eB1.x, eB1.y, eB1.z, eB1.w};
            float p0 = 0.f, p1 = 0.f;
            #pragma unroll
            for (int i = 0; i < 8; ++i) {
                p0 += q8[i] * bf2f(k0[i]) + qe8[i] * ef0[i];
                p1 += q8[i] * bf2f(k1[i]) + qe8[i] * ef1[i];
            }
            #pragma unroll
            for (int o = 1; o <= 8; o <<= 1) {
                p0 += __shfl_xor(p0, o);
                p1 += __shfl_xor(p1, o);
            }
            const float a0 = p0 + qbe;
            const float a1 = two ? (p1 + qbe) : -3.0e38f;   // dummy tail: weight 0
            // group-max batched online update (deferred-max THR=8)
            const float gm = fmaxf(a0, a1);
            if (gm > m + 8.f) {
                const float sc = __expf(m - gm);
                den *= sc;
                #pragma unroll
                for (int i = 0; i < 8; ++i) { va[i] *= sc; ws[i] *= sc; }
                m = gm;
            }
            const float w0 = __expf(a0 - m);
            const float w1 = __expf(a1 - m);
            den += w0 + w1;
            #pragma unroll
            for (int i = 0; i < 8; ++i) {
                va[i] += w0 * bf2f(v0[i]) + w1 * bf2f(v1[i]);
                ws[i] += w0 * ef0[i] + w1 * ef1[i];
            }
        }
    }

    // merge halves: half 1 publishes, half 0 combines and writes out
    if (half == 1) {
        if (l15 == 0) { lds_m[slot][g] = m; lds_den[slot][g] = den; }
        #pragma unroll
        for (int i = 0; i < 8; ++i) {
            lds_va[slot][g][sl + i] = va[i];
            lds_ws[slot][g][sl + i] = ws[i];
        }
    }
    __syncthreads();
    if (half == 0 && nvalid) {
        const float m1 = lds_m[slot][g], den1 = lds_den[slot][g];
        const float M = fmaxf(m, m1);
        const float s0 = __expf(m - M), s1 = __expf(m1 - M);
        const float dtot = den * s0 + den1 * s1;
        const float rden = (dtot > 0.f) ? 1.f / dtot : 0.f;
        unsigned short vo[8], wo[8];
        #pragma unroll
        for (int i = 0; i < 8; ++i) {
            vo[i] = f2bf((va[i] * s0 + lds_va[slot][g][sl + i] * s1) * rden);
            wo[i] = f2bf((ws[i] * s0 + lds_ws[slot][g][sl + i] * s1) * rden);
        }
        *(uint4*)&vacc_bf[(size_t)node * 512 + g * 128 + sl] = *(uint4*)vo;
        *(uint4*)&wsum_bf[(size_t)node * 512 + g * 128 + sl] = *(uint4*)wo;
    }
}

// ---------------- K6: fused tail: y = vacc + wsum@We_h + hb*be + skip; LN; out-GEMM; ELU --
// 16 rows/block, 4 waves; wave w = head w for stage 1, cols [w*32,w*32+32) for stage 2.
__global__ __launch_bounds__(256) void tail_k(
    const unsigned short* __restrict__ wsum_bf, const unsigned short* __restrict__ Wefrag,
    const float* __restrict__ be, const unsigned short* __restrict__ vacc_bf,
    const float* __restrict__ qs, const int* __restrict__ row_start,
    const unsigned short* __restrict__ Wlfrag, const float* __restrict__ lng,
    const float* __restrict__ lnb, const float* __restrict__ blin,
    const float* __restrict__ x, float* __restrict__ out, int n)
{
    const int t = threadIdx.x, lane = t & 63, w = t >> 6;
    const int r0 = blockIdx.x * 16;
    const int lr = lane & 15, lk = (lane >> 4) << 3;
    __shared__ unsigned short nlds[16][520];        // normed bf16, +8 pad (16B-aligned rows)
    __shared__ float red_s[4][16], red_q[4][16], mval[16], rval[16];

    // ---- stage 1: wave w computes 16 rows x head-w cols of y
    f32x4 acc[8] = {};
    #pragma unroll
    for (int kt = 0; kt < 4; ++kt) {
        int row = r0 + lr; row = row < n ? row : n - 1;
        bf16x8 a = *(const bf16x8*)&wsum_bf[(size_t)row * 512 + w * 128 + kt * 32 + lk];
        #pragma unroll
        for (int ni = 0; ni < 8; ++ni) {
            bf16x8 bfr = *(const bf16x8*)&Wefrag[(size_t)(((w * 8 + ni) * 4 + kt) * 64 + lane) * 8];
            acc[ni] = __builtin_amdgcn_mfma_f32_16x16x32_bf16(a, bfr, acc[ni], 0, 0, 0);
        }
    }
    float g8[8], b8[8];
    #pragma unroll
    for (int ni = 0; ni < 8; ++ni) { int col = w * 128 + ni * 16 + lr; g8[ni] = lng[col]; b8[ni] = lnb[col]; }
    float sum_[4], sq_[4];
    #pragma unroll
    for (int j = 0; j < 4; ++j) {
        int row = r0 + (lane >> 4) * 4 + j;
        int rowc = row < n ? row : n - 1;
        const float hb = (row_start[rowc + 1] > row_start[rowc]) ? 1.f : 0.f;
        float s = 0.f, q = 0.f;
        #pragma unroll
        for (int ni = 0; ni < 8; ++ni) {
            int col = w * 128 + ni * 16 + lr;
            float y = acc[ni][j] + bf2f(vacc_bf[(size_t)rowc * 512 + col]) + hb * be[col]
                    + qs[(size_t)rowc * 512 + col];
            acc[ni][j] = y;
            s += y; q += y * y;
        }
        sum_[j] = s; sq_[j] = q;
    }
    #pragma unroll
    for (int o = 1; o <= 8; o <<= 1) {
        #pragma unroll
        for (int j = 0; j < 4; ++j) { sum_[j] += __shfl_xor(sum_[j], o); sq_[j] += __shfl_xor(sq_[j], o); }
    }
    if (lr == 0) {
        #pragma unroll
        for (int j = 0; j < 4; ++j) {
            red_s[w][(lane >> 4) * 4 + j] = sum_[j];
            red_q[w][(lane >> 4) * 4 + j] = sq_[j];
        }
    }
    __syncthreads();
    if (t < 16) {
        float S = red_s[0][t] + red_s[1][t] + red_s[2][t] + red_s[3][t];
        float Q = red_q[0][t] + red_q[1][t] + red_q[2][t] + red_q[3][t];
        float mu = S * (1.f / 512.f);
        float var = Q * (1.f / 512.f) - mu * mu;
        mval[t] = mu;
        rval[t] = rsqrtf(fmaxf(var, 0.f) + 1e-5f);
    }
    __syncthreads();
    #pragma unroll
    for (int j = 0; j < 4; ++j) {
        int rowl = (lane >> 4) * 4 + j;
        float mu = mval[rowl], rv = rval[rowl];
        #pragma unroll
        for (int ni = 0; ni < 8; ++ni) {
            int col = w * 128 + ni * 16 + lr;
            nlds[rowl][col] = f2bf((acc[ni][j] - mu) * rv * g8[ni] + b8[ni]);
        }
    }
    __syncthreads();
    // ---- stage 2: out = elu(nlds @ Wlin + blin + x), wave w covers cols [w*32, w*32+32)
    f32x4 acc2[2] = {};
    #pragma unroll
    for (int kt = 0; kt < 16; ++kt) {
        bf16x8 a2 = *(const bf16x8*)&nlds[lr][kt * 32 + lk];
        #pragma unroll
        for (int ni = 0; ni < 2; ++ni) {
            bf16x8 bfr = *(const bf16x8*)&Wlfrag[(size_t)(((w * 2 + ni) * 16 + kt) * 64 + lane) * 8];
            acc2[ni] = __builtin_amdgcn_mfma_f32_16x16x32_bf16(a2, bfr, acc2[ni], 0, 0, 0);
        }
    }
    #pragma unroll
    for (int j = 0; j < 4; ++j) {
        int row = r0 + (lane >> 4) * 4 + j;
        if (row < n) {
            #pragma unroll
            for (int ni = 0; ni < 2; ++ni) {
                int col = w * 32 + ni * 16 + lr;
                float z = acc2[ni][j] + blin[col] + x[(size_t)row * 128 + col];
                out[(size_t)row * 128 + col] = z > 0.f ? z : expm1f(z);
            }
        }
    }
}

extern "C" void kernel_launch(void* const* d_in, const int* in_sizes, int n_in,
                              void* d_out, int out_size, void* d_ws, size_t ws_size,
                              hipStream_t stream)
{
    const float* x   = (const float*)d_in[0];
    const int*   ei  = (const int*)d_in[1];
    const float* ea  = (const float*)d_in[2];
    const float* Wq  = (const float*)d_in[3];
    const float* bq  = (const float*)d_in[4];
    const float* Wk  = (const float*)d_in[5];
    const float* bk  = (const float*)d_in[6];
    const float* Wv  = (const float*)d_in[7];
    const float* bv  = (const float*)d_in[8];
    const float* We  = (const float*)d_in[9];
    const float* be  = (const float*)d_in[10];
    const float* Wsk = (const float*)d_in[11];
    const float* bsk = (const float*)d_in[12];
    const float* lng = (const float*)d_in[13];
    const float* lnb = (const float*)d_in[14];
    const float* Wl  = (const float*)d_in[15];
    const float* bl  = (const float*)d_in[16];
    float* out = (float*)d_out;

    const int n = in_sizes[0] / 128;
    const int E = in_sizes[1] / 2;

    float* qs    = (float*)d_ws;                    // n*512 (skip)
    float* WqeT  = qs + (size_t)n * 512;            // 128*512
    float* bqe   = WqeT + 128 * 512;                // 512
    float* bcat  = bqe + 512;                       // 2560
    unsigned short* x_bf    = (unsigned short*)(bcat + 2560);   // n*128
    unsigned short* wsum_bf = x_bf + (size_t)n * 128;           // n*512
    unsigned short* vacc_bf = wsum_bf + (size_t)n * 512;        // n*512
    unsigned short* kvq     = vacc_bf + (size_t)n * 512;        // n*2048 (q|k|v|qe)
    unsigned short* Wfrag   = kvq + (size_t)n * 2048;           // 128*2560
    unsigned short* Wefrag  = Wfrag + 128 * 2560;               // 128*512
    unsigned short* Wlfrag  = Wefrag + 128 * 512;               // 512*128
    int2* csr = (int2*)(((uintptr_t)(Wlfrag + 512 * 128) + 7) & ~(uintptr_t)7);  // E pairs
    int* deg       = (int*)(csr + E);
    int* row_start = deg + n;
    int* cursor    = row_start + n + 1;

    hipMemsetAsync(deg, 0, (size_t)n * sizeof(int), stream);

    wqe_k<<<258, 256, 0, stream>>>(Wq, bq, We, WqeT, bqe);
    const int nb1 = (n * 32 + 255) / 256;           // x-conversion blocks (4 elems/thread)
    prep_k<<<nb1 + 234, 256, 0, stream>>>(x, Wq, bq, Wk, bk, Wv, bv, Wsk, bsk, WqeT, bqe,
                                          We, Wl, x_bf, Wfrag, Wefrag, Wlfrag, bcat, n, nb1);
    dim3 g1((n + 63) / 64, 40);
    node_gemm_mfma<<<g1, 256, 0, stream>>>(x_bf, Wfrag, bcat, qs, kvq, n);
    deg_count_k<<<(E + 255) / 256, 256, 0, stream>>>(ei + E, deg, E);
    scan_k<<<1, 1024, 0, stream>>>(deg, row_start, cursor, n);
    scatter_k<<<(E + 255) / 256, 256, 0, stream>>>(ei, cursor, csr, E);
    edge_k<<<(n + 1) / 2, 256, 0, stream>>>(kvq, ea, be, row_start, csr,
                                            wsum_bf, vacc_bf, n);
    tail_k<<<(n + 15) / 16, 256, 0, stream>>>(wsum_bf, Wefrag, be, vacc_bf, qs, row_start,
                                              Wlfrag, lng, lnb, bl, x, out, n);
}

// Round 7
// 181.216 us; speedup vs baseline: 8.2384x; 1.0000x over previous
//
#include <hip/hip_runtime.h>
#include <math.h>

// UniMP / TransformerConv block. bf16-MFMA GEMMs, single-pass flash-style edge phase
// (2 waves per node + LDS online-softmax merge, unroll-4), fused tail (GEMM+LN+GEMM+ELU).
//   alpha = q_s.k + ea.qe_s + q_s.be   (scale 1/sqrt(D) folded into Wq/WqeT/bqe)
//   agg   = sum attn*v[src] + (sum attn*ea) @ We_h + be_h
// Node tensors: qs f32 [n][512] = skip, kvq bf16 [n][2048] = [q|k|v|qe]
// 6 kernels: wqe(+degzero) -> prep(+degcount) -> scan -> node_gemm(+scatter) -> edge -> tail

typedef short bf16x8 __attribute__((ext_vector_type(8)));
typedef unsigned short u16x8 __attribute__((ext_vector_type(8)));
typedef float f32x4 __attribute__((ext_vector_type(4)));

#define SCALE 0.08838834764831845f  // 1/sqrt(128)

__device__ inline unsigned short f2bf(float f) {
    union { float f; unsigned u; } v; v.f = f;
    unsigned r = (v.u + 0x7FFFu + ((v.u >> 16) & 1u)) >> 16;
    return (unsigned short)r;
}
__device__ inline float bf2f(unsigned short u) {
    union { unsigned u; float f; } v; v.u = ((unsigned)u) << 16; return v.f;
}

// ---------------- K0: WqeT = s*Wq@We^T; bqe = s*bq@We^T; zero deg ----------------
__global__ __launch_bounds__(256) void wqe_k(
    const float* __restrict__ Wq, const float* __restrict__ bq,
    const float* __restrict__ We,
    float* __restrict__ WqeT, float* __restrict__ bqe,
    int* __restrict__ deg, int n)
{
    const int b = blockIdx.x;
    if (b < 256) {
        const int gid = b * 256 + threadIdx.x;      // 0..65535
        const int m = gid >> 9, hc = gid & 511;
        const int h = hc >> 7, c = hc & 127;
        const float* wq = &Wq[(size_t)m * 512 + h * 128];
        const float* we = &We[(size_t)c * 512 + h * 128];
        float s0 = 0.f, s1 = 0.f;
        #pragma unroll 8
        for (int d = 0; d < 128; d += 2) { s0 += wq[d] * we[d]; s1 += wq[d + 1] * we[d + 1]; }
        WqeT[(size_t)m * 512 + hc] = (s0 + s1) * SCALE;
    } else if (b < 258) {
        const int hc = (b - 256) * 256 + threadIdx.x;
        const int h = hc >> 7, c = hc & 127;
        const float* we = &We[(size_t)c * 512 + h * 128];
        const float* bb = &bq[h * 128];
        float s = 0.f;
        #pragma unroll 8
        for (int d = 0; d < 128; ++d) s += bb[d] * we[d];
        bqe[hc] = s * SCALE;
    } else {
        int idx = (b - 258) * 256 + threadIdx.x;
        if (idx < n) deg[idx] = 0;
    }
}

// ---------------- K0b: bf16 conversions + fragment layouts + deg_count ----------------
__global__ __launch_bounds__(256) void prep_k(
    const float* __restrict__ x,
    const float* __restrict__ Wq, const float* __restrict__ bq,
    const float* __restrict__ Wk, const float* __restrict__ bk,
    const float* __restrict__ Wv, const float* __restrict__ bv,
    const float* __restrict__ Ws, const float* __restrict__ bs,
    const float* __restrict__ WqeT, const float* __restrict__ bqe,
    const float* __restrict__ We, const float* __restrict__ Wlin,
    unsigned short* __restrict__ x_bf, unsigned short* __restrict__ Wfrag,
    unsigned short* __restrict__ Wefrag, unsigned short* __restrict__ Wlfrag,
    float* __restrict__ bcat,
    const int* __restrict__ ei, int* __restrict__ deg, int E, int n, int nb1)
{
    const int b = blockIdx.x, t = threadIdx.x;
    if (b < nb1) {                                  // x -> bf16, 4 elems/thread
        int i = (b * 256 + t) * 4;
        if (i < n * 128) {
            float4 v = *(const float4*)&x[i];
            unsigned short o[4] = { f2bf(v.x), f2bf(v.y), f2bf(v.z), f2bf(v.w) };
            *(uint2*)&x_bf[i] = *(uint2*)o;
        }
    } else if (b < nb1 + 160) {                     // Wfrag: [q|k|v|skip|qe] 128x2560
        int g = (b - nb1) * 256 + t;                // (nt*4+kt)*64+lane, nt<160
        int lane = g & 63, kt = (g >> 6) & 3, nt = g >> 8;
        int ncol = nt * 16 + (lane & 15);
        int k0 = kt * 32 + ((lane >> 4) << 3);
        const float* W; int c; float sc = 1.f;
        if      (ncol < 512)  { W = Wq;   c = ncol; sc = SCALE; }
        else if (ncol < 1024) { W = Wk;   c = ncol - 512; }
        else if (ncol < 1536) { W = Wv;   c = ncol - 1024; }
        else if (ncol < 2048) { W = Ws;   c = ncol - 1536; }
        else                  { W = WqeT; c = ncol - 2048; }
        unsigned short o[8];
        #pragma unroll
        for (int j = 0; j < 8; ++j) o[j] = f2bf(W[(size_t)(k0 + j) * 512 + c] * sc);
        *(uint4*)&Wfrag[(size_t)g * 8] = *(uint4*)o;
    } else if (b < nb1 + 192) {                     // Wefrag: We 128x512
        int g = (b - nb1 - 160) * 256 + t;          // nt<32, kt<4
        int lane = g & 63, kt = (g >> 6) & 3, nt = g >> 8;
        int ncol = nt * 16 + (lane & 15);
        int k0 = kt * 32 + ((lane >> 4) << 3);
        unsigned short o[8];
        #pragma unroll
        for (int j = 0; j < 8; ++j) o[j] = f2bf(We[(size_t)(k0 + j) * 512 + ncol]);
        *(uint4*)&Wefrag[(size_t)g * 8] = *(uint4*)o;
    } else if (b < nb1 + 224) {                     // Wlfrag: Wlin 512x128
        int g = (b - nb1 - 192) * 256 + t;          // (nt*16+kt)*64+lane, nt<8, kt<16
        int lane = g & 63, kt = (g >> 6) & 15, nt = g >> 10;
        int ncol = nt * 16 + (lane & 15);
        int k0 = kt * 32 + ((lane >> 4) << 3);
        unsigned short o[8];
        #pragma unroll
        for (int j = 0; j < 8; ++j) o[j] = f2bf(Wlin[(size_t)(k0 + j) * 128 + ncol]);
        *(uint4*)&Wlfrag[(size_t)g * 8] = *(uint4*)o;
    } else if (b < nb1 + 234) {                     // bcat[2560]
        int c = (b - nb1 - 224) * 256 + t;
        if (c < 2560)
            bcat[c] = (c < 512) ? bq[c] * SCALE : (c < 1024) ? bk[c - 512]
                     : (c < 1536) ? bv[c - 1024] : (c < 2048) ? bs[c - 1536] : bqe[c - 2048];
    } else {                                        // deg_count
        int e = (b - nb1 - 234) * 256 + t;
        if (e < E) atomicAdd(&deg[ei[E + e]], 1);
    }
}

// ---------------- K2: exclusive scan of deg -> row_start, cursor ----------------
__global__ __launch_bounds__(1024) void scan_k(const int* __restrict__ deg,
                                               int* __restrict__ row_start,
                                               int* __restrict__ cursor, int n)
{
    __shared__ int part[1024];
    const int t = threadIdx.x;
    const int c0 = t * 16;                  // supports n <= 16384
    int loc[16];
    int s = 0;
    #pragma unroll
    for (int i = 0; i < 16; ++i) {
        int idx = c0 + i;
        int dv = (idx < n) ? deg[idx] : 0;
        loc[i] = s; s += dv;
    }
    part[t] = s;
    __syncthreads();
    int incl = s;
    for (int off = 1; off < 1024; off <<= 1) {
        int other = (t >= off) ? part[t - off] : 0;
        __syncthreads();
        incl += other;
        part[t] = incl;
        __syncthreads();
    }
    const int base = incl - s;
    #pragma unroll
    for (int i = 0; i < 16; ++i) {
        int idx = c0 + i;
        if (idx < n) { row_start[idx] = base + loc[i]; cursor[idx] = base + loc[i]; }
    }
    if (t == 1023) row_start[n] = incl;
}

// ---------------- K3: node GEMM (bf16 MFMA, no LDS) + CSR scatter slice ----------------
// skip -> qs f32 [n][512]; q,k,v,qe -> kvq bf16 [n][2048]
__global__ __launch_bounds__(256) void node_gemm_mfma(
    const unsigned short* __restrict__ x_bf, const unsigned short* __restrict__ Wfrag,
    const float* __restrict__ bcat, float* __restrict__ qs,
    unsigned short* __restrict__ kvq,
    const int* __restrict__ ei, int* __restrict__ cursor, int2* __restrict__ csr,
    int E, int n)
{
    if (blockIdx.y == 40) {                         // scatter slice
        const int nth = gridDim.x * 256;
        for (int e = blockIdx.x * 256 + threadIdx.x; e < E; e += nth) {
            int dnode = ei[E + e];
            int p = atomicAdd(&cursor[dnode], 1);
            csr[p] = make_int2(e, ei[e]);           // (eid, src)
        }
        return;
    }
    const int t = threadIdx.x, lane = t & 63, w = t >> 6;
    const int m0 = blockIdx.x * 64 + (w >> 1) * 32;
    const int n0 = blockIdx.y * 64 + (w & 1) * 32;
    const int lr = lane & 15, lk = (lane >> 4) << 3;
    f32x4 acc[2][2] = {};
    #pragma unroll
    for (int kt = 0; kt < 4; ++kt) {
        bf16x8 a[2], bf[2];
        #pragma unroll
        for (int mi = 0; mi < 2; ++mi) {
            int row = m0 + mi * 16 + lr; row = row < n ? row : n - 1;
            a[mi] = *(const bf16x8*)&x_bf[(size_t)row * 128 + kt * 32 + lk];
        }
        #pragma unroll
        for (int ni = 0; ni < 2; ++ni) {
            int nt = (n0 + ni * 16) >> 4;
            bf[ni] = *(const bf16x8*)&Wfrag[(size_t)((nt * 4 + kt) * 64 + lane) * 8];
        }
        #pragma unroll
        for (int mi = 0; mi < 2; ++mi)
            #pragma unroll
            for (int ni = 0; ni < 2; ++ni)
                acc[mi][ni] = __builtin_amdgcn_mfma_f32_16x16x32_bf16(a[mi], bf[ni], acc[mi][ni], 0, 0, 0);
    }
    #pragma unroll
    for (int mi = 0; mi < 2; ++mi)
        #pragma unroll
        for (int j = 0; j < 4; ++j) {
            int row = m0 + mi * 16 + (lane >> 4) * 4 + j;
            if (row < n) {
                #pragma unroll
                for (int ni = 0; ni < 2; ++ni) {
                    int col = n0 + ni * 16 + lr;
                    float val = acc[mi][ni][j] + bcat[col];
                    if (col < 1536)       kvq[(size_t)row * 2048 + col] = f2bf(val);        // q,k,v
                    else if (col < 2048)  qs[(size_t)row * 512 + col - 1536] = val;         // skip
                    else                  kvq[(size_t)row * 2048 + col - 512] = f2bf(val);  // qe
                }
            }
        }
}

// ---------------- K5: flash-style edge phase, 2 waves/node + LDS merge, unroll-4 ----------
// Block = 4 waves = 2 nodes. Wave pair (slot, half). 4 lane-groups x 16 lanes per wave:
// group g owns head g, lane owns 8 dims. Each half processes a contiguous edge range.
__global__ __launch_bounds__(256, 4) void edge_k(
    const unsigned short* __restrict__ kvq, const float* __restrict__ ea,
    const float* __restrict__ be,
    const int* __restrict__ row_start, const int2* __restrict__ csr,
    unsigned short* __restrict__ wsum_bf, unsigned short* __restrict__ vacc_bf, int n)
{
    const int t = threadIdx.x, lane = t & 63, w = t >> 6;
    const int slot = w >> 1, half = w & 1;
    const int node = blockIdx.x * 2 + slot;
    const bool nvalid = node < n;
    const int nodec = nvalid ? node : 0;
    const int g = lane >> 4;            // head
    const int l15 = lane & 15;
    const int sl = l15 * 8;             // dim slice within head

    __shared__ float lds_m[2][4], lds_den[2][4];
    __shared__ float lds_va[2][4][128], lds_ws[2][4][128];

    int rs = 0, deg = 0;
    if (nvalid) { rs = row_start[node]; deg = row_start[node + 1] - rs; }
    const int dh = (deg + 1) >> 1;
    const int lo = half ? dh : 0;
    const int myc = half ? (deg - dh) : dh;

    // per-lane q_s, qe_s (pre-scaled, bf16)
    float q8[8], qe8[8];
    {
        const u16x8 uq  = *(const u16x8*)&kvq[(size_t)nodec * 2048 + g * 128 + sl];
        const u16x8 uqe = *(const u16x8*)&kvq[(size_t)nodec * 2048 + 1536 + g * 128 + sl];
        #pragma unroll
        for (int i = 0; i < 8; ++i) { q8[i] = bf2f(uq[i]); qe8[i] = bf2f(uqe[i]); }
    }
    float qbe;
    {
        const float* bp = &be[g * 128 + sl];
        float pb = 0.f;
        #pragma unroll
        for (int i = 0; i < 8; ++i) pb += q8[i] * bp[i];
        #pragma unroll
        for (int o = 1; o <= 8; o <<= 1) pb += __shfl_xor(pb, o);
        qbe = pb;
    }

    float m = -3.0e38f, den = 0.f;
    float va[8] = {}, ws[8] = {};

    for (int j0 = 0; j0 < myc; j0 += 64) {
        const int cnt = min(64, myc - j0);
        int2 my = make_int2(0, 0);
        if (lane < cnt) my = csr[rs + lo + j0 + lane];
        for (int jj = 0; jj < cnt; jj += 4) {
            const int i1 = min(jj + 1, cnt - 1), i2 = min(jj + 2, cnt - 1), i3 = min(jj + 3, cnt - 1);
            const bool b1 = jj + 1 < cnt, b2 = jj + 2 < cnt, b3 = jj + 3 < cnt;
            const int e0 = __shfl(my.x, jj), s0_ = __shfl(my.y, jj);
            const int e1 = __shfl(my.x, i1), s1_ = __shfl(my.y, i1);
            const int e2 = __shfl(my.x, i2), s2_ = __shfl(my.y, i2);
            const int e3 = __shfl(my.x, i3), s3_ = __shfl(my.y, i3);
            // 16 independent loads issue together (needs the 128-VGPR budget)
            const float* ep0 = &ea[(size_t)e0 * 128 + sl];
            const float* ep1 = &ea[(size_t)e1 * 128 + sl];
            const float* ep2 = &ea[(size_t)e2 * 128 + sl];
            const float* ep3 = &ea[(size_t)e3 * 128 + sl];
            float4 A0 = *(const float4*)ep0, B0 = *(const float4*)(ep0 + 4);
            float4 A1 = *(const float4*)ep1, B1 = *(const float4*)(ep1 + 4);
            float4 A2 = *(const float4*)ep2, B2 = *(const float4*)(ep2 + 4);
            float4 A3 = *(const float4*)ep3, B3 = *(const float4*)(ep3 + 4);
            const u16x8 K0 = *(const u16x8*)&kvq[(size_t)s0_ * 2048 + 512 + g * 128 + sl];
            const u16x8 V0 = *(const u16x8*)&kvq[(size_t)s0_ * 2048 + 1024 + g * 128 + sl];
            const u16x8 K1 = *(const u16x8*)&kvq[(size_t)s1_ * 2048 + 512 + g * 128 + sl];
            const u16x8 V1 = *(const u16x8*)&kvq[(size_t)s1_ * 2048 + 1024 + g * 128 + sl];
            const u16x8 K2 = *(const u16x8*)&kvq[(size_t)s2_ * 2048 + 512 + g * 128 + sl];
            const u16x8 V2 = *(const u16x8*)&kvq[(size_t)s2_ * 2048 + 1024 + g * 128 + sl];
            const u16x8 K3 = *(const u16x8*)&kvq[(size_t)s3_ * 2048 + 512 + g * 128 + sl];
            const u16x8 V3 = *(const u16x8*)&kvq[(size_t)s3_ * 2048 + 1024 + g * 128 + sl];
            float ef0[8] = {A0.x, A0.y, A0.z, A0.w, B0.x, B0.y, B0.z, B0.w};
            float ef1[8] = {A1.x, A1.y, A1.z, A1.w, B1.x, B1.y, B1.z, B1.w};
            float ef2[8] = {A2.x, A2.y, A2.z, A2.w, B2.x, B2.y, B2.z, B2.w};
            float ef3[8] = {A3.x, A3.y, A3.z, A3.w, B3.x, B3.y, B3.z, B3.w};
            float p0 = 0.f, p1 = 0.f, p2 = 0.f, p3 = 0.f;
            #pragma unroll
            for (int i = 0; i < 8; ++i) {
                p0 += q8[i] * bf2f(K0[i]) + qe8[i] * ef0[i];
                p1 += q8[i] * bf2f(K1[i]) + qe8[i] * ef1[i];
                p2 += q8[i] * bf2f(K2[i]) + qe8[i] * ef2[i];
                p3 += q8[i] * bf2f(K3[i]) + qe8[i] * ef3[i];
            }
            #pragma unroll
            for (int o = 1; o <= 8; o <<= 1) {
                p0 += __shfl_xor(p0, o); p1 += __shfl_xor(p1, o);
                p2 += __shfl_xor(p2, o); p3 += __shfl_xor(p3, o);
            }
            const float a0 = p0 + qbe;
            const float a1 = b1 ? (p1 + qbe) : -3.0e38f;
            const float a2 = b2 ? (p2 + qbe) : -3.0e38f;
            const float a3 = b3 ? (p3 + qbe) : -3.0e38f;
            // one deferred-max rescale per 4 edges (THR=8)
            const float gm = fmaxf(fmaxf(a0, a1), fmaxf(a2, a3));
            if (gm > m + 8.f) {
                const float sc = __expf(m - gm);
                den *= sc;
                #pragma unroll
                for (int i = 0; i < 8; ++i) { va[i] *= sc; ws[i] *= sc; }
                m = gm;
            }
            const float w0 = __expf(a0 - m);
            const float w1 = __expf(a1 - m);
            const float w2 = __expf(a2 - m);
            const float w3 = __expf(a3 - m);
            den += (w0 + w1) + (w2 + w3);
            #pragma unroll
            for (int i = 0; i < 8; ++i) {
                va[i] += (w0 * bf2f(V0[i]) + w1 * bf2f(V1[i])) + (w2 * bf2f(V2[i]) + w3 * bf2f(V3[i]));
                ws[i] += (w0 * ef0[i] + w1 * ef1[i]) + (w2 * ef2[i] + w3 * ef3[i]);
            }
        }
    }

    // merge halves: half 1 publishes, half 0 combines and writes out
    if (half == 1) {
        if (l15 == 0) { lds_m[slot][g] = m; lds_den[slot][g] = den; }
        #pragma unroll
        for (int i = 0; i < 8; ++i) {
            lds_va[slot][g][sl + i] = va[i];
            lds_ws[slot][g][sl + i] = ws[i];
        }
    }
    __syncthreads();
    if (half == 0 && nvalid) {
        const float m1 = lds_m[slot][g], den1 = lds_den[slot][g];
        const float M = fmaxf(m, m1);
        const float s0 = __expf(m - M), s1 = __expf(m1 - M);
        const float dtot = den * s0 + den1 * s1;
        const float rden = (dtot > 0.f) ? 1.f / dtot : 0.f;
        unsigned short vo[8], wo[8];
        #pragma unroll
        for (int i = 0; i < 8; ++i) {
            vo[i] = f2bf((va[i] * s0 + lds_va[slot][g][sl + i] * s1) * rden);
            wo[i] = f2bf((ws[i] * s0 + lds_ws[slot][g][sl + i] * s1) * rden);
        }
        *(uint4*)&vacc_bf[(size_t)node * 512 + g * 128 + sl] = *(uint4*)vo;
        *(uint4*)&wsum_bf[(size_t)node * 512 + g * 128 + sl] = *(uint4*)wo;
    }
}

// ---------------- K6: fused tail: y = vacc + wsum@We_h + hb*be + skip; LN; out-GEMM; ELU --
// 16 rows/block, 4 waves; wave w = head w for stage 1, cols [w*32,w*32+32) for stage 2.
__global__ __launch_bounds__(256) void tail_k(
    const unsigned short* __restrict__ wsum_bf, const unsigned short* __restrict__ Wefrag,
    const float* __restrict__ be, const unsigned short* __restrict__ vacc_bf,
    const float* __restrict__ qs, const int* __restrict__ row_start,
    const unsigned short* __restrict__ Wlfrag, const float* __restrict__ lng,
    const float* __restrict__ lnb, const float* __restrict__ blin,
    const float* __restrict__ x, float* __restrict__ out, int n)
{
    const int t = threadIdx.x, lane = t & 63, w = t >> 6;
    const int r0 = blockIdx.x * 16;
    const int lr = lane & 15, lk = (lane >> 4) << 3;
    __shared__ unsigned short nlds[16][520];        // normed bf16, +8 pad (16B-aligned rows)
    __shared__ float red_s[4][16], red_q[4][16], mval[16], rval[16];

    // ---- stage 1: wave w computes 16 rows x head-w cols of y
    f32x4 acc[8] = {};
    #pragma unroll
    for (int kt = 0; kt < 4; ++kt) {
        int row = r0 + lr; row = row < n ? row : n - 1;
        bf16x8 a = *(const bf16x8*)&wsum_bf[(size_t)row * 512 + w * 128 + kt * 32 + lk];
        #pragma unroll
        for (int ni = 0; ni < 8; ++ni) {
            bf16x8 bfr = *(const bf16x8*)&Wefrag[(size_t)(((w * 8 + ni) * 4 + kt) * 64 + lane) * 8];
            acc[ni] = __builtin_amdgcn_mfma_f32_16x16x32_bf16(a, bfr, acc[ni], 0, 0, 0);
        }
    }
    float g8[8], b8[8];
    #pragma unroll
    for (int ni = 0; ni < 8; ++ni) { int col = w * 128 + ni * 16 + lr; g8[ni] = lng[col]; b8[ni] = lnb[col]; }
    float sum_[4], sq_[4];
    #pragma unroll
    for (int j = 0; j < 4; ++j) {
        int row = r0 + (lane >> 4) * 4 + j;
        int rowc = row < n ? row : n - 1;
        const float hb = (row_start[rowc + 1] > row_start[rowc]) ? 1.f : 0.f;
        float s = 0.f, q = 0.f;
        #pragma unroll
        for (int ni = 0; ni < 8; ++ni) {
            int col = w * 128 + ni * 16 + lr;
            float y = acc[ni][j] + bf2f(vacc_bf[(size_t)rowc * 512 + col]) + hb * be[col]
                    + qs[(size_t)rowc * 512 + col];
            acc[ni][j] = y;
            s += y; q += y * y;
        }
        sum_[j] = s; sq_[j] = q;
    }
    #pragma unroll
    for (int o = 1; o <= 8; o <<= 1) {
        #pragma unroll
        for (int j = 0; j < 4; ++j) { sum_[j] += __shfl_xor(sum_[j], o); sq_[j] += __shfl_xor(sq_[j], o); }
    }
    if (lr == 0) {
        #pragma unroll
        for (int j = 0; j < 4; ++j) {
            red_s[w][(lane >> 4) * 4 + j] = sum_[j];
            red_q[w][(lane >> 4) * 4 + j] = sq_[j];
        }
    }
    __syncthreads();
    if (t < 16) {
        float S = red_s[0][t] + red_s[1][t] + red_s[2][t] + red_s[3][t];
        float Q = red_q[0][t] + red_q[1][t] + red_q[2][t] + red_q[3][t];
        float mu = S * (1.f / 512.f);
        float var = Q * (1.f / 512.f) - mu * mu;
        mval[t] = mu;
        rval[t] = rsqrtf(fmaxf(var, 0.f) + 1e-5f);
    }
    __syncthreads();
    #pragma unroll
    for (int j = 0; j < 4; ++j) {
        int rowl = (lane >> 4) * 4 + j;
        float mu = mval[rowl], rv = rval[rowl];
        #pragma unroll
        for (int ni = 0; ni < 8; ++ni) {
            int col = w * 128 + ni * 16 + lr;
            nlds[rowl][col] = f2bf((acc[ni][j] - mu) * rv * g8[ni] + b8[ni]);
        }
    }
    __syncthreads();
    // ---- stage 2: out = elu(nlds @ Wlin + blin + x), wave w covers cols [w*32, w*32+32)
    f32x4 acc2[2] = {};
    #pragma unroll
    for (int kt = 0; kt < 16; ++kt) {
        bf16x8 a2 = *(const bf16x8*)&nlds[lr][kt * 32 + lk];
        #pragma unroll
        for (int ni = 0; ni < 2; ++ni) {
            bf16x8 bfr = *(const bf16x8*)&Wlfrag[(size_t)(((w * 2 + ni) * 16 + kt) * 64 + lane) * 8];
            acc2[ni] = __builtin_amdgcn_mfma_f32_16x16x32_bf16(a2, bfr, acc2[ni], 0, 0, 0);
        }
    }
    #pragma unroll
    for (int j = 0; j < 4; ++j) {
        int row = r0 + (lane >> 4) * 4 + j;
        if (row < n) {
            #pragma unroll
            for (int ni = 0; ni < 2; ++ni) {
                int col = w * 32 + ni * 16 + lr;
                float z = acc2[ni][j] + blin[col] + x[(size_t)row * 128 + col];
                out[(size_t)row * 128 + col] = z > 0.f ? z : expm1f(z);
            }
        }
    }
}

extern "C" void kernel_launch(void* const* d_in, const int* in_sizes, int n_in,
                              void* d_out, int out_size, void* d_ws, size_t ws_size,
                              hipStream_t stream)
{
    const float* x   = (const float*)d_in[0];
    const int*   ei  = (const int*)d_in[1];
    const float* ea  = (const float*)d_in[2];
    const float* Wq  = (const float*)d_in[3];
    const float* bq  = (const float*)d_in[4];
    const float* Wk  = (const float*)d_in[5];
    const float* bk  = (const float*)d_in[6];
    const float* Wv  = (const float*)d_in[7];
    const float* bv  = (const float*)d_in[8];
    const float* We  = (const float*)d_in[9];
    const float* be  = (const float*)d_in[10];
    const float* Wsk = (const float*)d_in[11];
    const float* bsk = (const float*)d_in[12];
    const float* lng = (const float*)d_in[13];
    const float* lnb = (const float*)d_in[14];
    const float* Wl  = (const float*)d_in[15];
    const float* bl  = (const float*)d_in[16];
    float* out = (float*)d_out;

    const int n = in_sizes[0] / 128;
    const int E = in_sizes[1] / 2;

    float* qs    = (float*)d_ws;                    // n*512 (skip)
    float* WqeT  = qs + (size_t)n * 512;            // 128*512
    float* bqe   = WqeT + 128 * 512;                // 512
    float* bcat  = bqe + 512;                       // 2560
    unsigned short* x_bf    = (unsigned short*)(bcat + 2560);   // n*128
    unsigned short* wsum_bf = x_bf + (size_t)n * 128;           // n*512
    unsigned short* vacc_bf = wsum_bf + (size_t)n * 512;        // n*512
    unsigned short* kvq     = vacc_bf + (size_t)n * 512;        // n*2048 (q|k|v|qe)
    unsigned short* Wfrag   = kvq + (size_t)n * 2048;           // 128*2560
    unsigned short* Wefrag  = Wfrag + 128 * 2560;               // 128*512
    unsigned short* Wlfrag  = Wefrag + 128 * 512;               // 512*128
    int2* csr = (int2*)(((uintptr_t)(Wlfrag + 512 * 128) + 7) & ~(uintptr_t)7);  // E pairs
    int* deg       = (int*)(csr + E);
    int* row_start = deg + n;
    int* cursor    = row_start + n + 1;

    const int ndegb = (n + 255) / 256;
    wqe_k<<<258 + ndegb, 256, 0, stream>>>(Wq, bq, We, WqeT, bqe, deg, n);
    const int nb1 = (n * 32 + 255) / 256;           // x-conversion blocks (4 elems/thread)
    const int ndc = (E + 255) / 256;
    prep_k<<<nb1 + 234 + ndc, 256, 0, stream>>>(x, Wq, bq, Wk, bk, Wv, bv, Wsk, bsk, WqeT, bqe,
                                                We, Wl, x_bf, Wfrag, Wefrag, Wlfrag, bcat,
                                                ei, deg, E, n, nb1);
    scan_k<<<1, 1024, 0, stream>>>(deg, row_start, cursor, n);
    dim3 g1((n + 63) / 64, 41);
    node_gemm_mfma<<<g1, 256, 0, stream>>>(x_bf, Wfrag, bcat, qs, kvq, ei, cursor, csr, E, n);
    edge_k<<<(n + 1) / 2, 256, 0, stream>>>(kvq, ea, be, row_start, csr,
                                            wsum_bf, vacc_bf, n);
    tail_k<<<(n + 15) / 16, 256, 0, stream>>>(wsum_bf, Wefrag, be, vacc_bf, qs, row_start,
                                              Wlfrag, lng, lnb, bl, x, out, n);
}

// Round 8
// 171.072 us; speedup vs baseline: 8.7270x; 1.0593x over previous
//
#include <hip/hip_runtime.h>
#include <math.h>

// UniMP / TransformerConv block. bf16-MFMA GEMMs, single-pass flash-style edge phase
// (2 waves/node + LDS online-softmax merge, unroll-2 + 1-deep software pipeline),
// fused tail (GEMM+LN+GEMM+ELU).
//   alpha = q_s.k + ea.qe_s + q_s.be   (scale 1/sqrt(D) folded into Wq/WqeT/bqe)
//   agg   = sum attn*v[src] + (sum attn*ea) @ We_h + be_h
// Node tensors: qs f32 [n][512] = skip, kvq bf16 [n][2048] = [q|k|v|qe]
// 6 kernels: wqe(+degzero) -> prep(+degcount) -> scan -> node_gemm(+scatter) -> edge -> tail

typedef short bf16x8 __attribute__((ext_vector_type(8)));
typedef unsigned short u16x8 __attribute__((ext_vector_type(8)));
typedef float f32x4 __attribute__((ext_vector_type(4)));

#define SCALE 0.08838834764831845f  // 1/sqrt(128)

__device__ inline unsigned short f2bf(float f) {
    union { float f; unsigned u; } v; v.f = f;
    unsigned r = (v.u + 0x7FFFu + ((v.u >> 16) & 1u)) >> 16;
    return (unsigned short)r;
}
__device__ inline float bf2f(unsigned short u) {
    union { unsigned u; float f; } v; v.u = ((unsigned)u) << 16; return v.f;
}

// ---------------- K0: WqeT = s*Wq@We^T; bqe = s*bq@We^T; zero deg ----------------
__global__ __launch_bounds__(256) void wqe_k(
    const float* __restrict__ Wq, const float* __restrict__ bq,
    const float* __restrict__ We,
    float* __restrict__ WqeT, float* __restrict__ bqe,
    int* __restrict__ deg, int n)
{
    const int b = blockIdx.x;
    if (b < 256) {
        const int gid = b * 256 + threadIdx.x;      // 0..65535
        const int m = gid >> 9, hc = gid & 511;
        const int h = hc >> 7, c = hc & 127;
        const float* wq = &Wq[(size_t)m * 512 + h * 128];
        const float* we = &We[(size_t)c * 512 + h * 128];
        float s0 = 0.f, s1 = 0.f;
        #pragma unroll 8
        for (int d = 0; d < 128; d += 2) { s0 += wq[d] * we[d]; s1 += wq[d + 1] * we[d + 1]; }
        WqeT[(size_t)m * 512 + hc] = (s0 + s1) * SCALE;
    } else if (b < 258) {
        const int hc = (b - 256) * 256 + threadIdx.x;
        const int h = hc >> 7, c = hc & 127;
        const float* we = &We[(size_t)c * 512 + h * 128];
        const float* bb = &bq[h * 128];
        float s = 0.f;
        #pragma unroll 8
        for (int d = 0; d < 128; ++d) s += bb[d] * we[d];
        bqe[hc] = s * SCALE;
    } else {
        int idx = (b - 258) * 256 + threadIdx.x;
        if (idx < n) deg[idx] = 0;
    }
}

// ---------------- K0b: bf16 conversions + fragment layouts + deg_count ----------------
__global__ __launch_bounds__(256) void prep_k(
    const float* __restrict__ x,
    const float* __restrict__ Wq, const float* __restrict__ bq,
    const float* __restrict__ Wk, const float* __restrict__ bk,
    const float* __restrict__ Wv, const float* __restrict__ bv,
    const float* __restrict__ Ws, const float* __restrict__ bs,
    const float* __restrict__ WqeT, const float* __restrict__ bqe,
    const float* __restrict__ We, const float* __restrict__ Wlin,
    unsigned short* __restrict__ x_bf, unsigned short* __restrict__ Wfrag,
    unsigned short* __restrict__ Wefrag, unsigned short* __restrict__ Wlfrag,
    float* __restrict__ bcat,
    const int* __restrict__ ei, int* __restrict__ deg, int E, int n, int nb1)
{
    const int b = blockIdx.x, t = threadIdx.x;
    if (b < nb1) {                                  // x -> bf16, 4 elems/thread
        int i = (b * 256 + t) * 4;
        if (i < n * 128) {
            float4 v = *(const float4*)&x[i];
            unsigned short o[4] = { f2bf(v.x), f2bf(v.y), f2bf(v.z), f2bf(v.w) };
            *(uint2*)&x_bf[i] = *(uint2*)o;
        }
    } else if (b < nb1 + 160) {                     // Wfrag: [q|k|v|skip|qe] 128x2560
        int g = (b - nb1) * 256 + t;                // (nt*4+kt)*64+lane, nt<160
        int lane = g & 63, kt = (g >> 6) & 3, nt = g >> 8;
        int ncol = nt * 16 + (lane & 15);
        int k0 = kt * 32 + ((lane >> 4) << 3);
        const float* W; int c; float sc = 1.f;
        if      (ncol < 512)  { W = Wq;   c = ncol; sc = SCALE; }
        else if (ncol < 1024) { W = Wk;   c = ncol - 512; }
        else if (ncol < 1536) { W = Wv;   c = ncol - 1024; }
        else if (ncol < 2048) { W = Ws;   c = ncol - 1536; }
        else                  { W = WqeT; c = ncol - 2048; }
        unsigned short o[8];
        #pragma unroll
        for (int j = 0; j < 8; ++j) o[j] = f2bf(W[(size_t)(k0 + j) * 512 + c] * sc);
        *(uint4*)&Wfrag[(size_t)g * 8] = *(uint4*)o;
    } else if (b < nb1 + 192) {                     // Wefrag: We 128x512
        int g = (b - nb1 - 160) * 256 + t;          // nt<32, kt<4
        int lane = g & 63, kt = (g >> 6) & 3, nt = g >> 8;
        int ncol = nt * 16 + (lane & 15);
        int k0 = kt * 32 + ((lane >> 4) << 3);
        unsigned short o[8];
        #pragma unroll
        for (int j = 0; j < 8; ++j) o[j] = f2bf(We[(size_t)(k0 + j) * 512 + ncol]);
        *(uint4*)&Wefrag[(size_t)g * 8] = *(uint4*)o;
    } else if (b < nb1 + 224) {                     // Wlfrag: Wlin 512x128
        int g = (b - nb1 - 192) * 256 + t;          // (nt*16+kt)*64+lane, nt<8, kt<16
        int lane = g & 63, kt = (g >> 6) & 15, nt = g >> 10;
        int ncol = nt * 16 + (lane & 15);
        int k0 = kt * 32 + ((lane >> 4) << 3);
        unsigned short o[8];
        #pragma unroll
        for (int j = 0; j < 8; ++j) o[j] = f2bf(Wlin[(size_t)(k0 + j) * 128 + ncol]);
        *(uint4*)&Wlfrag[(size_t)g * 8] = *(uint4*)o;
    } else if (b < nb1 + 234) {                     // bcat[2560]
        int c = (b - nb1 - 224) * 256 + t;
        if (c < 2560)
            bcat[c] = (c < 512) ? bq[c] * SCALE : (c < 1024) ? bk[c - 512]
                     : (c < 1536) ? bv[c - 1024] : (c < 2048) ? bs[c - 1536] : bqe[c - 2048];
    } else {                                        // deg_count
        int e = (b - nb1 - 234) * 256 + t;
        if (e < E) atomicAdd(&deg[ei[E + e]], 1);
    }
}

// ---------------- K2: exclusive scan of deg -> row_start, cursor ----------------
__global__ __launch_bounds__(1024) void scan_k(const int* __restrict__ deg,
                                               int* __restrict__ row_start,
                                               int* __restrict__ cursor, int n)
{
    __shared__ int part[1024];
    const int t = threadIdx.x;
    const int c0 = t * 16;                  // supports n <= 16384
    int loc[16];
    int s = 0;
    #pragma unroll
    for (int i = 0; i < 16; ++i) {
        int idx = c0 + i;
        int dv = (idx < n) ? deg[idx] : 0;
        loc[i] = s; s += dv;
    }
    part[t] = s;
    __syncthreads();
    int incl = s;
    for (int off = 1; off < 1024; off <<= 1) {
        int other = (t >= off) ? part[t - off] : 0;
        __syncthreads();
        incl += other;
        part[t] = incl;
        __syncthreads();
    }
    const int base = incl - s;
    #pragma unroll
    for (int i = 0; i < 16; ++i) {
        int idx = c0 + i;
        if (idx < n) { row_start[idx] = base + loc[i]; cursor[idx] = base + loc[i]; }
    }
    if (t == 1023) row_start[n] = incl;
}

// ---------------- K3: node GEMM (bf16 MFMA, no LDS) + CSR scatter slice ----------------
// skip -> qs f32 [n][512]; q,k,v,qe -> kvq bf16 [n][2048]
__global__ __launch_bounds__(256) void node_gemm_mfma(
    const unsigned short* __restrict__ x_bf, const unsigned short* __restrict__ Wfrag,
    const float* __restrict__ bcat, float* __restrict__ qs,
    unsigned short* __restrict__ kvq,
    const int* __restrict__ ei, int* __restrict__ cursor, int2* __restrict__ csr,
    int E, int n)
{
    if (blockIdx.y == 40) {                         // scatter slice
        const int nth = gridDim.x * 256;
        for (int e = blockIdx.x * 256 + threadIdx.x; e < E; e += nth) {
            int dnode = ei[E + e];
            int p = atomicAdd(&cursor[dnode], 1);
            csr[p] = make_int2(e, ei[e]);           // (eid, src)
        }
        return;
    }
    const int t = threadIdx.x, lane = t & 63, w = t >> 6;
    const int m0 = blockIdx.x * 64 + (w >> 1) * 32;
    const int n0 = blockIdx.y * 64 + (w & 1) * 32;
    const int lr = lane & 15, lk = (lane >> 4) << 3;
    f32x4 acc[2][2] = {};
    #pragma unroll
    for (int kt = 0; kt < 4; ++kt) {
        bf16x8 a[2], bf[2];
        #pragma unroll
        for (int mi = 0; mi < 2; ++mi) {
            int row = m0 + mi * 16 + lr; row = row < n ? row : n - 1;
            a[mi] = *(const bf16x8*)&x_bf[(size_t)row * 128 + kt * 32 + lk];
        }
        #pragma unroll
        for (int ni = 0; ni < 2; ++ni) {
            int nt = (n0 + ni * 16) >> 4;
            bf[ni] = *(const bf16x8*)&Wfrag[(size_t)((nt * 4 + kt) * 64 + lane) * 8];
        }
        #pragma unroll
        for (int mi = 0; mi < 2; ++mi)
            #pragma unroll
            for (int ni = 0; ni < 2; ++ni)
                acc[mi][ni] = __builtin_amdgcn_mfma_f32_16x16x32_bf16(a[mi], bf[ni], acc[mi][ni], 0, 0, 0);
    }
    #pragma unroll
    for (int mi = 0; mi < 2; ++mi)
        #pragma unroll
        for (int j = 0; j < 4; ++j) {
            int row = m0 + mi * 16 + (lane >> 4) * 4 + j;
            if (row < n) {
                #pragma unroll
                for (int ni = 0; ni < 2; ++ni) {
                    int col = n0 + ni * 16 + lr;
                    float val = acc[mi][ni][j] + bcat[col];
                    if (col < 1536)       kvq[(size_t)row * 2048 + col] = f2bf(val);        // q,k,v
                    else if (col < 2048)  qs[(size_t)row * 512 + col - 1536] = val;         // skip
                    else                  kvq[(size_t)row * 2048 + col - 512] = f2bf(val);  // qe
                }
            }
        }
}

// ---------------- K5: flash-style edge phase, 2 waves/node + LDS merge ----------------
// unroll-2 + 1-deep software pipeline (issue next pair's loads before computing current).
// Block = 4 waves = 2 nodes. Wave pair (slot, half). 4 lane-groups x 16 lanes per wave:
// group g owns head g, lane owns 8 dims. Each half processes a contiguous edge range.
__global__ __launch_bounds__(256, 4) void edge_k(
    const unsigned short* __restrict__ kvq, const float* __restrict__ ea,
    const float* __restrict__ be,
    const int* __restrict__ row_start, const int2* __restrict__ csr,
    unsigned short* __restrict__ wsum_bf, unsigned short* __restrict__ vacc_bf, int n)
{
    const int t = threadIdx.x, lane = t & 63, w = t >> 6;
    const int slot = w >> 1, half = w & 1;
    const int node = blockIdx.x * 2 + slot;
    const bool nvalid = node < n;
    const int nodec = nvalid ? node : 0;
    const int g = lane >> 4;            // head
    const int l15 = lane & 15;
    const int sl = l15 * 8;             // dim slice within head

    __shared__ float lds_m[2][4], lds_den[2][4];
    __shared__ float lds_va[2][4][128], lds_ws[2][4][128];

    int rs = 0, deg = 0;
    if (nvalid) { rs = row_start[node]; deg = row_start[node + 1] - rs; }
    const int dh = (deg + 1) >> 1;
    const int lo = half ? dh : 0;
    const int myc = half ? (deg - dh) : dh;

    // per-lane q_s, qe_s (pre-scaled, bf16)
    float q8[8], qe8[8];
    {
        const u16x8 uq  = *(const u16x8*)&kvq[(size_t)nodec * 2048 + g * 128 + sl];
        const u16x8 uqe = *(const u16x8*)&kvq[(size_t)nodec * 2048 + 1536 + g * 128 + sl];
        #pragma unroll
        for (int i = 0; i < 8; ++i) { q8[i] = bf2f(uq[i]); qe8[i] = bf2f(uqe[i]); }
    }
    float qbe;
    {
        const float* bp = &be[g * 128 + sl];
        float pb = 0.f;
        #pragma unroll
        for (int i = 0; i < 8; ++i) pb += q8[i] * bp[i];
        #pragma unroll
        for (int o = 1; o <= 8; o <<= 1) pb += __shfl_xor(pb, o);
        qbe = pb;
    }

    float m = -3.0e38f, den = 0.f;
    float va[8] = {}, ws[8] = {};

    for (int j0 = 0; j0 < myc; j0 += 64) {
        const int cnt = min(64, myc - j0);
        int2 my = make_int2(0, 0);
        if (lane < cnt) my = csr[rs + lo + j0 + lane];

        // ---- preload pair 0 (current register set)
        float4 cA0, cB0, cA1, cB1; u16x8 cK0, cV0, cK1, cV1;
        {
            const int i1 = (1 < cnt) ? 1 : 0;
            const int e0 = __shfl(my.x, 0), s0_ = __shfl(my.y, 0);
            const int e1 = __shfl(my.x, i1), s1_ = __shfl(my.y, i1);
            const float* ep0 = &ea[(size_t)e0 * 128 + sl];
            const float* ep1 = &ea[(size_t)e1 * 128 + sl];
            cA0 = *(const float4*)ep0; cB0 = *(const float4*)(ep0 + 4);
            cA1 = *(const float4*)ep1; cB1 = *(const float4*)(ep1 + 4);
            cK0 = *(const u16x8*)&kvq[(size_t)s0_ * 2048 + 512 + g * 128 + sl];
            cV0 = *(const u16x8*)&kvq[(size_t)s0_ * 2048 + 1024 + g * 128 + sl];
            cK1 = *(const u16x8*)&kvq[(size_t)s1_ * 2048 + 512 + g * 128 + sl];
            cV1 = *(const u16x8*)&kvq[(size_t)s1_ * 2048 + 1024 + g * 128 + sl];
        }

        for (int jj = 0; jj < cnt; jj += 2) {
            // ---- issue next pair's loads (hide latency under current compute)
            float4 nA0, nB0, nA1, nB1; u16x8 nK0, nV0, nK1, nV1;
            {
                const int nj = (jj + 2 < cnt) ? jj + 2 : jj;        // clamped; unused on exit
                const int i1 = (nj + 1 < cnt) ? nj + 1 : nj;
                const int e0 = __shfl(my.x, nj), s0_ = __shfl(my.y, nj);
                const int e1 = __shfl(my.x, i1), s1_ = __shfl(my.y, i1);
                const float* ep0 = &ea[(size_t)e0 * 128 + sl];
                const float* ep1 = &ea[(size_t)e1 * 128 + sl];
                nA0 = *(const float4*)ep0; nB0 = *(const float4*)(ep0 + 4);
                nA1 = *(const float4*)ep1; nB1 = *(const float4*)(ep1 + 4);
                nK0 = *(const u16x8*)&kvq[(size_t)s0_ * 2048 + 512 + g * 128 + sl];
                nV0 = *(const u16x8*)&kvq[(size_t)s0_ * 2048 + 1024 + g * 128 + sl];
                nK1 = *(const u16x8*)&kvq[(size_t)s1_ * 2048 + 512 + g * 128 + sl];
                nV1 = *(const u16x8*)&kvq[(size_t)s1_ * 2048 + 1024 + g * 128 + sl];
            }
            // ---- compute with current pair
            const bool two = (jj + 1 < cnt);
            float ef0[8] = {cA0.x, cA0.y, cA0.z, cA0.w, cB0.x, cB0.y, cB0.z, cB0.w};
            float ef1[8] = {cA1.x, cA1.y, cA1.z, cA1.w, cB1.x, cB1.y, cB1.z, cB1.w};
            float p0 = 0.f, p1 = 0.f;
            #pragma unroll
            for (int i = 0; i < 8; ++i) {
                p0 += q8[i] * bf2f(cK0[i]) + qe8[i] * ef0[i];
                p1 += q8[i] * bf2f(cK1[i]) + qe8[i] * ef1[i];
            }
            #pragma unroll
            for (int o = 1; o <= 8; o <<= 1) {
                p0 += __shfl_xor(p0, o);
                p1 += __shfl_xor(p1, o);
            }
            const float a0 = p0 + qbe;
            const float a1 = two ? (p1 + qbe) : -3.0e38f;   // dummy tail: weight 0
            // group-max batched online update (deferred-max THR=8)
            const float gm = fmaxf(a0, a1);
            if (gm > m + 8.f) {
                const float sc = __expf(m - gm);
                den *= sc;
                #pragma unroll
                for (int i = 0; i < 8; ++i) { va[i] *= sc; ws[i] *= sc; }
                m = gm;
            }
            const float w0 = __expf(a0 - m);
            const float w1 = __expf(a1 - m);
            den += w0 + w1;
            #pragma unroll
            for (int i = 0; i < 8; ++i) {
                va[i] += w0 * bf2f(cV0[i]) + w1 * bf2f(cV1[i]);
                ws[i] += w0 * ef0[i] + w1 * ef1[i];
            }
            // ---- rotate pipeline registers
            cA0 = nA0; cB0 = nB0; cA1 = nA1; cB1 = nB1;
            cK0 = nK0; cV0 = nV0; cK1 = nK1; cV1 = nV1;
        }
    }

    // merge halves: half 1 publishes, half 0 combines and writes out
    if (half == 1) {
        if (l15 == 0) { lds_m[slot][g] = m; lds_den[slot][g] = den; }
        #pragma unroll
        for (int i = 0; i < 8; ++i) {
            lds_va[slot][g][sl + i] = va[i];
            lds_ws[slot][g][sl + i] = ws[i];
        }
    }
    __syncthreads();
    if (half == 0 && nvalid) {
        const float m1 = lds_m[slot][g], den1 = lds_den[slot][g];
        const float M = fmaxf(m, m1);
        const float s0 = __expf(m - M), s1 = __expf(m1 - M);
        const float dtot = den * s0 + den1 * s1;
        const float rden = (dtot > 0.f) ? 1.f / dtot : 0.f;
        unsigned short vo[8], wo[8];
        #pragma unroll
        for (int i = 0; i < 8; ++i) {
            vo[i] = f2bf((va[i] * s0 + lds_va[slot][g][sl + i] * s1) * rden);
            wo[i] = f2bf((ws[i] * s0 + lds_ws[slot][g][sl + i] * s1) * rden);
        }
        *(uint4*)&vacc_bf[(size_t)node * 512 + g * 128 + sl] = *(uint4*)vo;
        *(uint4*)&wsum_bf[(size_t)node * 512 + g * 128 + sl] = *(uint4*)wo;
    }
}

// ---------------- K6: fused tail: y = vacc + wsum@We_h + hb*be + skip; LN; out-GEMM; ELU --
// 16 rows/block, 4 waves; wave w = head w for stage 1, cols [w*32,w*32+32) for stage 2.
__global__ __launch_bounds__(256) void tail_k(
    const unsigned short* __restrict__ wsum_bf, const unsigned short* __restrict__ Wefrag,
    const float* __restrict__ be, const unsigned short* __restrict__ vacc_bf,
    const float* __restrict__ qs, const int* __restrict__ row_start,
    const unsigned short* __restrict__ Wlfrag, const float* __restrict__ lng,
    const float* __restrict__ lnb, const float* __restrict__ blin,
    const float* __restrict__ x, float* __restrict__ out, int n)
{
    const int t = threadIdx.x, lane = t & 63, w = t >> 6;
    const int r0 = blockIdx.x * 16;
    const int lr = lane & 15, lk = (lane >> 4) << 3;
    __shared__ unsigned short nlds[16][520];        // normed bf16, +8 pad (16B-aligned rows)
    __shared__ float red_s[4][16], red_q[4][16], mval[16], rval[16];

    // ---- stage 1: wave w computes 16 rows x head-w cols of y
    f32x4 acc[8] = {};
    #pragma unroll
    for (int kt = 0; kt < 4; ++kt) {
        int row = r0 + lr; row = row < n ? row : n - 1;
        bf16x8 a = *(const bf16x8*)&wsum_bf[(size_t)row * 512 + w * 128 + kt * 32 + lk];
        #pragma unroll
        for (int ni = 0; ni < 8; ++ni) {
            bf16x8 bfr = *(const bf16x8*)&Wefrag[(size_t)(((w * 8 + ni) * 4 + kt) * 64 + lane) * 8];
            acc[ni] = __builtin_amdgcn_mfma_f32_16x16x32_bf16(a, bfr, acc[ni], 0, 0, 0);
        }
    }
    float g8[8], b8[8];
    #pragma unroll
    for (int ni = 0; ni < 8; ++ni) { int col = w * 128 + ni * 16 + lr; g8[ni] = lng[col]; b8[ni] = lnb[col]; }
    float sum_[4], sq_[4];
    #pragma unroll
    for (int j = 0; j < 4; ++j) {
        int row = r0 + (lane >> 4) * 4 + j;
        int rowc = row < n ? row : n - 1;
        const float hb = (row_start[rowc + 1] > row_start[rowc]) ? 1.f : 0.f;
        float s = 0.f, q = 0.f;
        #pragma unroll
        for (int ni = 0; ni < 8; ++ni) {
            int col = w * 128 + ni * 16 + lr;
            float y = acc[ni][j] + bf2f(vacc_bf[(size_t)rowc * 512 + col]) + hb * be[col]
                    + qs[(size_t)rowc * 512 + col];
            acc[ni][j] = y;
            s += y; q += y * y;
        }
        sum_[j] = s; sq_[j] = q;
    }
    #pragma unroll
    for (int o = 1; o <= 8; o <<= 1) {
        #pragma unroll
        for (int j = 0; j < 4; ++j) { sum_[j] += __shfl_xor(sum_[j], o); sq_[j] += __shfl_xor(sq_[j], o); }
    }
    if (lr == 0) {
        #pragma unroll
        for (int j = 0; j < 4; ++j) {
            red_s[w][(lane >> 4) * 4 + j] = sum_[j];
            red_q[w][(lane >> 4) * 4 + j] = sq_[j];
        }
    }
    __syncthreads();
    if (t < 16) {
        float S = red_s[0][t] + red_s[1][t] + red_s[2][t] + red_s[3][t];
        float Q = red_q[0][t] + red_q[1][t] + red_q[2][t] + red_q[3][t];
        float mu = S * (1.f / 512.f);
        float var = Q * (1.f / 512.f) - mu * mu;
        mval[t] = mu;
        rval[t] = rsqrtf(fmaxf(var, 0.f) + 1e-5f);
    }
    __syncthreads();
    #pragma unroll
    for (int j = 0; j < 4; ++j) {
        int rowl = (lane >> 4) * 4 + j;
        float mu = mval[rowl], rv = rval[rowl];
        #pragma unroll
        for (int ni = 0; ni < 8; ++ni) {
            int col = w * 128 + ni * 16 + lr;
            nlds[rowl][col] = f2bf((acc[ni][j] - mu) * rv * g8[ni] + b8[ni]);
        }
    }
    __syncthreads();
    // ---- stage 2: out = elu(nlds @ Wlin + blin + x), wave w covers cols [w*32, w*32+32)
    f32x4 acc2[2] = {};
    #pragma unroll
    for (int kt = 0; kt < 16; ++kt) {
        bf16x8 a2 = *(const bf16x8*)&nlds[lr][kt * 32 + lk];
        #pragma unroll
        for (int ni = 0; ni < 2; ++ni) {
            bf16x8 bfr = *(const bf16x8*)&Wlfrag[(size_t)(((w * 2 + ni) * 16 + kt) * 64 + lane) * 8];
            acc2[ni] = __builtin_amdgcn_mfma_f32_16x16x32_bf16(a2, bfr, acc2[ni], 0, 0, 0);
        }
    }
    #pragma unroll
    for (int j = 0; j < 4; ++j) {
        int row = r0 + (lane >> 4) * 4 + j;
        if (row < n) {
            #pragma unroll
            for (int ni = 0; ni < 2; ++ni) {
                int col = w * 32 + ni * 16 + lr;
                float z = acc2[ni][j] + blin[col] + x[(size_t)row * 128 + col];
                out[(size_t)row * 128 + col] = z > 0.f ? z : expm1f(z);
            }
        }
    }
}

extern "C" void kernel_launch(void* const* d_in, const int* in_sizes, int n_in,
                              void* d_out, int out_size, void* d_ws, size_t ws_size,
                              hipStream_t stream)
{
    const float* x   = (const float*)d_in[0];
    const int*   ei  = (const int*)d_in[1];
    const float* ea  = (const float*)d_in[2];
    const float* Wq  = (const float*)d_in[3];
    const float* bq  = (const float*)d_in[4];
    const float* Wk  = (const float*)d_in[5];
    const float* bk  = (const float*)d_in[6];
    const float* Wv  = (const float*)d_in[7];
    const float* bv  = (const float*)d_in[8];
    const float* We  = (const float*)d_in[9];
    const float* be  = (const float*)d_in[10];
    const float* Wsk = (const float*)d_in[11];
    const float* bsk = (const float*)d_in[12];
    const float* lng = (const float*)d_in[13];
    const float* lnb = (const float*)d_in[14];
    const float* Wl  = (const float*)d_in[15];
    const float* bl  = (const float*)d_in[16];
    float* out = (float*)d_out;

    const int n = in_sizes[0] / 128;
    const int E = in_sizes[1] / 2;

    float* qs    = (float*)d_ws;                    // n*512 (skip)
    float* WqeT  = qs + (size_t)n * 512;            // 128*512
    float* bqe   = WqeT + 128 * 512;                // 512
    float* bcat  = bqe + 512;                       // 2560
    unsigned short* x_bf    = (unsigned short*)(bcat + 2560);   // n*128
    unsigned short* wsum_bf = x_bf + (size_t)n * 128;           // n*512
    unsigned short* vacc_bf = wsum_bf + (size_t)n * 512;        // n*512
    unsigned short* kvq     = vacc_bf + (size_t)n * 512;        // n*2048 (q|k|v|qe)
    unsigned short* Wfrag   = kvq + (size_t)n * 2048;           // 128*2560
    unsigned short* Wefrag  = Wfrag + 128 * 2560;               // 128*512
    unsigned short* Wlfrag  = Wefrag + 128 * 512;               // 512*128
    int2* csr = (int2*)(((uintptr_t)(Wlfrag + 512 * 128) + 7) & ~(uintptr_t)7);  // E pairs
    int* deg       = (int*)(csr + E);
    int* row_start = deg + n;
    int* cursor    = row_start + n + 1;

    const int ndegb = (n + 255) / 256;
    wqe_k<<<258 + ndegb, 256, 0, stream>>>(Wq, bq, We, WqeT, bqe, deg, n);
    const int nb1 = (n * 32 + 255) / 256;           // x-conversion blocks (4 elems/thread)
    const int ndc = (E + 255) / 256;
    prep_k<<<nb1 + 234 + ndc, 256, 0, stream>>>(x, Wq, bq, Wk, bk, Wv, bv, Wsk, bsk, WqeT, bqe,
                                                We, Wl, x_bf, Wfrag, Wefrag, Wlfrag, bcat,
                                                ei, deg, E, n, nb1);
    scan_k<<<1, 1024, 0, stream>>>(deg, row_start, cursor, n);
    dim3 g1((n + 63) / 64, 41);
    node_gemm_mfma<<<g1, 256, 0, stream>>>(x_bf, Wfrag, bcat, qs, kvq, ei, cursor, csr, E, n);
    edge_k<<<(n + 1) / 2, 256, 0, stream>>>(kvq, ea, be, row_start, csr,
                                            wsum_bf, vacc_bf, n);
    tail_k<<<(n + 15) / 16, 256, 0, stream>>>(wsum_bf, Wefrag, be, vacc_bf, qs, row_start,
                                              Wlfrag, lng, lnb, bl, x, out, n);
}

// Round 9
// 170.618 us; speedup vs baseline: 8.7502x; 1.0027x over previous
//
#include <hip/hip_runtime.h>
#include <math.h>

// UniMP / TransformerConv block. bf16-MFMA GEMMs, single-pass flash-style edge phase
// (2 waves/node + LDS online-softmax merge, unroll-2 + 1-deep software pipeline),
// fused tail (GEMM+LN+GEMM+ELU).
//   alpha = q_s.k + ea.qe_s + q_s.be   (scale 1/sqrt(D) folded into Wq/WqeT/bqe)
//   agg   = sum attn*v[src] + (sum attn*ea) @ We_h + be_h
// Node tensors: qs f32 [n][512] = skip, kvq bf16 [n][2048] = [q|k|v|qe]
// 6 kernels: wqe(+degzero) -> prep(+degcount) -> scan -> node_gemm(+scatter) -> edge -> tail

typedef short bf16x8 __attribute__((ext_vector_type(8)));
typedef unsigned short u16x8 __attribute__((ext_vector_type(8)));
typedef float f32x4 __attribute__((ext_vector_type(4)));

#define SCALE 0.08838834764831845f  // 1/sqrt(128)

__device__ inline unsigned short f2bf(float f) {
    union { float f; unsigned u; } v; v.f = f;
    unsigned r = (v.u + 0x7FFFu + ((v.u >> 16) & 1u)) >> 16;
    return (unsigned short)r;
}
__device__ inline float bf2f(unsigned short u) {
    union { unsigned u; float f; } v; v.u = ((unsigned)u) << 16; return v.f;
}

// ---------------- K0: WqeT = s*Wq@We^T; bqe = s*bq@We^T; zero deg ----------------
__global__ __launch_bounds__(256) void wqe_k(
    const float* __restrict__ Wq, const float* __restrict__ bq,
    const float* __restrict__ We,
    float* __restrict__ WqeT, float* __restrict__ bqe,
    int* __restrict__ deg, int n)
{
    const int b = blockIdx.x;
    if (b < 256) {
        const int gid = b * 256 + threadIdx.x;      // 0..65535
        const int m = gid >> 9, hc = gid & 511;
        const int h = hc >> 7, c = hc & 127;
        const float* wq = &Wq[(size_t)m * 512 + h * 128];
        const float* we = &We[(size_t)c * 512 + h * 128];
        float s0 = 0.f, s1 = 0.f;
        #pragma unroll 8
        for (int d = 0; d < 128; d += 2) { s0 += wq[d] * we[d]; s1 += wq[d + 1] * we[d + 1]; }
        WqeT[(size_t)m * 512 + hc] = (s0 + s1) * SCALE;
    } else if (b < 258) {
        const int hc = (b - 256) * 256 + threadIdx.x;
        const int h = hc >> 7, c = hc & 127;
        const float* we = &We[(size_t)c * 512 + h * 128];
        const float* bb = &bq[h * 128];
        float s = 0.f;
        #pragma unroll 8
        for (int d = 0; d < 128; ++d) s += bb[d] * we[d];
        bqe[hc] = s * SCALE;
    } else {
        int idx = (b - 258) * 256 + threadIdx.x;
        if (idx < n) deg[idx] = 0;
    }
}

// ---------------- K0b: bf16 conversions + fragment layouts + deg_count ----------------
__global__ __launch_bounds__(256) void prep_k(
    const float* __restrict__ x,
    const float* __restrict__ Wq, const float* __restrict__ bq,
    const float* __restrict__ Wk, const float* __restrict__ bk,
    const float* __restrict__ Wv, const float* __restrict__ bv,
    const float* __restrict__ Ws, const float* __restrict__ bs,
    const float* __restrict__ WqeT, const float* __restrict__ bqe,
    const float* __restrict__ We, const float* __restrict__ Wlin,
    unsigned short* __restrict__ x_bf, unsigned short* __restrict__ Wfrag,
    unsigned short* __restrict__ Wefrag, unsigned short* __restrict__ Wlfrag,
    float* __restrict__ bcat,
    const int* __restrict__ ei, int* __restrict__ deg, int E, int n, int nb1)
{
    const int b = blockIdx.x, t = threadIdx.x;
    if (b < nb1) {                                  // x -> bf16, 4 elems/thread
        int i = (b * 256 + t) * 4;
        if (i < n * 128) {
            float4 v = *(const float4*)&x[i];
            unsigned short o[4] = { f2bf(v.x), f2bf(v.y), f2bf(v.z), f2bf(v.w) };
            *(uint2*)&x_bf[i] = *(uint2*)o;
        }
    } else if (b < nb1 + 160) {                     // Wfrag: [q|k|v|skip|qe] 128x2560
        int g = (b - nb1) * 256 + t;                // (nt*4+kt)*64+lane, nt<160
        int lane = g & 63, kt = (g >> 6) & 3, nt = g >> 8;
        int ncol = nt * 16 + (lane & 15);
        int k0 = kt * 32 + ((lane >> 4) << 3);
        const float* W; int c; float sc = 1.f;
        if      (ncol < 512)  { W = Wq;   c = ncol; sc = SCALE; }
        else if (ncol < 1024) { W = Wk;   c = ncol - 512; }
        else if (ncol < 1536) { W = Wv;   c = ncol - 1024; }
        else if (ncol < 2048) { W = Ws;   c = ncol - 1536; }
        else                  { W = WqeT; c = ncol - 2048; }
        unsigned short o[8];
        #pragma unroll
        for (int j = 0; j < 8; ++j) o[j] = f2bf(W[(size_t)(k0 + j) * 512 + c] * sc);
        *(uint4*)&Wfrag[(size_t)g * 8] = *(uint4*)o;
    } else if (b < nb1 + 192) {                     // Wefrag: We 128x512
        int g = (b - nb1 - 160) * 256 + t;          // nt<32, kt<4
        int lane = g & 63, kt = (g >> 6) & 3, nt = g >> 8;
        int ncol = nt * 16 + (lane & 15);
        int k0 = kt * 32 + ((lane >> 4) << 3);
        unsigned short o[8];
        #pragma unroll
        for (int j = 0; j < 8; ++j) o[j] = f2bf(We[(size_t)(k0 + j) * 512 + ncol]);
        *(uint4*)&Wefrag[(size_t)g * 8] = *(uint4*)o;
    } else if (b < nb1 + 224) {                     // Wlfrag: Wlin 512x128
        int g = (b - nb1 - 192) * 256 + t;          // (nt*16+kt)*64+lane, nt<8, kt<16
        int lane = g & 63, kt = (g >> 6) & 15, nt = g >> 10;
        int ncol = nt * 16 + (lane & 15);
        int k0 = kt * 32 + ((lane >> 4) << 3);
        unsigned short o[8];
        #pragma unroll
        for (int j = 0; j < 8; ++j) o[j] = f2bf(Wlin[(size_t)(k0 + j) * 128 + ncol]);
        *(uint4*)&Wlfrag[(size_t)g * 8] = *(uint4*)o;
    } else if (b < nb1 + 234) {                     // bcat[2560]
        int c = (b - nb1 - 224) * 256 + t;
        if (c < 2560)
            bcat[c] = (c < 512) ? bq[c] * SCALE : (c < 1024) ? bk[c - 512]
                     : (c < 1536) ? bv[c - 1024] : (c < 2048) ? bs[c - 1536] : bqe[c - 2048];
    } else {                                        // deg_count
        int e = (b - nb1 - 234) * 256 + t;
        if (e < E) atomicAdd(&deg[ei[E + e]], 1);
    }
}

// ---------------- K2: exclusive scan of deg -> row_start, cursor ----------------
__global__ __launch_bounds__(1024) void scan_k(const int* __restrict__ deg,
                                               int* __restrict__ row_start,
                                               int* __restrict__ cursor, int n)
{
    __shared__ int part[1024];
    const int t = threadIdx.x;
    const int c0 = t * 16;                  // supports n <= 16384
    int loc[16];
    int s = 0;
    #pragma unroll
    for (int i = 0; i < 16; ++i) {
        int idx = c0 + i;
        int dv = (idx < n) ? deg[idx] : 0;
        loc[i] = s; s += dv;
    }
    part[t] = s;
    __syncthreads();
    int incl = s;
    for (int off = 1; off < 1024; off <<= 1) {
        int other = (t >= off) ? part[t - off] : 0;
        __syncthreads();
        incl += other;
        part[t] = incl;
        __syncthreads();
    }
    const int base = incl - s;
    #pragma unroll
    for (int i = 0; i < 16; ++i) {
        int idx = c0 + i;
        if (idx < n) { row_start[idx] = base + loc[i]; cursor[idx] = base + loc[i]; }
    }
    if (t == 1023) row_start[n] = incl;
}

// ---------------- K3: node GEMM (bf16 MFMA, no LDS) + CSR scatter slice ----------------
// skip -> qs f32 [n][512]; q,k,v,qe -> kvq bf16 [n][2048]
__global__ __launch_bounds__(256) void node_gemm_mfma(
    const unsigned short* __restrict__ x_bf, const unsigned short* __restrict__ Wfrag,
    const float* __restrict__ bcat, float* __restrict__ qs,
    unsigned short* __restrict__ kvq,
    const int* __restrict__ ei, int* __restrict__ cursor, int2* __restrict__ csr,
    int E, int n)
{
    if (blockIdx.y == 40) {                         // scatter slice
        const int nth = gridDim.x * 256;
        for (int e = blockIdx.x * 256 + threadIdx.x; e < E; e += nth) {
            int dnode = ei[E + e];
            int p = atomicAdd(&cursor[dnode], 1);
            csr[p] = make_int2(e, ei[e]);           // (eid, src)
        }
        return;
    }
    const int t = threadIdx.x, lane = t & 63, w = t >> 6;
    const int m0 = blockIdx.x * 64 + (w >> 1) * 32;
    const int n0 = blockIdx.y * 64 + (w & 1) * 32;
    const int lr = lane & 15, lk = (lane >> 4) << 3;
    f32x4 acc[2][2] = {};
    #pragma unroll
    for (int kt = 0; kt < 4; ++kt) {
        bf16x8 a[2], bf[2];
        #pragma unroll
        for (int mi = 0; mi < 2; ++mi) {
            int row = m0 + mi * 16 + lr; row = row < n ? row : n - 1;
            a[mi] = *(const bf16x8*)&x_bf[(size_t)row * 128 + kt * 32 + lk];
        }
        #pragma unroll
        for (int ni = 0; ni < 2; ++ni) {
            int nt = (n0 + ni * 16) >> 4;
            bf[ni] = *(const bf16x8*)&Wfrag[(size_t)((nt * 4 + kt) * 64 + lane) * 8];
        }
        #pragma unroll
        for (int mi = 0; mi < 2; ++mi)
            #pragma unroll
            for (int ni = 0; ni < 2; ++ni)
                acc[mi][ni] = __builtin_amdgcn_mfma_f32_16x16x32_bf16(a[mi], bf[ni], acc[mi][ni], 0, 0, 0);
    }
    #pragma unroll
    for (int mi = 0; mi < 2; ++mi)
        #pragma unroll
        for (int j = 0; j < 4; ++j) {
            int row = m0 + mi * 16 + (lane >> 4) * 4 + j;
            if (row < n) {
                #pragma unroll
                for (int ni = 0; ni < 2; ++ni) {
                    int col = n0 + ni * 16 + lr;
                    float val = acc[mi][ni][j] + bcat[col];
                    if (col < 1536)       kvq[(size_t)row * 2048 + col] = f2bf(val);        // q,k,v
                    else if (col < 2048)  qs[(size_t)row * 512 + col - 1536] = val;         // skip
                    else                  kvq[(size_t)row * 2048 + col - 512] = f2bf(val);  // qe
                }
            }
        }
}

// ---------------- K5: flash-style edge phase, 2 waves/node + LDS merge ----------------
// unroll-2 + 1-deep software pipeline (issue next pair's loads before computing current).
// Block = 4 waves = 2 nodes. Wave pair (slot, half). 4 lane-groups x 16 lanes per wave:
// group g owns head g, lane owns 8 dims. Each half processes a contiguous edge range.
__global__ __launch_bounds__(256, 4) void edge_k(
    const unsigned short* __restrict__ kvq, const float* __restrict__ ea,
    const float* __restrict__ be,
    const int* __restrict__ row_start, const int2* __restrict__ csr,
    unsigned short* __restrict__ wsum_bf, unsigned short* __restrict__ vacc_bf, int n)
{
    const int t = threadIdx.x, lane = t & 63, w = t >> 6;
    const int slot = w >> 1, half = w & 1;
    const int node = blockIdx.x * 2 + slot;
    const bool nvalid = node < n;
    const int nodec = nvalid ? node : 0;
    const int g = lane >> 4;            // head
    const int l15 = lane & 15;
    const int sl = l15 * 8;             // dim slice within head

    __shared__ float lds_m[2][4], lds_den[2][4];
    __shared__ float lds_va[2][4][128], lds_ws[2][4][128];

    int rs = 0, deg = 0;
    if (nvalid) { rs = row_start[node]; deg = row_start[node + 1] - rs; }
    const int dh = (deg + 1) >> 1;
    const int lo = half ? dh : 0;
    const int myc = half ? (deg - dh) : dh;

    // per-lane q_s, qe_s (pre-scaled, bf16)
    float q8[8], qe8[8];
    {
        const u16x8 uq  = *(const u16x8*)&kvq[(size_t)nodec * 2048 + g * 128 + sl];
        const u16x8 uqe = *(const u16x8*)&kvq[(size_t)nodec * 2048 + 1536 + g * 128 + sl];
        #pragma unroll
        for (int i = 0; i < 8; ++i) { q8[i] = bf2f(uq[i]); qe8[i] = bf2f(uqe[i]); }
    }
    float qbe;
    {
        const float* bp = &be[g * 128 + sl];
        float pb = 0.f;
        #pragma unroll
        for (int i = 0; i < 8; ++i) pb += q8[i] * bp[i];
        #pragma unroll
        for (int o = 1; o <= 8; o <<= 1) pb += __shfl_xor(pb, o);
        qbe = pb;
    }

    float m = -3.0e38f, den = 0.f;
    float va[8] = {}, ws[8] = {};

    for (int j0 = 0; j0 < myc; j0 += 64) {
        const int cnt = min(64, myc - j0);
        int2 my = make_int2(0, 0);
        if (lane < cnt) my = csr[rs + lo + j0 + lane];

        // ---- preload pair 0 (current register set)
        float4 cA0, cB0, cA1, cB1; u16x8 cK0, cV0, cK1, cV1;
        {
            const int i1 = (1 < cnt) ? 1 : 0;
            const int e0 = __shfl(my.x, 0), s0_ = __shfl(my.y, 0);
            const int e1 = __shfl(my.x, i1), s1_ = __shfl(my.y, i1);
            const float* ep0 = &ea[(size_t)e0 * 128 + sl];
            const float* ep1 = &ea[(size_t)e1 * 128 + sl];
            cA0 = *(const float4*)ep0; cB0 = *(const float4*)(ep0 + 4);
            cA1 = *(const float4*)ep1; cB1 = *(const float4*)(ep1 + 4);
            cK0 = *(const u16x8*)&kvq[(size_t)s0_ * 2048 + 512 + g * 128 + sl];
            cV0 = *(const u16x8*)&kvq[(size_t)s0_ * 2048 + 1024 + g * 128 + sl];
            cK1 = *(const u16x8*)&kvq[(size_t)s1_ * 2048 + 512 + g * 128 + sl];
            cV1 = *(const u16x8*)&kvq[(size_t)s1_ * 2048 + 1024 + g * 128 + sl];
        }

        for (int jj = 0; jj < cnt; jj += 2) {
            // ---- issue next pair's loads (hide latency under current compute)
            float4 nA0, nB0, nA1, nB1; u16x8 nK0, nV0, nK1, nV1;
            {
                const int nj = (jj + 2 < cnt) ? jj + 2 : jj;        // clamped; unused on exit
                const int i1 = (nj + 1 < cnt) ? nj + 1 : nj;
                const int e0 = __shfl(my.x, nj), s0_ = __shfl(my.y, nj);
                const int e1 = __shfl(my.x, i1), s1_ = __shfl(my.y, i1);
                const float* ep0 = &ea[(size_t)e0 * 128 + sl];
                const float* ep1 = &ea[(size_t)e1 * 128 + sl];
                nA0 = *(const float4*)ep0; nB0 = *(const float4*)(ep0 + 4);
                nA1 = *(const float4*)ep1; nB1 = *(const float4*)(ep1 + 4);
                nK0 = *(const u16x8*)&kvq[(size_t)s0_ * 2048 + 512 + g * 128 + sl];
                nV0 = *(const u16x8*)&kvq[(size_t)s0_ * 2048 + 1024 + g * 128 + sl];
                nK1 = *(const u16x8*)&kvq[(size_t)s1_ * 2048 + 512 + g * 128 + sl];
                nV1 = *(const u16x8*)&kvq[(size_t)s1_ * 2048 + 1024 + g * 128 + sl];
            }
            // ---- compute with current pair
            const bool two = (jj + 1 < cnt);
            float ef0[8] = {cA0.x, cA0.y, cA0.z, cA0.w, cB0.x, cB0.y, cB0.z, cB0.w};
            float ef1[8] = {cA1.x, cA1.y, cA1.z, cA1.w, cB1.x, cB1.y, cB1.z, cB1.w};
            float p0 = 0.f, p1 = 0.f;
            #pragma unroll
            for (int i = 0; i < 8; ++i) {
                p0 += q8[i] * bf2f(cK0[i]) + qe8[i] * ef0[i];
                p1 += q8[i] * bf2f(cK1[i]) + qe8[i] * ef1[i];
            }
            #pragma unroll
            for (int o = 1; o <= 8; o <<= 1) {
                p0 += __shfl_xor(p0, o);
                p1 += __shfl_xor(p1, o);
            }
            const float a0 = p0 + qbe;
            const float a1 = two ? (p1 + qbe) : -3.0e38f;   // dummy tail: weight 0
            // group-max batched online update (deferred-max THR=8)
            const float gm = fmaxf(a0, a1);
            if (gm > m + 8.f) {
                const float sc = __expf(m - gm);
                den *= sc;
                #pragma unroll
                for (int i = 0; i < 8; ++i) { va[i] *= sc; ws[i] *= sc; }
                m = gm;
            }
            const float w0 = __expf(a0 - m);
            const float w1 = __expf(a1 - m);
            den += w0 + w1;
            #pragma unroll
            for (int i = 0; i < 8; ++i) {
                va[i] += w0 * bf2f(cV0[i]) + w1 * bf2f(cV1[i]);
                ws[i] += w0 * ef0[i] + w1 * ef1[i];
            }
            // ---- rotate pipeline registers
            cA0 = nA0; cB0 = nB0; cA1 = nA1; cB1 = nB1;
            cK0 = nK0; cV0 = nV0; cK1 = nK1; cV1 = nV1;
        }
    }

    // merge halves: half 1 publishes, half 0 combines and writes out
    if (half == 1) {
        if (l15 == 0) { lds_m[slot][g] = m; lds_den[slot][g] = den; }
        #pragma unroll
        for (int i = 0; i < 8; ++i) {
            lds_va[slot][g][sl + i] = va[i];
            lds_ws[slot][g][sl + i] = ws[i];
        }
    }
    __syncthreads();
    if (half == 0 && nvalid) {
        const float m1 = lds_m[slot][g], den1 = lds_den[slot][g];
        const float M = fmaxf(m, m1);
        const float s0 = __expf(m - M), s1 = __expf(m1 - M);
        const float dtot = den * s0 + den1 * s1;
        const float rden = (dtot > 0.f) ? 1.f / dtot : 0.f;
        unsigned short vo[8], wo[8];
        #pragma unroll
        for (int i = 0; i < 8; ++i) {
            vo[i] = f2bf((va[i] * s0 + lds_va[slot][g][sl + i] * s1) * rden);
            wo[i] = f2bf((ws[i] * s0 + lds_ws[slot][g][sl + i] * s1) * rden);
        }
        *(uint4*)&vacc_bf[(size_t)node * 512 + g * 128 + sl] = *(uint4*)vo;
        *(uint4*)&wsum_bf[(size_t)node * 512 + g * 128 + sl] = *(uint4*)wo;
    }
}

// ---------------- K6: fused tail: y = vacc + wsum@We_h + hb*be + skip; LN; out-GEMM; ELU --
// 16 rows/block, 4 waves; wave w = head w for stage 1, cols [w*32,w*32+32) for stage 2.
__global__ __launch_bounds__(256) void tail_k(
    const unsigned short* __restrict__ wsum_bf, const unsigned short* __restrict__ Wefrag,
    const float* __restrict__ be, const unsigned short* __restrict__ vacc_bf,
    const float* __restrict__ qs, const int* __restrict__ row_start,
    const unsigned short* __restrict__ Wlfrag, const float* __restrict__ lng,
    const float* __restrict__ lnb, const float* __restrict__ blin,
    const float* __restrict__ x, float* __restrict__ out, int n)
{
    const int t = threadIdx.x, lane = t & 63, w = t >> 6;
    const int r0 = blockIdx.x * 16;
    const int lr = lane & 15, lk = (lane >> 4) << 3;
    __shared__ unsigned short nlds[16][520];        // normed bf16, +8 pad (16B-aligned rows)
    __shared__ float red_s[4][16], red_q[4][16], mval[16], rval[16];

    // ---- stage 1: wave w computes 16 rows x head-w cols of y
    f32x4 acc[8] = {};
    #pragma unroll
    for (int kt = 0; kt < 4; ++kt) {
        int row = r0 + lr; row = row < n ? row : n - 1;
        bf16x8 a = *(const bf16x8*)&wsum_bf[(size_t)row * 512 + w * 128 + kt * 32 + lk];
        #pragma unroll
        for (int ni = 0; ni < 8; ++ni) {
            bf16x8 bfr = *(const bf16x8*)&Wefrag[(size_t)(((w * 8 + ni) * 4 + kt) * 64 + lane) * 8];
            acc[ni] = __builtin_amdgcn_mfma_f32_16x16x32_bf16(a, bfr, acc[ni], 0, 0, 0);
        }
    }
    float g8[8], b8[8];
    #pragma unroll
    for (int ni = 0; ni < 8; ++ni) { int col = w * 128 + ni * 16 + lr; g8[ni] = lng[col]; b8[ni] = lnb[col]; }
    float sum_[4], sq_[4];
    #pragma unroll
    for (int j = 0; j < 4; ++j) {
        int row = r0 + (lane >> 4) * 4 + j;
        int rowc = row < n ? row : n - 1;
        const float hb = (row_start[rowc + 1] > row_start[rowc]) ? 1.f : 0.f;
        float s = 0.f, q = 0.f;
        #pragma unroll
        for (int ni = 0; ni < 8; ++ni) {
            int col = w * 128 + ni * 16 + lr;
            float y = acc[ni][j] + bf2f(vacc_bf[(size_t)rowc * 512 + col]) + hb * be[col]
                    + qs[(size_t)rowc * 512 + col];
            acc[ni][j] = y;
            s += y; q += y * y;
        }
        sum_[j] = s; sq_[j] = q;
    }
    #pragma unroll
    for (int o = 1; o <= 8; o <<= 1) {
        #pragma unroll
        for (int j = 0; j < 4; ++j) { sum_[j] += __shfl_xor(sum_[j], o); sq_[j] += __shfl_xor(sq_[j], o); }
    }
    if (lr == 0) {
        #pragma unroll
        for (int j = 0; j < 4; ++j) {
            red_s[w][(lane >> 4) * 4 + j] = sum_[j];
            red_q[w][(lane >> 4) * 4 + j] = sq_[j];
        }
    }
    __syncthreads();
    if (t < 16) {
        float S = red_s[0][t] + red_s[1][t] + red_s[2][t] + red_s[3][t];
        float Q = red_q[0][t] + red_q[1][t] + red_q[2][t] + red_q[3][t];
        float mu = S * (1.f / 512.f);
        float var = Q * (1.f / 512.f) - mu * mu;
        mval[t] = mu;
        rval[t] = rsqrtf(fmaxf(var, 0.f) + 1e-5f);
    }
    __syncthreads();
    #pragma unroll
    for (int j = 0; j < 4; ++j) {
        int rowl = (lane >> 4) * 4 + j;
        float mu = mval[rowl], rv = rval[rowl];
        #pragma unroll
        for (int ni = 0; ni < 8; ++ni) {
            int col = w * 128 + ni * 16 + lr;
            nlds[rowl][col] = f2bf((acc[ni][j] - mu) * rv * g8[ni] + b8[ni]);
        }
    }
    __syncthreads();
    // ---- stage 2: out = elu(nlds @ Wlin + blin + x), wave w covers cols [w*32, w*32+32)
    f32x4 acc2[2] = {};
    #pragma unroll
    for (int kt = 0; kt < 16; ++kt) {
        bf16x8 a2 = *(const bf16x8*)&nlds[lr][kt * 32 + lk];
        #pragma unroll
        for (int ni = 0; ni < 2; ++ni) {
            bf16x8 bfr = *(const bf16x8*)&Wlfrag[(size_t)(((w * 2 + ni) * 16 + kt) * 64 + lane) * 8];
            acc2[ni] = __builtin_amdgcn_mfma_f32_16x16x32_bf16(a2, bfr, acc2[ni], 0, 0, 0);
        }
    }
    #pragma unroll
    for (int j = 0; j < 4; ++j) {
        int row = r0 + (lane >> 4) * 4 + j;
        if (row < n) {
            #pragma unroll
            for (int ni = 0; ni < 2; ++ni) {
                int col = w * 32 + ni * 16 + lr;
                float z = acc2[ni][j] + blin[col] + x[(size_t)row * 128 + col];
                out[(size_t)row * 128 + col] = z > 0.f ? z : expm1f(z);
            }
        }
    }
}

extern "C" void kernel_launch(void* const* d_in, const int* in_sizes, int n_in,
                              void* d_out, int out_size, void* d_ws, size_t ws_size,
                              hipStream_t stream)
{
    const float* x   = (const float*)d_in[0];
    const int*   ei  = (const int*)d_in[1];
    const float* ea  = (const float*)d_in[2];
    const float* Wq  = (const float*)d_in[3];
    const float* bq  = (const float*)d_in[4];
    const float* Wk  = (const float*)d_in[5];
    const float* bk  = (const float*)d_in[6];
    const float* Wv  = (const float*)d_in[7];
    const float* bv  = (const float*)d_in[8];
    const float* We  = (const float*)d_in[9];
    const float* be  = (const float*)d_in[10];
    const float* Wsk = (const float*)d_in[11];
    const float* bsk = (const float*)d_in[12];
    const float* lng = (const float*)d_in[13];
    const float* lnb = (const float*)d_in[14];
    const float* Wl  = (const float*)d_in[15];
    const float* bl  = (const float*)d_in[16];
    float* out = (float*)d_out;

    const int n = in_sizes[0] / 128;
    const int E = in_sizes[1] / 2;

    float* qs    = (float*)d_ws;                    // n*512 (skip)
    float* WqeT  = qs + (size_t)n * 512;            // 128*512
    float* bqe   = WqeT + 128 * 512;                // 512
    float* bcat  = bqe + 512;                       // 2560
    unsigned short* x_bf    = (unsigned short*)(bcat + 2560);   // n*128
    unsigned short* wsum_bf = x_bf + (size_t)n * 128;           // n*512
    unsigned short* vacc_bf = wsum_bf + (size_t)n * 512;        // n*512
    unsigned short* kvq     = vacc_bf + (size_t)n * 512;        // n*2048 (q|k|v|qe)
    unsigned short* Wfrag   = kvq + (size_t)n * 2048;           // 128*2560
    unsigned short* Wefrag  = Wfrag + 128 * 2560;               // 128*512
    unsigned short* Wlfrag  = Wefrag + 128 * 512;               // 512*128
    int2* csr = (int2*)(((uintptr_t)(Wlfrag + 512 * 128) + 7) & ~(uintptr_t)7);  // E pairs
    int* deg       = (int*)(csr + E);
    int* row_start = deg + n;
    int* cursor    = row_start + n + 1;

    const int ndegb = (n + 255) / 256;
    wqe_k<<<258 + ndegb, 256, 0, stream>>>(Wq, bq, We, WqeT, bqe, deg, n);
    const int nb1 = (n * 32 + 255) / 256;           // x-conversion blocks (4 elems/thread)
    const int ndc = (E + 255) / 256;
    prep_k<<<nb1 + 234 + ndc, 256, 0, stream>>>(x, Wq, bq, Wk, bk, Wv, bv, Wsk, bsk, WqeT, bqe,
                                                We, Wl, x_bf, Wfrag, Wefrag, Wlfrag, bcat,
                                                ei, deg, E, n, nb1);
    scan_k<<<1, 1024, 0, stream>>>(deg, row_start, cursor, n);
    dim3 g1((n + 63) / 64, 41);
    node_gemm_mfma<<<g1, 256, 0, stream>>>(x_bf, Wfrag, bcat, qs, kvq, ei, cursor, csr, E, n);
    edge_k<<<(n + 1) / 2, 256, 0, stream>>>(kvq, ea, be, row_start, csr,
                                            wsum_bf, vacc_bf, n);
    tail_k<<<(n + 15) / 16, 256, 0, stream>>>(wsum_bf, Wefrag, be, vacc_bf, qs, row_start,
                                              Wlfrag, lng, lnb, bl, x, out, n);
}